// Round 1
// baseline (326.101 us; speedup 1.0000x reference)
//
#include <hip/hip_runtime.h>
#include <hip/hip_bf16.h>
#include <type_traits>

#define DI __device__ __forceinline__

typedef unsigned short u16;
typedef __bf16 bf16x8 __attribute__((ext_vector_type(8)));
typedef u16 u16x8 __attribute__((ext_vector_type(8)));
typedef float f32x4 __attribute__((ext_vector_type(4)));

constexpr int Bb = 2, Ls = 2048, Hh = 16, KVh = 4, HD = 64;
constexpr int NQKV = 1536;
constexpr float SCALE = 0.125f;          // 1/sqrt(64)
constexpr float LOG2E = 1.44269504088896f;

DI u16 f2bf(float f) {
  __hip_bfloat16 h = __float2bfloat16(f);
  return __builtin_bit_cast(u16, h);
}

DI f32x4 mfma16(bf16x8 a, bf16x8 b, f32x4 c) {
  return __builtin_amdgcn_mfma_f32_16x16x32_bf16(a, b, c, 0, 0, 0);
}

// ---- stage 1: conversions ------------------------------------------------
__global__ void cvt_hs(const float* __restrict__ in, u16* __restrict__ out) {
  int i = blockIdx.x * 256 + threadIdx.x;           // over n/4 vec4 chunks
  float4 v = reinterpret_cast<const float4*>(in)[i];
  ushort4 o;
  o.x = f2bf(v.x); o.y = f2bf(v.y); o.z = f2bf(v.z); o.w = f2bf(v.w);
  reinterpret_cast<ushort4*>(out)[i] = o;
}

// in: f32 [1024][N] -> out bf16 [N][1024] at row offset rowoff
__global__ void cvt_wt(const float* __restrict__ in, u16* __restrict__ out,
                       int N, int rowoff) {
  int idx = blockIdx.x * 256 + threadIdx.x;         // over 1024*N
  int k = idx / N, n = idx - k * N;
  out[(size_t)(rowoff + n) * 1024 + k] = f2bf(in[idx]);
}

// ---- GEMM: A[M][K] bf16 * Bt[N][K] bf16 -> C[M][N] ------------------------
template <typename OUTT>
__global__ __launch_bounds__(256) void gemm_bt(
    const u16* __restrict__ A, const u16* __restrict__ Bt,
    OUTT* __restrict__ C, int M, int N, int K) {
  __shared__ u16 lA[128 * 32];
  __shared__ u16 lB[128 * 32];
  const int m0 = blockIdx.y * 128, n0 = blockIdx.x * 128;
  const int tid = threadIdx.x;
  const int w = tid >> 6, lane = tid & 63;
  const int wr = (w >> 1) * 64, wc = (w & 1) * 64;
  const int lr = lane & 15, lk = (lane >> 4) * 8;
  const int r0 = tid >> 2, c0 = (tid & 3) * 8;      // staging chunk
  const int r1 = r0 + 64;
  f32x4 acc[4][4] = {};
  for (int k0 = 0; k0 < K; k0 += 32) {
    __syncthreads();
    *reinterpret_cast<u16x8*>(&lA[r0 * 32 + c0]) =
        *reinterpret_cast<const u16x8*>(&A[(size_t)(m0 + r0) * K + k0 + c0]);
    *reinterpret_cast<u16x8*>(&lA[r1 * 32 + c0]) =
        *reinterpret_cast<const u16x8*>(&A[(size_t)(m0 + r1) * K + k0 + c0]);
    *reinterpret_cast<u16x8*>(&lB[r0 * 32 + c0]) =
        *reinterpret_cast<const u16x8*>(&Bt[(size_t)(n0 + r0) * K + k0 + c0]);
    *reinterpret_cast<u16x8*>(&lB[r1 * 32 + c0]) =
        *reinterpret_cast<const u16x8*>(&Bt[(size_t)(n0 + r1) * K + k0 + c0]);
    __syncthreads();
    bf16x8 af[4], bfv[4];
#pragma unroll
    for (int m = 0; m < 4; m++)
      af[m] = *reinterpret_cast<const bf16x8*>(&lA[(wr + m * 16 + lr) * 32 + lk]);
#pragma unroll
    for (int n = 0; n < 4; n++)
      bfv[n] = *reinterpret_cast<const bf16x8*>(&lB[(wc + n * 16 + lr) * 32 + lk]);
#pragma unroll
    for (int m = 0; m < 4; m++)
#pragma unroll
      for (int n = 0; n < 4; n++)
        acc[m][n] = mfma16(af[m], bfv[n], acc[m][n]);
  }
  const int rr = (lane >> 4) * 4, cc = lane & 15;
#pragma unroll
  for (int m = 0; m < 4; m++) {
#pragma unroll
    for (int r = 0; r < 4; r++) {
      int row = m0 + wr + m * 16 + rr + r;
#pragma unroll
      for (int n = 0; n < 4; n++) {
        int col = n0 + wc + n * 16 + cc;
        float v = acc[m][n][r];
        if constexpr (std::is_same<OUTT, float>::value)
          C[(size_t)row * N + col] = v;
        else
          C[(size_t)row * N + col] = f2bf(v);
      }
    }
  }
}

// ---- stage 3: reorg Q/K compact, V transpose -----------------------------
__global__ void reorg_qk(const u16* __restrict__ qkv, u16* __restrict__ Qc,
                         u16* __restrict__ Kc) {
  int idx = blockIdx.x * 256 + threadIdx.x;   // B*(H+KV)*L*8 = 655360
  int d8 = (idx & 7) * 8;
  int t = idx >> 3;
  int l = t & (Ls - 1); t >>= 11;
  int hh = t % 20, b = t / 20;
  int srccol = (hh < 16 ? hh * 64 : 1024 + (hh - 16) * 64) + d8;
  u16x8 v = *reinterpret_cast<const u16x8*>(
      &qkv[(size_t)(b * Ls + l) * NQKV + srccol]);
  u16* dst = (hh < 16)
                 ? &Qc[((size_t)(b * Hh + hh) * Ls + l) * HD + d8]
                 : &Kc[((size_t)(b * KVh + (hh - 16)) * Ls + l) * HD + d8];
  *reinterpret_cast<u16x8*>(dst) = v;
}

// Vt[b][kv][d][l] = V[b][l][kv][d]
__global__ void trans_v(const u16* __restrict__ qkv, u16* __restrict__ Vt) {
  __shared__ u16 tile[64][72];                // 144B row stride, 16B aligned
  int l0 = blockIdx.x * 64;
  int bk = blockIdx.y;                        // b*4+kv
  int b = bk >> 2, kv = bk & 3;
  int tid = threadIdx.x;
  for (int i = tid; i < 512; i += 256) {
    int l = i >> 3, d8 = (i & 7) * 8;
    u16x8 v = *reinterpret_cast<const u16x8*>(
        &qkv[(size_t)(b * Ls + l0 + l) * NQKV + 1280 + kv * 64 + d8]);
    *reinterpret_cast<u16x8*>(&tile[l][d8]) = v;
  }
  __syncthreads();
  for (int i = tid; i < 512; i += 256) {
    int d = i >> 3, l8 = (i & 7) * 8;
    u16x8 tv;
#pragma unroll
    for (int j = 0; j < 8; j++) tv[j] = tile[l8 + j][d];
    *reinterpret_cast<u16x8*>(&Vt[((size_t)bk * HD + d) * Ls + l0 + l8]) = tv;
  }
}

// ---- stage 4: flash attention -------------------------------------------
__global__ __launch_bounds__(256) void attn(
    const u16* __restrict__ Qc, const u16* __restrict__ Kc,
    const u16* __restrict__ Vt, const int* __restrict__ seg,
    u16* __restrict__ Obuf) {
  int qt = blockIdx.x, h = blockIdx.y, b = blockIdx.z;
  int kvh = h >> 2;
  int w = threadIdx.x >> 6, lane = threadIdx.x & 63;
  int q0 = qt * 64 + w * 16;
  float slope = exp2f(-0.5f * (float)(h + 1));
  const u16* Qb = Qc + (size_t)(b * Hh + h) * Ls * HD;
  const u16* Kb = Kc + (size_t)(b * KVh + kvh) * Ls * HD;
  const u16* Vb = Vt + (size_t)(b * KVh + kvh) * HD * Ls;
  const int* segb = seg + b * Ls;
  int lr = lane & 15, hi = lane >> 4, lk = hi * 8;
  bf16x8 qa0 = *reinterpret_cast<const bf16x8*>(&Qb[(q0 + lr) * HD + lk]);
  bf16x8 qa1 = *reinterpret_cast<const bf16x8*>(&Qb[(q0 + lr) * HD + 32 + lk]);
  int qrow = q0 + hi * 4;
  int qsg[4];
#pragma unroll
  for (int r = 0; r < 4; r++) qsg[r] = segb[qrow + r];
  float m_run[4], l_run[4];
#pragma unroll
  for (int r = 0; r < 4; r++) { m_run[r] = -1e30f; l_run[r] = 0.f; }
  f32x4 oacc[4] = {};
  __shared__ u16 pl[4][16 * 32];
  u16* pw = pl[w];
  for (int k0 = 0; k0 < q0 + 16; k0 += 32) {
    f32x4 s[2];
#pragma unroll
    for (int t = 0; t < 2; t++) {
      bf16x8 kb0 = *reinterpret_cast<const bf16x8*>(
          &Kb[(k0 + t * 16 + lr) * HD + lk]);
      bf16x8 kb1 = *reinterpret_cast<const bf16x8*>(
          &Kb[(k0 + t * 16 + lr) * HD + 32 + lk]);
      f32x4 z = {};
      z = mfma16(qa0, kb0, z);
      z = mfma16(qa1, kb1, z);
      s[t] = z;
    }
#pragma unroll
    for (int t = 0; t < 2; t++) {
      int j = k0 + t * 16 + lr;
      int cs = segb[j];
#pragma unroll
      for (int r = 0; r < 4; r++) {
        int i = qrow + r;
        bool valid = (j <= i) && (cs == qsg[r]);
        s[t][r] = valid ? s[t][r] * SCALE - slope * (float)(i - j) : -1e30f;
      }
    }
#pragma unroll
    for (int r = 0; r < 4; r++) {
      float v = fmaxf(s[0][r], s[1][r]);
#pragma unroll
      for (int d = 1; d < 16; d <<= 1) v = fmaxf(v, __shfl_xor(v, d));
      float mn = fmaxf(m_run[r], v);
      float fac = exp2f((m_run[r] - mn) * LOG2E);
      m_run[r] = mn;
      float p0 = exp2f((s[0][r] - mn) * LOG2E);
      float p1 = exp2f((s[1][r] - mn) * LOG2E);
      s[0][r] = p0; s[1][r] = p1;
      float rs = p0 + p1;
#pragma unroll
      for (int d = 1; d < 16; d <<= 1) rs += __shfl_xor(rs, d);
      l_run[r] = l_run[r] * fac + rs;
#pragma unroll
      for (int n = 0; n < 4; n++) oacc[n][r] *= fac;
    }
    // P (C-layout) -> LDS -> A-frag layout
#pragma unroll
    for (int t = 0; t < 2; t++)
#pragma unroll
      for (int r = 0; r < 4; r++)
        pw[(hi * 4 + r) * 32 + t * 16 + lr] = f2bf(s[t][r]);
    bf16x8 pa = *reinterpret_cast<const bf16x8*>(&pw[lr * 32 + lk]);
#pragma unroll
    for (int n = 0; n < 4; n++) {
      bf16x8 vb = *reinterpret_cast<const bf16x8*>(
          &Vb[(size_t)(n * 16 + lr) * Ls + k0 + lk]);
      oacc[n] = mfma16(pa, vb, oacc[n]);
    }
  }
#pragma unroll
  for (int r = 0; r < 4; r++) {
    float inv = 1.0f / l_run[r];
    int row = b * Ls + qrow + r;
#pragma unroll
    for (int n = 0; n < 4; n++)
      Obuf[(size_t)row * 1024 + h * 64 + n * 16 + lr] = f2bf(oacc[n][r] * inv);
  }
}

// ---- launch ---------------------------------------------------------------
extern "C" void kernel_launch(void* const* d_in, const int* in_sizes, int n_in,
                              void* d_out, int out_size, void* d_ws, size_t ws_size,
                              hipStream_t stream) {
  const float* hs = (const float*)d_in[0];
  const int* seg = (const int*)d_in[1];
  const float* Wq = (const float*)d_in[2];
  const float* Wk = (const float*)d_in[3];
  const float* Wv = (const float*)d_in[4];
  const float* Wo = (const float*)d_in[5];
  float* out = (float*)d_out;
  char* ws = (char*)d_ws;
  // layout (bytes): hsb 8.4M | wqkvT 3.1M | woT 2.1M | qkvb 12.6M | qc 8.4M |
  //                 kc 2.1M | vt 2.1M ; obuf aliases hsb (dead after GEMM1)
  u16* hsb   = (u16*)(ws);
  u16* wqkvT = (u16*)(ws + 8388608);
  u16* woT   = (u16*)(ws + 11534336);
  u16* qkvb  = (u16*)(ws + 13631488);
  u16* qc    = (u16*)(ws + 26214400);
  u16* kc    = (u16*)(ws + 34603008);
  u16* vt    = (u16*)(ws + 36700160);
  u16* obuf  = hsb;

  cvt_hs<<<dim3(4096), dim3(256), 0, stream>>>(hs, hsb);
  cvt_wt<<<dim3(4096), dim3(256), 0, stream>>>(Wq, wqkvT, 1024, 0);
  cvt_wt<<<dim3(1024), dim3(256), 0, stream>>>(Wk, wqkvT, 256, 1024);
  cvt_wt<<<dim3(1024), dim3(256), 0, stream>>>(Wv, wqkvT, 256, 1280);
  cvt_wt<<<dim3(4096), dim3(256), 0, stream>>>(Wo, woT, 1024, 0);
  gemm_bt<u16><<<dim3(12, 32), dim3(256), 0, stream>>>(hsb, wqkvT, qkvb,
                                                       4096, 1536, 1024);
  reorg_qk<<<dim3(2560), dim3(256), 0, stream>>>(qkvb, qc, kc);
  trans_v<<<dim3(32, 8), dim3(256), 0, stream>>>(qkvb, vt);
  attn<<<dim3(32, 16, 2), dim3(256), 0, stream>>>(qc, kc, vt, seg, obuf);
  gemm_bt<float><<<dim3(8, 32), dim3(256), 0, stream>>>(obuf, woT, out,
                                                        4096, 1024, 1024);
}

// Round 2
// 142.218 us; speedup vs baseline: 2.2930x; 2.2930x over previous
//
#include <hip/hip_runtime.h>
#include <hip/hip_bf16.h>
#include <type_traits>

#define DI __device__ __forceinline__

typedef unsigned short u16;
typedef unsigned int u32;
typedef __bf16 bf16x8 __attribute__((ext_vector_type(8)));
typedef u16 u16x8 __attribute__((ext_vector_type(8)));
typedef float f32x4 __attribute__((ext_vector_type(4)));
typedef float f32x16 __attribute__((ext_vector_type(16)));
typedef u32 u32x4 __attribute__((ext_vector_type(4)));

constexpr int Bb = 2, Ls = 2048, Hh = 16, KVh = 4, HD = 64;
constexpr int NQKV = 1536;
constexpr float LOG2E = 1.44269504088896f;

DI u16 f2bf(float f) {
  __hip_bfloat16 h = __float2bfloat16(f);
  return __builtin_bit_cast(u16, h);
}

DI f32x4 mfma16(bf16x8 a, bf16x8 b, f32x4 c) {
  return __builtin_amdgcn_mfma_f32_16x16x32_bf16(a, b, c, 0, 0, 0);
}
DI f32x16 mfma32(bf16x8 a, bf16x8 b, f32x16 c) {
  return __builtin_amdgcn_mfma_f32_32x32x16_bf16(a, b, c, 0, 0, 0);
}

// ---- stage 1: conversions ------------------------------------------------
__global__ void cvt_hs(const float* __restrict__ in, u16* __restrict__ out) {
  int i = blockIdx.x * 256 + threadIdx.x;
  float4 v = reinterpret_cast<const float4*>(in)[i];
  ushort4 o;
  o.x = f2bf(v.x); o.y = f2bf(v.y); o.z = f2bf(v.z); o.w = f2bf(v.w);
  reinterpret_cast<ushort4*>(out)[i] = o;
}

// in: f32 [1024][N] -> out bf16 [N][1024] at row offset rowoff
__global__ void cvt_wt(const float* __restrict__ in, u16* __restrict__ out,
                       int N, int rowoff) {
  int idx = blockIdx.x * 256 + threadIdx.x;
  int k = idx / N, n = idx - k * N;
  out[(size_t)(rowoff + n) * 1024 + k] = f2bf(in[idx]);
}

// segment start per row: segments are sorted -> contiguous ranges
__global__ void seg_start(const int* __restrict__ seg, int* __restrict__ sst) {
  int b = blockIdx.y;
  int l = blockIdx.x * 256 + threadIdx.x;
  const int* s = seg + b * Ls;
  int v = s[l];
  int lo = 0, hi = l;
  while (lo < hi) {
    int mid = (lo + hi) >> 1;
    if (s[mid] < v) lo = mid + 1; else hi = mid;
  }
  sst[b * Ls + l] = lo;
}

// ---- GEMM: A[M][K] bf16 * Bt[N][K] bf16 -> C[M][N] ------------------------
template <typename OUTT>
__global__ __launch_bounds__(256) void gemm_bt(
    const u16* __restrict__ A, const u16* __restrict__ Bt,
    OUTT* __restrict__ C, int M, int N, int K) {
  __shared__ u16 lA[128 * 32];
  __shared__ u16 lB[128 * 32];
  const int m0 = blockIdx.y * 128, n0 = blockIdx.x * 128;
  const int tid = threadIdx.x;
  const int w = tid >> 6, lane = tid & 63;
  const int wr = (w >> 1) * 64, wc = (w & 1) * 64;
  const int lr = lane & 15, lk = (lane >> 4) * 8;
  const int r0 = tid >> 2, c0 = (tid & 3) * 8;
  const int r1 = r0 + 64;
  f32x4 acc[4][4] = {};
  for (int k0 = 0; k0 < K; k0 += 32) {
    __syncthreads();
    *reinterpret_cast<u16x8*>(&lA[r0 * 32 + c0]) =
        *reinterpret_cast<const u16x8*>(&A[(size_t)(m0 + r0) * K + k0 + c0]);
    *reinterpret_cast<u16x8*>(&lA[r1 * 32 + c0]) =
        *reinterpret_cast<const u16x8*>(&A[(size_t)(m0 + r1) * K + k0 + c0]);
    *reinterpret_cast<u16x8*>(&lB[r0 * 32 + c0]) =
        *reinterpret_cast<const u16x8*>(&Bt[(size_t)(n0 + r0) * K + k0 + c0]);
    *reinterpret_cast<u16x8*>(&lB[r1 * 32 + c0]) =
        *reinterpret_cast<const u16x8*>(&Bt[(size_t)(n0 + r1) * K + k0 + c0]);
    __syncthreads();
    bf16x8 af[4], bfv[4];
#pragma unroll
    for (int m = 0; m < 4; m++)
      af[m] = *reinterpret_cast<const bf16x8*>(&lA[(wr + m * 16 + lr) * 32 + lk]);
#pragma unroll
    for (int n = 0; n < 4; n++)
      bfv[n] = *reinterpret_cast<const bf16x8*>(&lB[(wc + n * 16 + lr) * 32 + lk]);
#pragma unroll
    for (int m = 0; m < 4; m++)
#pragma unroll
      for (int n = 0; n < 4; n++)
        acc[m][n] = mfma16(af[m], bfv[n], acc[m][n]);
  }
  const int rr = (lane >> 4) * 4, cc = lane & 15;
#pragma unroll
  for (int m = 0; m < 4; m++) {
#pragma unroll
    for (int r = 0; r < 4; r++) {
      int row = m0 + wr + m * 16 + rr + r;
#pragma unroll
      for (int n = 0; n < 4; n++) {
        int col = n0 + wc + n * 16 + cc;
        float v = acc[m][n][r];
        if constexpr (std::is_same<OUTT, float>::value)
          C[(size_t)row * N + col] = v;
        else
          C[(size_t)row * N + col] = f2bf(v);
      }
    }
  }
}

// ---- stage 3: reorg Q/K compact, V transpose -----------------------------
__global__ void reorg_qk(const u16* __restrict__ qkv, u16* __restrict__ Qc,
                         u16* __restrict__ Kc) {
  int idx = blockIdx.x * 256 + threadIdx.x;
  int d8 = (idx & 7) * 8;
  int t = idx >> 3;
  int l = t & (Ls - 1); t >>= 11;
  int hh = t % 20, b = t / 20;
  int srccol = (hh < 16 ? hh * 64 : 1024 + (hh - 16) * 64) + d8;
  u16x8 v = *reinterpret_cast<const u16x8*>(
      &qkv[(size_t)(b * Ls + l) * NQKV + srccol]);
  u16* dst = (hh < 16)
                 ? &Qc[((size_t)(b * Hh + hh) * Ls + l) * HD + d8]
                 : &Kc[((size_t)(b * KVh + (hh - 16)) * Ls + l) * HD + d8];
  *reinterpret_cast<u16x8*>(dst) = v;
}

// Vt[b][kv][d][l] = V[b][l][kv][d]
__global__ void trans_v(const u16* __restrict__ qkv, u16* __restrict__ Vt) {
  __shared__ u16 tile[64][72];
  int l0 = blockIdx.x * 64;
  int bk = blockIdx.y;
  int b = bk >> 2, kv = bk & 3;
  int tid = threadIdx.x;
  for (int i = tid; i < 512; i += 256) {
    int l = i >> 3, d8 = (i & 7) * 8;
    u16x8 v = *reinterpret_cast<const u16x8*>(
        &qkv[(size_t)(b * Ls + l0 + l) * NQKV + 1280 + kv * 64 + d8]);
    *reinterpret_cast<u16x8*>(&tile[l][d8]) = v;
  }
  __syncthreads();
  for (int i = tid; i < 512; i += 256) {
    int d = i >> 3, l8 = (i & 7) * 8;
    u16x8 tv;
#pragma unroll
    for (int j = 0; j < 8; j++) tv[j] = tile[l8 + j][d];
    *reinterpret_cast<u16x8*>(&Vt[((size_t)bk * HD + d) * Ls + l0 + l8]) = tv;
  }
}

// ---- stage 4: flash attention, swapped-operand 32x32 ---------------------
// One wave per block; wave owns 32 q-rows. Lane owns q = qw + (lane&31);
// hi = lane>>5 selects which 16-of-32 score regs this lane holds.
// QK: mfma(A=K, B=Q) -> scores[key(regs)][q(lane)]
// PV: mfma(A=Vt, B=P) -> O^T[d(regs)][q(lane)] ; m/l/fac stay lane-local.
__global__ __launch_bounds__(64) void attn(
    const u16* __restrict__ Qc, const u16* __restrict__ Kc,
    const u16* __restrict__ Vt, const int* __restrict__ sst,
    u16* __restrict__ Obuf) {
  const int qt = blockIdx.x, h = blockIdx.y, b = blockIdx.z;
  const int kvh = h >> 2;
  const int lane = threadIdx.x;
  const int qi = lane & 31, hi = lane >> 5;
  const int qw = qt * 32;
  const int q = qw + qi;
  const float slope = exp2f(-0.5f * (float)(h + 1));
  const float SL = slope * LOG2E;          // alibi slope in log2 domain
  const float SL32 = 32.f * SL;
  const float Cs = 0.125f * LOG2E;         // SCALE * log2(e)
  const u16* Qb = Qc + (size_t)(b * Hh + h) * Ls * HD;
  const u16* Kb = Kc + (size_t)(b * KVh + kvh) * Ls * HD;
  const u16* Vb = Vt + (size_t)(b * KVh + kvh) * HD * Ls;

  bf16x8 qf[4];
#pragma unroll
  for (int c = 0; c < 4; c++)
    qf[c] = *reinterpret_cast<const bf16x8*>(&Qb[q * HD + c * 16 + hi * 8]);

  const int start = sst[b * Ls + q];
  const int start_min = __shfl(start, 0);
  const int start_max = __shfl(start, 31);
  const int k_begin = start_min & ~31;

  float m_run = -1e30f, l_run = 0.f;
  f32x16 olo = {}, ohi = {};
  float dj[16];                            // (j - q) * SL per score reg
#pragma unroll
  for (int r = 0; r < 16; r++) {
    int krow = (r & 3) + 8 * (r >> 2) + 4 * hi;
    dj[r] = (float)(k_begin + krow - q) * SL;
  }

  for (int k0 = k_begin; k0 <= qw; k0 += 32) {
    // QK^T (swapped): 4 hd-chunks
    f32x16 acc = {};
#pragma unroll
    for (int c = 0; c < 4; c++) {
      bf16x8 kf = *reinterpret_cast<const bf16x8*>(
          &Kb[(size_t)(k0 + qi) * HD + c * 16 + hi * 8]);
      acc = mfma32(kf, qf[c], acc);
    }
    float t[16];
#pragma unroll
    for (int r = 0; r < 16; r++) t[r] = fmaf(acc[r], Cs, dj[r]);
    bool clean = (k0 >= start_max) && (k0 + 31 <= qw);
    if (!clean) {
#pragma unroll
      for (int r = 0; r < 16; r++) {
        int j = k0 + (r & 3) + 8 * (r >> 2) + 4 * hi;
        t[r] = (j >= start && j <= q) ? t[r] : -3.0e38f;
      }
    }
#pragma unroll
    for (int r = 0; r < 16; r++) dj[r] += SL32;

    // row max: in-lane tree + 1 cross-half shuffle
    float mt = fmaxf(t[0], t[1]);
#pragma unroll
    for (int r = 2; r < 16; r++) mt = fmaxf(mt, t[r]);
    mt = fmaxf(mt, __shfl_xor(mt, 32));
    if (!__all(mt <= m_run + 8.f)) {       // defer-max (THR=8)
      float m_new = fmaxf(m_run, mt);
      float fac = exp2f(m_run - m_new);
      m_run = m_new;
      l_run *= fac;
#pragma unroll
      for (int r = 0; r < 16; r++) { olo[r] *= fac; ohi[r] *= fac; }
    }
    float p[16];
#pragma unroll
    for (int r = 0; r < 16; r++) p[r] = exp2f(t[r] - m_run);
    float ts = 0.f;
#pragma unroll
    for (int r = 0; r < 16; r++) ts += p[r];
    l_run += ts + __shfl_xor(ts, 32);

    // pack P -> bf16 pairs; redistribute across hi-halves to B-frag layout
    u32 pk[8], sw[8];
#pragma unroll
    for (int i = 0; i < 8; i++)
      pk[i] = (u32)f2bf(p[2 * i]) | ((u32)f2bf(p[2 * i + 1]) << 16);
#pragma unroll
    for (int i = 0; i < 8; i++) sw[i] = __shfl_xor(pk[i], 32);
    u32x4 f0 = { hi ? sw[2] : pk[0], hi ? sw[3] : pk[1],
                 hi ? pk[2] : sw[0], hi ? pk[3] : sw[1] };
    u32x4 f1 = { hi ? sw[6] : pk[4], hi ? sw[7] : pk[5],
                 hi ? pk[6] : sw[4], hi ? pk[7] : sw[5] };
    bf16x8 pf0 = __builtin_bit_cast(bf16x8, f0);
    bf16x8 pf1 = __builtin_bit_cast(bf16x8, f1);

    // PV (swapped): O^T accumulate, d in regs, q per-lane
    {
      const u16* vb0 = &Vb[(size_t)qi * Ls + k0 + hi * 8];
      const u16* vb1 = &Vb[(size_t)(32 + qi) * Ls + k0 + hi * 8];
      bf16x8 v00 = *reinterpret_cast<const bf16x8*>(vb0);
      bf16x8 v01 = *reinterpret_cast<const bf16x8*>(vb0 + 16);
      bf16x8 v10 = *reinterpret_cast<const bf16x8*>(vb1);
      bf16x8 v11 = *reinterpret_cast<const bf16x8*>(vb1 + 16);
      olo = mfma32(v00, pf0, olo);
      olo = mfma32(v01, pf1, olo);
      ohi = mfma32(v10, pf0, ohi);
      ohi = mfma32(v11, pf1, ohi);
    }
  }

  const float inv = 1.f / l_run;
  const size_t orow = (size_t)(b * Ls + q) * 1024 + h * 64;
#pragma unroll
  for (int g = 0; g < 4; g++) {
    int d0 = g * 8 + hi * 4;
    ushort4 pa, pb;
    pa.x = f2bf(olo[4 * g + 0] * inv); pa.y = f2bf(olo[4 * g + 1] * inv);
    pa.z = f2bf(olo[4 * g + 2] * inv); pa.w = f2bf(olo[4 * g + 3] * inv);
    pb.x = f2bf(ohi[4 * g + 0] * inv); pb.y = f2bf(ohi[4 * g + 1] * inv);
    pb.z = f2bf(ohi[4 * g + 2] * inv); pb.w = f2bf(ohi[4 * g + 3] * inv);
    *reinterpret_cast<ushort4*>(&Obuf[orow + d0]) = pa;
    *reinterpret_cast<ushort4*>(&Obuf[orow + 32 + d0]) = pb;
  }
}

// ---- launch ---------------------------------------------------------------
extern "C" void kernel_launch(void* const* d_in, const int* in_sizes, int n_in,
                              void* d_out, int out_size, void* d_ws, size_t ws_size,
                              hipStream_t stream) {
  const float* hs = (const float*)d_in[0];
  const int* seg = (const int*)d_in[1];
  const float* Wq = (const float*)d_in[2];
  const float* Wk = (const float*)d_in[3];
  const float* Wv = (const float*)d_in[4];
  const float* Wo = (const float*)d_in[5];
  float* out = (float*)d_out;
  char* ws = (char*)d_ws;
  u16* hsb   = (u16*)(ws);
  u16* wqkvT = (u16*)(ws + 8388608);
  u16* woT   = (u16*)(ws + 11534336);
  u16* qkvb  = (u16*)(ws + 13631488);
  u16* qc    = (u16*)(ws + 26214400);
  u16* kc    = (u16*)(ws + 34603008);
  u16* vt    = (u16*)(ws + 36700160);
  int* sst   = (int*)(ws + 38797312);
  u16* obuf  = hsb;   // hsb dead after GEMM1

  cvt_hs<<<dim3(4096), dim3(256), 0, stream>>>(hs, hsb);
  cvt_wt<<<dim3(4096), dim3(256), 0, stream>>>(Wq, wqkvT, 1024, 0);
  cvt_wt<<<dim3(1024), dim3(256), 0, stream>>>(Wk, wqkvT, 256, 1024);
  cvt_wt<<<dim3(1024), dim3(256), 0, stream>>>(Wv, wqkvT, 256, 1280);
  cvt_wt<<<dim3(4096), dim3(256), 0, stream>>>(Wo, woT, 1024, 0);
  seg_start<<<dim3(8, 2), dim3(256), 0, stream>>>(seg, sst);
  gemm_bt<u16><<<dim3(12, 32), dim3(256), 0, stream>>>(hsb, wqkvT, qkvb,
                                                       4096, 1536, 1024);
  reorg_qk<<<dim3(2560), dim3(256), 0, stream>>>(qkvb, qc, kc);
  trans_v<<<dim3(32, 8), dim3(256), 0, stream>>>(qkvb, vt);
  attn<<<dim3(64, 16, 2), dim3(64), 0, stream>>>(qc, kc, vt, sst, obuf);
  gemm_bt<float><<<dim3(8, 32), dim3(256), 0, stream>>>(obuf, woT, out,
                                                        4096, 1024, 1024);
}

// Round 3
// 134.645 us; speedup vs baseline: 2.4219x; 1.0563x over previous
//
#include <hip/hip_runtime.h>
#include <hip/hip_bf16.h>
#include <type_traits>

#define DI __device__ __forceinline__

typedef unsigned short u16;
typedef unsigned int u32;
typedef __bf16 bf16x8 __attribute__((ext_vector_type(8)));
typedef u16 u16x8 __attribute__((ext_vector_type(8)));
typedef float f32x4 __attribute__((ext_vector_type(4)));
typedef float f32x16 __attribute__((ext_vector_type(16)));
typedef u32 u32x4 __attribute__((ext_vector_type(4)));

constexpr int Bb = 2, Ls = 2048, Hh = 16, KVh = 4, HD = 64;
constexpr int NQKV = 1536;
constexpr float LOG2E = 1.44269504088896f;

DI u16 f2bf(float f) {
  __hip_bfloat16 h = __float2bfloat16(f);
  return __builtin_bit_cast(u16, h);
}

DI f32x4 mfma16(bf16x8 a, bf16x8 b, f32x4 c) {
  return __builtin_amdgcn_mfma_f32_16x16x32_bf16(a, b, c, 0, 0, 0);
}
DI f32x16 mfma32(bf16x8 a, bf16x8 b, f32x16 c) {
  return __builtin_amdgcn_mfma_f32_32x32x16_bf16(a, b, c, 0, 0, 0);
}

// async global->LDS, 16B per lane; LDS dest = wave-uniform base + lane*16
DI void gld16(const u16* g, u16* l) {
  __builtin_amdgcn_global_load_lds(
      (const __attribute__((address_space(1))) u32*)g,
      (__attribute__((address_space(3))) u32*)l, 16, 0, 0);
}

// ---- stage 1: conversions ------------------------------------------------
__global__ void cvt_hs(const float* __restrict__ in, u16* __restrict__ out) {
  int i = blockIdx.x * 256 + threadIdx.x;
  float4 v = reinterpret_cast<const float4*>(in)[i];
  ushort4 o;
  o.x = f2bf(v.x); o.y = f2bf(v.y); o.z = f2bf(v.z); o.w = f2bf(v.w);
  reinterpret_cast<ushort4*>(out)[i] = o;
}

// in: f32 [1024][N] -> out bf16 [N][1024] at row offset rowoff (tiled transpose)
__global__ void cvt_wt(const float* __restrict__ in, u16* __restrict__ out,
                       int N, int rowoff) {
  __shared__ u16 t[32][33];
  int k0 = blockIdx.y * 32, n0 = blockIdx.x * 32;
  int tx = threadIdx.x & 31, ty = threadIdx.x >> 5;   // 256 thr: ty 0..7
#pragma unroll
  for (int i = ty; i < 32; i += 8)
    t[i][tx] = f2bf(in[(size_t)(k0 + i) * N + n0 + tx]);
  __syncthreads();
#pragma unroll
  for (int i = ty; i < 32; i += 8)
    out[(size_t)(rowoff + n0 + i) * 1024 + k0 + tx] = t[tx][i];
}

// segment start per row: segments are sorted -> contiguous ranges
__global__ void seg_start(const int* __restrict__ seg, int* __restrict__ sst) {
  int b = blockIdx.y;
  int l = blockIdx.x * 256 + threadIdx.x;
  const int* s = seg + b * Ls;
  int v = s[l];
  int lo = 0, hi = l;
  while (lo < hi) {
    int mid = (lo + hi) >> 1;
    if (s[mid] < v) lo = mid + 1; else hi = mid;
  }
  sst[b * Ls + l] = lo;
}

// ---- GEMM: A[M][K] bf16 * Bt[N][K] bf16 -> C[M][N] ------------------------
template <typename OUTT>
__global__ __launch_bounds__(256) void gemm_bt(
    const u16* __restrict__ A, const u16* __restrict__ Bt,
    OUTT* __restrict__ C, int M, int N, int K) {
  __shared__ u16 lA[128 * 32];
  __shared__ u16 lB[128 * 32];
  const int m0 = blockIdx.y * 128, n0 = blockIdx.x * 128;
  const int tid = threadIdx.x;
  const int w = tid >> 6, lane = tid & 63;
  const int wr = (w >> 1) * 64, wc = (w & 1) * 64;
  const int lr = lane & 15, lk = (lane >> 4) * 8;
  const int r0 = tid >> 2, c0 = (tid & 3) * 8;
  const int r1 = r0 + 64;
  // staging: thread tid -> LDS bytes [tid*16, tid*16+16): linear per wave
  u16* dA0 = (u16*)((char*)lA + ((tid & 192) << 4));
  u16* dA1 = (u16*)((char*)lA + 4096 + ((tid & 192) << 4));
  u16* dB0 = (u16*)((char*)lB + ((tid & 192) << 4));
  u16* dB1 = (u16*)((char*)lB + 4096 + ((tid & 192) << 4));
  const u16* pA0 = &A[(size_t)(m0 + r0) * K + c0];
  const u16* pA1 = &A[(size_t)(m0 + r1) * K + c0];
  const u16* pB0 = &Bt[(size_t)(n0 + r0) * K + c0];
  const u16* pB1 = &Bt[(size_t)(n0 + r1) * K + c0];
  f32x4 acc[4][4] = {};
  for (int k0 = 0; k0 < K; k0 += 32) {
    __syncthreads();
    gld16(pA0 + k0, dA0);
    gld16(pA1 + k0, dA1);
    gld16(pB0 + k0, dB0);
    gld16(pB1 + k0, dB1);
    __syncthreads();
    bf16x8 af[4], bfv[4];
#pragma unroll
    for (int m = 0; m < 4; m++)
      af[m] = *reinterpret_cast<const bf16x8*>(&lA[(wr + m * 16 + lr) * 32 + lk]);
#pragma unroll
    for (int n = 0; n < 4; n++)
      bfv[n] = *reinterpret_cast<const bf16x8*>(&lB[(wc + n * 16 + lr) * 32 + lk]);
#pragma unroll
    for (int m = 0; m < 4; m++)
#pragma unroll
      for (int n = 0; n < 4; n++)
        acc[m][n] = mfma16(af[m], bfv[n], acc[m][n]);
  }
  const int rr = (lane >> 4) * 4, cc = lane & 15;
#pragma unroll
  for (int m = 0; m < 4; m++) {
#pragma unroll
    for (int r = 0; r < 4; r++) {
      int row = m0 + wr + m * 16 + rr + r;
#pragma unroll
      for (int n = 0; n < 4; n++) {
        int col = n0 + wc + n * 16 + cc;
        float v = acc[m][n][r];
        if constexpr (std::is_same<OUTT, float>::value)
          C[(size_t)row * N + col] = v;
        else
          C[(size_t)row * N + col] = f2bf(v);
      }
    }
  }
}

// ---- stage 3: reorg Q/K compact, V transpose -----------------------------
__global__ void reorg_qk(const u16* __restrict__ qkv, u16* __restrict__ Qc,
                         u16* __restrict__ Kc) {
  int idx = blockIdx.x * 256 + threadIdx.x;
  int d8 = (idx & 7) * 8;
  int t = idx >> 3;
  int l = t & (Ls - 1); t >>= 11;
  int hh = t % 20, b = t / 20;
  int srccol = (hh < 16 ? hh * 64 : 1024 + (hh - 16) * 64) + d8;
  u16x8 v = *reinterpret_cast<const u16x8*>(
      &qkv[(size_t)(b * Ls + l) * NQKV + srccol]);
  u16* dst = (hh < 16)
                 ? &Qc[((size_t)(b * Hh + hh) * Ls + l) * HD + d8]
                 : &Kc[((size_t)(b * KVh + (hh - 16)) * Ls + l) * HD + d8];
  *reinterpret_cast<u16x8*>(dst) = v;
}

// Vt[b][kv][d][l] = V[b][l][kv][d]
__global__ void trans_v(const u16* __restrict__ qkv, u16* __restrict__ Vt) {
  __shared__ u16 tile[64][72];
  int l0 = blockIdx.x * 64;
  int bk = blockIdx.y;
  int b = bk >> 2, kv = bk & 3;
  int tid = threadIdx.x;
  for (int i = tid; i < 512; i += 256) {
    int l = i >> 3, d8 = (i & 7) * 8;
    u16x8 v = *reinterpret_cast<const u16x8*>(
        &qkv[(size_t)(b * Ls + l0 + l) * NQKV + 1280 + kv * 64 + d8]);
    *reinterpret_cast<u16x8*>(&tile[l][d8]) = v;
  }
  __syncthreads();
  for (int i = tid; i < 512; i += 256) {
    int d = i >> 3, l8 = (i & 7) * 8;
    u16x8 tv;
#pragma unroll
    for (int j = 0; j < 8; j++) tv[j] = tile[l8 + j][d];
    *reinterpret_cast<u16x8*>(&Vt[((size_t)bk * HD + d) * Ls + l0 + l8]) = tv;
  }
}

// ---- stage 4: flash attention, swapped-operand 32x32, 4-wave split-KV ----
// Block = 4 waves over same 32 q-rows; wave w takes key tiles k_begin+32w,
// stride 128. Each wave runs independent online softmax; LDS merge at end.
__global__ __launch_bounds__(256) void attn(
    const u16* __restrict__ Qc, const u16* __restrict__ Kc,
    const u16* __restrict__ Vt, const int* __restrict__ sst,
    u16* __restrict__ Obuf) {
  const int qt = blockIdx.x, h = blockIdx.y, b = blockIdx.z;
  const int kvh = h >> 2;
  const int tid = threadIdx.x;
  const int w = tid >> 6, lane = tid & 63;
  const int qi = lane & 31, hi = lane >> 5;
  const int qw = qt * 32;
  const int q = qw + qi;
  const float slope = exp2f(-0.5f * (float)(h + 1));
  const float SL = slope * LOG2E;
  const float SL128 = 128.f * SL;
  const float Cs = 0.125f * LOG2E;
  const u16* Qb = Qc + (size_t)(b * Hh + h) * Ls * HD;
  const u16* Kb = Kc + (size_t)(b * KVh + kvh) * Ls * HD;
  const u16* Vb = Vt + (size_t)(b * KVh + kvh) * HD * Ls;

  __shared__ float lm[3][2][64];
  __shared__ float lo[3][64][33];

  bf16x8 qf[4];
#pragma unroll
  for (int c = 0; c < 4; c++)
    qf[c] = *reinterpret_cast<const bf16x8*>(&Qb[q * HD + c * 16 + hi * 8]);

  const int start = sst[b * Ls + q];
  const int start_min = __shfl(start, 0);
  const int start_max = __shfl(start, 31);
  const int k_begin = start_min & ~31;

  float m_run = -1e30f, l_run = 0.f;
  f32x16 olo = {}, ohi = {};
  float dj[16];
#pragma unroll
  for (int r = 0; r < 16; r++) {
    int krow = (r & 3) + 8 * (r >> 2) + 4 * hi;
    dj[r] = (float)(k_begin + 32 * w + krow - q) * SL;
  }

  for (int k0 = k_begin + 32 * w; k0 <= qw; k0 += 128) {
    f32x16 acc = {};
#pragma unroll
    for (int c = 0; c < 4; c++) {
      bf16x8 kf = *reinterpret_cast<const bf16x8*>(
          &Kb[(size_t)(k0 + qi) * HD + c * 16 + hi * 8]);
      acc = mfma32(kf, qf[c], acc);
    }
    float t[16];
#pragma unroll
    for (int r = 0; r < 16; r++) t[r] = fmaf(acc[r], Cs, dj[r]);
    bool clean = (k0 >= start_max) && (k0 + 31 <= qw);
    if (!clean) {
#pragma unroll
      for (int r = 0; r < 16; r++) {
        int j = k0 + (r & 3) + 8 * (r >> 2) + 4 * hi;
        t[r] = (j >= start && j <= q) ? t[r] : -3.0e38f;
      }
    }
#pragma unroll
    for (int r = 0; r < 16; r++) dj[r] += SL128;

    float mt = fmaxf(t[0], t[1]);
#pragma unroll
    for (int r = 2; r < 16; r++) mt = fmaxf(mt, t[r]);
    mt = fmaxf(mt, __shfl_xor(mt, 32));
    if (!__all(mt <= m_run + 8.f)) {       // defer-max (THR=8)
      float m_new = fmaxf(m_run, mt);
      float fac = exp2f(m_run - m_new);
      m_run = m_new;
      l_run *= fac;
#pragma unroll
      for (int r = 0; r < 16; r++) { olo[r] *= fac; ohi[r] *= fac; }
    }
    float p[16];
#pragma unroll
    for (int r = 0; r < 16; r++) p[r] = exp2f(t[r] - m_run);
    float ts = 0.f;
#pragma unroll
    for (int r = 0; r < 16; r++) ts += p[r];
    l_run += ts + __shfl_xor(ts, 32);

    u32 pk[8], sw[8];
#pragma unroll
    for (int i = 0; i < 8; i++)
      pk[i] = (u32)f2bf(p[2 * i]) | ((u32)f2bf(p[2 * i + 1]) << 16);
#pragma unroll
    for (int i = 0; i < 8; i++) sw[i] = __shfl_xor(pk[i], 32);
    u32x4 f0 = { hi ? sw[2] : pk[0], hi ? sw[3] : pk[1],
                 hi ? pk[2] : sw[0], hi ? pk[3] : sw[1] };
    u32x4 f1 = { hi ? sw[6] : pk[4], hi ? sw[7] : pk[5],
                 hi ? pk[6] : sw[4], hi ? pk[7] : sw[5] };
    bf16x8 pf0 = __builtin_bit_cast(bf16x8, f0);
    bf16x8 pf1 = __builtin_bit_cast(bf16x8, f1);

    {
      const u16* vb0 = &Vb[(size_t)qi * Ls + k0 + hi * 8];
      const u16* vb1 = &Vb[(size_t)(32 + qi) * Ls + k0 + hi * 8];
      bf16x8 v00 = *reinterpret_cast<const bf16x8*>(vb0);
      bf16x8 v01 = *reinterpret_cast<const bf16x8*>(vb0 + 16);
      bf16x8 v10 = *reinterpret_cast<const bf16x8*>(vb1);
      bf16x8 v11 = *reinterpret_cast<const bf16x8*>(vb1 + 16);
      olo = mfma32(v00, pf0, olo);
      olo = mfma32(v01, pf1, olo);
      ohi = mfma32(v10, pf0, ohi);
      ohi = mfma32(v11, pf1, ohi);
    }
  }

  // ---- cross-wave merge: waves 1-3 publish, wave 0 merges + stores ----
  if (w) {
    int wi = w - 1;
    lm[wi][0][lane] = m_run;
    lm[wi][1][lane] = l_run;
#pragma unroll
    for (int r = 0; r < 16; r++) {
      lo[wi][lane][r] = olo[r];
      lo[wi][lane][16 + r] = ohi[r];
    }
  }
  __syncthreads();
  if (w) return;

  float mw[3], lw[3];
  float M = m_run;
#pragma unroll
  for (int wi = 0; wi < 3; wi++) {
    mw[wi] = lm[wi][0][lane];
    lw[wi] = lm[wi][1][lane];
    M = fmaxf(M, mw[wi]);
  }
  float f0s = exp2f(m_run - M);
  float L = l_run * f0s;
#pragma unroll
  for (int r = 0; r < 16; r++) { olo[r] *= f0s; ohi[r] *= f0s; }
#pragma unroll
  for (int wi = 0; wi < 3; wi++) {
    float fw = exp2f(mw[wi] - M);
    L += lw[wi] * fw;
#pragma unroll
    for (int r = 0; r < 16; r++) {
      olo[r] += lo[wi][lane][r] * fw;
      ohi[r] += lo[wi][lane][16 + r] * fw;
    }
  }

  const float inv = 1.f / L;
  const size_t orow = (size_t)(b * Ls + q) * 1024 + h * 64;
#pragma unroll
  for (int g = 0; g < 4; g++) {
    int d0 = g * 8 + hi * 4;
    ushort4 pa, pb;
    pa.x = f2bf(olo[4 * g + 0] * inv); pa.y = f2bf(olo[4 * g + 1] * inv);
    pa.z = f2bf(olo[4 * g + 2] * inv); pa.w = f2bf(olo[4 * g + 3] * inv);
    pb.x = f2bf(ohi[4 * g + 0] * inv); pb.y = f2bf(ohi[4 * g + 1] * inv);
    pb.z = f2bf(ohi[4 * g + 2] * inv); pb.w = f2bf(ohi[4 * g + 3] * inv);
    *reinterpret_cast<ushort4*>(&Obuf[orow + d0]) = pa;
    *reinterpret_cast<ushort4*>(&Obuf[orow + 32 + d0]) = pb;
  }
}

// ---- launch ---------------------------------------------------------------
extern "C" void kernel_launch(void* const* d_in, const int* in_sizes, int n_in,
                              void* d_out, int out_size, void* d_ws, size_t ws_size,
                              hipStream_t stream) {
  const float* hs = (const float*)d_in[0];
  const int* seg = (const int*)d_in[1];
  const float* Wq = (const float*)d_in[2];
  const float* Wk = (const float*)d_in[3];
  const float* Wv = (const float*)d_in[4];
  const float* Wo = (const float*)d_in[5];
  float* out = (float*)d_out;
  char* ws = (char*)d_ws;
  u16* hsb   = (u16*)(ws);
  u16* wqkvT = (u16*)(ws + 8388608);
  u16* woT   = (u16*)(ws + 11534336);
  u16* qkvb  = (u16*)(ws + 13631488);
  u16* qc    = (u16*)(ws + 26214400);
  u16* kc    = (u16*)(ws + 34603008);
  u16* vt    = (u16*)(ws + 36700160);
  int* sst   = (int*)(ws + 38797312);
  u16* obuf  = hsb;   // hsb dead after GEMM1

  cvt_hs<<<dim3(4096), dim3(256), 0, stream>>>(hs, hsb);
  cvt_wt<<<dim3(32, 32), dim3(256), 0, stream>>>(Wq, wqkvT, 1024, 0);
  cvt_wt<<<dim3(8, 32), dim3(256), 0, stream>>>(Wk, wqkvT, 256, 1024);
  cvt_wt<<<dim3(8, 32), dim3(256), 0, stream>>>(Wv, wqkvT, 256, 1280);
  cvt_wt<<<dim3(32, 32), dim3(256), 0, stream>>>(Wo, woT, 1024, 0);
  seg_start<<<dim3(8, 2), dim3(256), 0, stream>>>(seg, sst);
  gemm_bt<u16><<<dim3(12, 32), dim3(256), 0, stream>>>(hsb, wqkvT, qkvb,
                                                       4096, 1536, 1024);
  reorg_qk<<<dim3(2560), dim3(256), 0, stream>>>(qkvb, qc, kc);
  trans_v<<<dim3(32, 8), dim3(256), 0, stream>>>(qkvb, vt);
  attn<<<dim3(64, 16, 2), dim3(256), 0, stream>>>(qc, kc, vt, sst, obuf);
  gemm_bt<float><<<dim3(8, 32), dim3(256), 0, stream>>>(obuf, woT, out,
                                                        4096, 1024, 1024);
}

// Round 4
// 126.856 us; speedup vs baseline: 2.5706x; 1.0614x over previous
//
#include <hip/hip_runtime.h>
#include <hip/hip_bf16.h>
#include <type_traits>

#define DI __device__ __forceinline__

typedef unsigned short u16;
typedef unsigned int u32;
typedef __bf16 bf16x8 __attribute__((ext_vector_type(8)));
typedef u16 u16x8 __attribute__((ext_vector_type(8)));
typedef float f32x4 __attribute__((ext_vector_type(4)));
typedef float f32x16 __attribute__((ext_vector_type(16)));
typedef u32 u32x2 __attribute__((ext_vector_type(2)));
typedef u32 u32x4 __attribute__((ext_vector_type(4)));

constexpr int Bb = 2, Ls = 2048, Hh = 16, KVh = 4, HD = 64;
constexpr float LOG2E = 1.44269504088896f;

DI u16 f2bf(float f) {
  __hip_bfloat16 h = __float2bfloat16(f);
  return __builtin_bit_cast(u16, h);
}

// packed f32x2 -> bf16x2 (RNE), single VOP3 op
DI u32 cvtpk(float lo, float hi) {
  u32 r;
  asm("v_cvt_pk_bf16_f32 %0, %1, %2" : "=v"(r) : "v"(lo), "v"(hi));
  return r;
}

DI f32x4 mfma16(bf16x8 a, bf16x8 b, f32x4 c) {
  return __builtin_amdgcn_mfma_f32_16x16x32_bf16(a, b, c, 0, 0, 0);
}
DI f32x16 mfma32(bf16x8 a, bf16x8 b, f32x16 c) {
  return __builtin_amdgcn_mfma_f32_32x32x16_bf16(a, b, c, 0, 0, 0);
}

// async global->LDS, 16B per lane; LDS dest = wave-uniform base + lane*16
DI void gld16(const u16* g, u16* l) {
  __builtin_amdgcn_global_load_lds(
      (const __attribute__((address_space(1))) u32*)g,
      (__attribute__((address_space(3))) u32*)l, 16, 0, 0);
}

// ---- stage 1: conversions ------------------------------------------------
__global__ void cvt_hs(const float* __restrict__ in, u16* __restrict__ out) {
  int i = blockIdx.x * 256 + threadIdx.x;
  float4 v = reinterpret_cast<const float4*>(in)[i];
  ushort4 o;
  o.x = f2bf(v.x); o.y = f2bf(v.y); o.z = f2bf(v.z); o.w = f2bf(v.w);
  reinterpret_cast<ushort4*>(out)[i] = o;
}

// in: f32 [1024][N] -> out bf16 [N][1024] at row offset rowoff (tiled transpose)
__global__ void cvt_wt(const float* __restrict__ in, u16* __restrict__ out,
                       int N, int rowoff) {
  __shared__ u16 t[32][33];
  int k0 = blockIdx.y * 32, n0 = blockIdx.x * 32;
  int tx = threadIdx.x & 31, ty = threadIdx.x >> 5;
#pragma unroll
  for (int i = ty; i < 32; i += 8)
    t[i][tx] = f2bf(in[(size_t)(k0 + i) * N + n0 + tx]);
  __syncthreads();
#pragma unroll
  for (int i = ty; i < 32; i += 8)
    out[(size_t)(rowoff + n0 + i) * 1024 + k0 + tx] = t[tx][i];
}

// segment start per row: segments are sorted -> contiguous ranges
__global__ void seg_start(const int* __restrict__ seg, int* __restrict__ sst) {
  int b = blockIdx.y;
  int l = blockIdx.x * 256 + threadIdx.x;
  const int* s = seg + b * Ls;
  int v = s[l];
  int lo = 0, hi = l;
  while (lo < hi) {
    int mid = (lo + hi) >> 1;
    if (s[mid] < v) lo = mid + 1; else hi = mid;
  }
  sst[b * Ls + l] = lo;
}

// ---- GEMM: A[M][K] bf16 * Bt[N][K] bf16 ----------------------------------
// MODE 0: C[M][N] float.  MODE 1 (qkv): scatter bf16 into Qc/Kc/Vt layouts.
template <int MODE>
__global__ __launch_bounds__(256) void gemm_bt(
    const u16* __restrict__ A, const u16* __restrict__ Bt,
    float* __restrict__ C, u16* __restrict__ Qc, u16* __restrict__ Kc,
    u16* __restrict__ Vt, int M, int N, int K) {
  __shared__ u16 lA[128 * 32];
  __shared__ u16 lB[128 * 32];
  const int m0 = blockIdx.y * 128, n0 = blockIdx.x * 128;
  const int tid = threadIdx.x;
  const int w = tid >> 6, lane = tid & 63;
  const int wr = (w >> 1) * 64, wc = (w & 1) * 64;
  const int lr = lane & 15, lk = (lane >> 4) * 8;
  const int r0 = tid >> 2, c0 = (tid & 3) * 8;
  const int r1 = r0 + 64;
  u16* dA0 = (u16*)((char*)lA + ((tid & 192) << 4));
  u16* dA1 = (u16*)((char*)lA + 4096 + ((tid & 192) << 4));
  u16* dB0 = (u16*)((char*)lB + ((tid & 192) << 4));
  u16* dB1 = (u16*)((char*)lB + 4096 + ((tid & 192) << 4));
  const u16* pA0 = &A[(size_t)(m0 + r0) * K + c0];
  const u16* pA1 = &A[(size_t)(m0 + r1) * K + c0];
  const u16* pB0 = &Bt[(size_t)(n0 + r0) * K + c0];
  const u16* pB1 = &Bt[(size_t)(n0 + r1) * K + c0];
  f32x4 acc[4][4] = {};
  for (int k0 = 0; k0 < K; k0 += 32) {
    __syncthreads();
    gld16(pA0 + k0, dA0);
    gld16(pA1 + k0, dA1);
    gld16(pB0 + k0, dB0);
    gld16(pB1 + k0, dB1);
    __syncthreads();
    bf16x8 af[4], bfv[4];
#pragma unroll
    for (int m = 0; m < 4; m++)
      af[m] = *reinterpret_cast<const bf16x8*>(&lA[(wr + m * 16 + lr) * 32 + lk]);
#pragma unroll
    for (int n = 0; n < 4; n++)
      bfv[n] = *reinterpret_cast<const bf16x8*>(&lB[(wc + n * 16 + lr) * 32 + lk]);
#pragma unroll
    for (int m = 0; m < 4; m++)
#pragma unroll
      for (int n = 0; n < 4; n++)
        acc[m][n] = mfma16(af[m], bfv[n], acc[m][n]);
  }
  const int rr = (lane >> 4) * 4, cc = lane & 15;
#pragma unroll
  for (int m = 0; m < 4; m++) {
    int row0 = m0 + wr + m * 16 + rr;
#pragma unroll
    for (int n = 0; n < 4; n++) {
      int col = n0 + wc + n * 16 + cc;
      if constexpr (MODE == 0) {
#pragma unroll
        for (int r = 0; r < 4; r++)
          C[(size_t)(row0 + r) * N + col] = acc[m][n][r];
      } else {
        int bb = row0 >> 11, l = row0 & 2047;
        int d = col & 63;
        if (col < 1024) {
          int hd = col >> 6;
          u16* base = &Qc[((size_t)(bb * 16 + hd) * 2048 + l) * 64 + d];
#pragma unroll
          for (int r = 0; r < 4; r++) base[r * 64] = f2bf(acc[m][n][r]);
        } else if (col < 1280) {
          int kv = (col - 1024) >> 6;
          u16* base = &Kc[((size_t)(bb * 4 + kv) * 2048 + l) * 64 + d];
#pragma unroll
          for (int r = 0; r < 4; r++) base[r * 64] = f2bf(acc[m][n][r]);
        } else {
          int kv = (col - 1280) >> 6;
          ushort4 pv;
          pv.x = f2bf(acc[m][n][0]); pv.y = f2bf(acc[m][n][1]);
          pv.z = f2bf(acc[m][n][2]); pv.w = f2bf(acc[m][n][3]);
          *reinterpret_cast<ushort4*>(
              &Vt[((size_t)(bb * 4 + kv) * 64 + d) * 2048 + l]) = pv;
        }
      }
    }
  }
}

// ---- flash attention: swapped 32x32, 4-wave split-KV, reg prefetch -------
__global__ __launch_bounds__(256) void attn(
    const u16* __restrict__ Qc, const u16* __restrict__ Kc,
    const u16* __restrict__ Vt, const int* __restrict__ sst,
    u16* __restrict__ Obuf) {
  const int qt = blockIdx.x, h = blockIdx.y, b = blockIdx.z;
  const int kvh = h >> 2;
  const int tid = threadIdx.x;
  const int w = tid >> 6, lane = tid & 63;
  const int qi = lane & 31, hi = lane >> 5;
  const int qw = qt * 32;
  const int q = qw + qi;
  const float slope = __builtin_amdgcn_exp2f(-0.5f * (float)(h + 1));
  const float SL = slope * LOG2E;
  const float SL128 = 128.f * SL;
  const float Cs = 0.125f * LOG2E;
  const u16* Qb = Qc + (size_t)(b * Hh + h) * Ls * HD;
  const u16* Kb = Kc + (size_t)(b * KVh + kvh) * Ls * HD;
  const u16* Vb = Vt + (size_t)(b * KVh + kvh) * HD * Ls;

  __shared__ float lm[3][2][64];
  __shared__ float lo[3][64][33];

  bf16x8 qf[4];
#pragma unroll
  for (int c = 0; c < 4; c++)
    qf[c] = *reinterpret_cast<const bf16x8*>(&Qb[q * HD + c * 16 + hi * 8]);

  const int start = sst[b * Ls + q];
  const int start_max = __shfl(start, 31);
  const int k_begin = __shfl(start, 0) & ~31;

  float m_run = 0.f, l_run = 0.f;     // m folded into djm; defer-max THR=8
  f32x16 olo = {}, ohi = {};
  float djm[16];
#pragma unroll
  for (int r = 0; r < 16; r++) {
    int krow = (r & 3) + 8 * (r >> 2) + 4 * hi;
    djm[r] = (float)(k_begin + 32 * w + krow - q) * SL;
  }

  int k0 = k_begin + 32 * w;
  u32x4 kr[4], vr[4];
  if (k0 <= qw) {
    const u16* kb = &Kb[(size_t)(k0 + qi) * HD + hi * 8];
#pragma unroll
    for (int c = 0; c < 4; c++)
      kr[c] = *reinterpret_cast<const u32x4*>(kb + c * 16);
    const u16* vb0 = &Vb[(size_t)qi * Ls + k0 + hi * 8];
    const u16* vb1 = &Vb[(size_t)(32 + qi) * Ls + k0 + hi * 8];
    vr[0] = *reinterpret_cast<const u32x4*>(vb0);
    vr[1] = *reinterpret_cast<const u32x4*>(vb0 + 16);
    vr[2] = *reinterpret_cast<const u32x4*>(vb1);
    vr[3] = *reinterpret_cast<const u32x4*>(vb1 + 16);
  }

  for (; k0 <= qw; k0 += 128) {
    // QK^T on current K regs
    f32x16 acc = {};
#pragma unroll
    for (int c = 0; c < 4; c++)
      acc = mfma32(__builtin_bit_cast(bf16x8, kr[c]), qf[c], acc);

    // prefetch next tile's K (consumed next iteration; hidden by softmax+PV)
    const int knx = (k0 + 128 <= qw) ? k0 + 128 : k0;
    {
      const u16* kb = &Kb[(size_t)(knx + qi) * HD + hi * 8];
#pragma unroll
      for (int c = 0; c < 4; c++)
        kr[c] = *reinterpret_cast<const u32x4*>(kb + c * 16);
    }

    float t[16];
#pragma unroll
    for (int r = 0; r < 16; r++) t[r] = fmaf(acc[r], Cs, djm[r]);
    const bool clean = (k0 >= start_max) && (k0 + 31 <= qw);
    if (!clean) {
#pragma unroll
      for (int r = 0; r < 16; r++) {
        int j = k0 + (r & 3) + 8 * (r >> 2) + 4 * hi;
        t[r] = (j >= start && j <= q) ? t[r] : -3.0e38f;
      }
    }
#pragma unroll
    for (int r = 0; r < 16; r++) djm[r] += SL128;

    float mt = fmaxf(t[0], t[1]);
#pragma unroll
    for (int r = 2; r < 16; r++) mt = fmaxf(mt, t[r]);
    mt = fmaxf(mt, __shfl_xor(mt, 32));
    if (!__all(mt <= 8.f)) {                     // rare with m folded at 0
      float dm = fmaxf(mt, 0.f);
      float fac = __builtin_amdgcn_exp2f(-dm);
      m_run += dm;
      l_run *= fac;
#pragma unroll
      for (int r = 0; r < 16; r++) { olo[r] *= fac; ohi[r] *= fac; }
#pragma unroll
      for (int r = 0; r < 16; r++) { djm[r] -= dm; t[r] -= dm; }
    }
    float p[16];
#pragma unroll
    for (int r = 0; r < 16; r++) p[r] = __builtin_amdgcn_exp2f(t[r]);
    float ts = 0.f;
#pragma unroll
    for (int r = 0; r < 16; r++) ts += p[r];
    l_run += ts + __shfl_xor(ts, 32);

    // pack P to bf16 pairs; swap halves to B-frag layout
    u32 pk[8], sw[8];
#pragma unroll
    for (int i = 0; i < 8; i++) pk[i] = cvtpk(p[2 * i], p[2 * i + 1]);
#pragma unroll
    for (int i = 0; i < 8; i++) sw[i] = __shfl_xor(pk[i], 32);
    u32x4 f0 = { hi ? sw[2] : pk[0], hi ? sw[3] : pk[1],
                 hi ? pk[2] : sw[0], hi ? pk[3] : sw[1] };
    u32x4 f1 = { hi ? sw[6] : pk[4], hi ? sw[7] : pk[5],
                 hi ? pk[6] : sw[4], hi ? pk[7] : sw[5] };
    bf16x8 pf0 = __builtin_bit_cast(bf16x8, f0);
    bf16x8 pf1 = __builtin_bit_cast(bf16x8, f1);

    // PV on current V regs
    olo = mfma32(__builtin_bit_cast(bf16x8, vr[0]), pf0, olo);
    olo = mfma32(__builtin_bit_cast(bf16x8, vr[1]), pf1, olo);
    ohi = mfma32(__builtin_bit_cast(bf16x8, vr[2]), pf0, ohi);
    ohi = mfma32(__builtin_bit_cast(bf16x8, vr[3]), pf1, ohi);

    // prefetch next tile's V (consumed at next iteration's PV)
    {
      const u16* vb0 = &Vb[(size_t)qi * Ls + knx + hi * 8];
      const u16* vb1 = &Vb[(size_t)(32 + qi) * Ls + knx + hi * 8];
      vr[0] = *reinterpret_cast<const u32x4*>(vb0);
      vr[1] = *reinterpret_cast<const u32x4*>(vb0 + 16);
      vr[2] = *reinterpret_cast<const u32x4*>(vb1);
      vr[3] = *reinterpret_cast<const u32x4*>(vb1 + 16);
    }
  }

  // ---- cross-wave merge: waves 1-3 publish, wave 0 merges + stores ----
  if (w) {
    int wi = w - 1;
    lm[wi][0][lane] = m_run;
    lm[wi][1][lane] = l_run;
#pragma unroll
    for (int r = 0; r < 16; r++) {
      lo[wi][lane][r] = olo[r];
      lo[wi][lane][16 + r] = ohi[r];
    }
  }
  __syncthreads();
  if (w) return;

  float mw[3], lw[3];
  float M = m_run;
#pragma unroll
  for (int wi = 0; wi < 3; wi++) {
    mw[wi] = lm[wi][0][lane];
    lw[wi] = lm[wi][1][lane];
    M = fmaxf(M, mw[wi]);
  }
  float f0s = __builtin_amdgcn_exp2f(m_run - M);
  float L = l_run * f0s;
#pragma unroll
  for (int r = 0; r < 16; r++) { olo[r] *= f0s; ohi[r] *= f0s; }
#pragma unroll
  for (int wi = 0; wi < 3; wi++) {
    float fw = __builtin_amdgcn_exp2f(mw[wi] - M);
    L += lw[wi] * fw;
#pragma unroll
    for (int r = 0; r < 16; r++) {
      olo[r] += lo[wi][lane][r] * fw;
      ohi[r] += lo[wi][lane][16 + r] * fw;
    }
  }

  const float inv = __builtin_amdgcn_rcpf(L);
  const size_t orow = (size_t)(b * Ls + q) * 1024 + h * 64;
#pragma unroll
  for (int g = 0; g < 4; g++) {
    int d0 = g * 8 + hi * 4;
    u32x2 pa = { cvtpk(olo[4 * g + 0] * inv, olo[4 * g + 1] * inv),
                 cvtpk(olo[4 * g + 2] * inv, olo[4 * g + 3] * inv) };
    u32x2 pb = { cvtpk(ohi[4 * g + 0] * inv, ohi[4 * g + 1] * inv),
                 cvtpk(ohi[4 * g + 2] * inv, ohi[4 * g + 3] * inv) };
    *reinterpret_cast<u32x2*>(&Obuf[orow + d0]) = pa;
    *reinterpret_cast<u32x2*>(&Obuf[orow + 32 + d0]) = pb;
  }
}

// ---- launch ---------------------------------------------------------------
extern "C" void kernel_launch(void* const* d_in, const int* in_sizes, int n_in,
                              void* d_out, int out_size, void* d_ws, size_t ws_size,
                              hipStream_t stream) {
  const float* hs = (const float*)d_in[0];
  const int* seg = (const int*)d_in[1];
  const float* Wq = (const float*)d_in[2];
  const float* Wk = (const float*)d_in[3];
  const float* Wv = (const float*)d_in[4];
  const float* Wo = (const float*)d_in[5];
  float* out = (float*)d_out;
  char* ws = (char*)d_ws;
  // hsb 8.4M | wqkvT 3.1M | woT 2.1M | qc 8.4M | kc 2.1M | vt 2.1M | sst 16K
  u16* hsb   = (u16*)(ws);
  u16* wqkvT = (u16*)(ws + 8388608);
  u16* woT   = (u16*)(ws + 11534336);
  u16* qc    = (u16*)(ws + 13631488);
  u16* kc    = (u16*)(ws + 22020096);
  u16* vt    = (u16*)(ws + 24117248);
  int* sst   = (int*)(ws + 26214400);
  u16* obuf  = hsb;   // hsb dead after GEMM1

  cvt_hs<<<dim3(4096), dim3(256), 0, stream>>>(hs, hsb);
  cvt_wt<<<dim3(32, 32), dim3(256), 0, stream>>>(Wq, wqkvT, 1024, 0);
  cvt_wt<<<dim3(8, 32), dim3(256), 0, stream>>>(Wk, wqkvT, 256, 1024);
  cvt_wt<<<dim3(8, 32), dim3(256), 0, stream>>>(Wv, wqkvT, 256, 1280);
  cvt_wt<<<dim3(32, 32), dim3(256), 0, stream>>>(Wo, woT, 1024, 0);
  seg_start<<<dim3(8, 2), dim3(256), 0, stream>>>(seg, sst);
  gemm_bt<1><<<dim3(12, 32), dim3(256), 0, stream>>>(
      hsb, wqkvT, nullptr, qc, kc, vt, 4096, 1536, 1024);
  attn<<<dim3(64, 16, 2), dim3(256), 0, stream>>>(qc, kc, vt, sst, obuf);
  gemm_bt<0><<<dim3(8, 32), dim3(256), 0, stream>>>(
      obuf, woT, out, nullptr, nullptr, nullptr, 4096, 1024, 1024);
}

// Round 5
// 123.549 us; speedup vs baseline: 2.6394x; 1.0268x over previous
//
#include <hip/hip_runtime.h>
#include <hip/hip_bf16.h>
#include <type_traits>

#define DI __device__ __forceinline__

typedef unsigned short u16;
typedef unsigned int u32;
typedef __bf16 bf16x8 __attribute__((ext_vector_type(8)));
typedef u16 u16x8 __attribute__((ext_vector_type(8)));
typedef float f32x4 __attribute__((ext_vector_type(4)));
typedef float f32x16 __attribute__((ext_vector_type(16)));
typedef u32 u32x2 __attribute__((ext_vector_type(2)));
typedef u32 u32x4 __attribute__((ext_vector_type(4)));

constexpr int Bb = 2, Ls = 2048, Hh = 16, KVh = 4, HD = 64;
constexpr float LOG2E = 1.44269504088896f;

DI u16 f2bf(float f) {
  __hip_bfloat16 h = __float2bfloat16(f);
  return __builtin_bit_cast(u16, h);
}

// packed f32x2 -> bf16x2 (RNE), single VOP3 op
DI u32 cvtpk(float lo, float hi) {
  u32 r;
  asm("v_cvt_pk_bf16_f32 %0, %1, %2" : "=v"(r) : "v"(lo), "v"(hi));
  return r;
}

DI f32x4 mfma16(bf16x8 a, bf16x8 b, f32x4 c) {
  return __builtin_amdgcn_mfma_f32_16x16x32_bf16(a, b, c, 0, 0, 0);
}
DI f32x16 mfma32(bf16x8 a, bf16x8 b, f32x16 c) {
  return __builtin_amdgcn_mfma_f32_32x32x16_bf16(a, b, c, 0, 0, 0);
}
DI bf16x8 bc(u32x4 v) { return __builtin_bit_cast(bf16x8, v); }

// async global->LDS, 16B per lane; LDS dest = wave-uniform base + lane*16
DI void gld16(const u16* g, u16* l) {
  __builtin_amdgcn_global_load_lds(
      (const __attribute__((address_space(1))) u32*)g,
      (__attribute__((address_space(3))) u32*)l, 16, 0, 0);
}

// ---- stage 1: conversions ------------------------------------------------
__global__ void cvt_hs(const float* __restrict__ in, u16* __restrict__ out) {
  int i = blockIdx.x * 256 + threadIdx.x;
  float4 v = reinterpret_cast<const float4*>(in)[i];
  ushort4 o;
  o.x = f2bf(v.x); o.y = f2bf(v.y); o.z = f2bf(v.z); o.w = f2bf(v.w);
  reinterpret_cast<ushort4*>(out)[i] = o;
}

// in: f32 [1024][N] -> out bf16 [N][1024] at row offset rowoff (tiled transpose)
__global__ void cvt_wt(const float* __restrict__ in, u16* __restrict__ out,
                       int N, int rowoff) {
  __shared__ u16 t[32][33];
  int k0 = blockIdx.y * 32, n0 = blockIdx.x * 32;
  int tx = threadIdx.x & 31, ty = threadIdx.x >> 5;
#pragma unroll
  for (int i = ty; i < 32; i += 8)
    t[i][tx] = f2bf(in[(size_t)(k0 + i) * N + n0 + tx]);
  __syncthreads();
#pragma unroll
  for (int i = ty; i < 32; i += 8)
    out[(size_t)(rowoff + n0 + i) * 1024 + k0 + tx] = t[tx][i];
}

// segment start per row: segments are sorted -> contiguous ranges
__global__ void seg_start(const int* __restrict__ seg, int* __restrict__ sst) {
  int b = blockIdx.y;
  int l = blockIdx.x * 256 + threadIdx.x;
  const int* s = seg + b * Ls;
  int v = s[l];
  int lo = 0, hi = l;
  while (lo < hi) {
    int mid = (lo + hi) >> 1;
    if (s[mid] < v) lo = mid + 1; else hi = mid;
  }
  sst[b * Ls + l] = lo;
}

// ---- GEMM: A[M][K] bf16 * Bt[N][K] bf16 ----------------------------------
// MODE 0: C[M][N] float.  MODE 1 (qkv): scatter bf16 into Qc/Kc/Vt layouts.
template <int MODE>
__global__ __launch_bounds__(256) void gemm_bt(
    const u16* __restrict__ A, const u16* __restrict__ Bt,
    float* __restrict__ C, u16* __restrict__ Qc, u16* __restrict__ Kc,
    u16* __restrict__ Vt, int M, int N, int K) {
  __shared__ u16 lA[128 * 32];
  __shared__ u16 lB[128 * 32];
  const int m0 = blockIdx.y * 128, n0 = blockIdx.x * 128;
  const int tid = threadIdx.x;
  const int w = tid >> 6, lane = tid & 63;
  const int wr = (w >> 1) * 64, wc = (w & 1) * 64;
  const int lr = lane & 15, lk = (lane >> 4) * 8;
  const int r0 = tid >> 2, c0 = (tid & 3) * 8;
  const int r1 = r0 + 64;
  u16* dA0 = (u16*)((char*)lA + ((tid & 192) << 4));
  u16* dA1 = (u16*)((char*)lA + 4096 + ((tid & 192) << 4));
  u16* dB0 = (u16*)((char*)lB + ((tid & 192) << 4));
  u16* dB1 = (u16*)((char*)lB + 4096 + ((tid & 192) << 4));
  const u16* pA0 = &A[(size_t)(m0 + r0) * K + c0];
  const u16* pA1 = &A[(size_t)(m0 + r1) * K + c0];
  const u16* pB0 = &Bt[(size_t)(n0 + r0) * K + c0];
  const u16* pB1 = &Bt[(size_t)(n0 + r1) * K + c0];
  f32x4 acc[4][4] = {};
  for (int k0 = 0; k0 < K; k0 += 32) {
    __syncthreads();
    gld16(pA0 + k0, dA0);
    gld16(pA1 + k0, dA1);
    gld16(pB0 + k0, dB0);
    gld16(pB1 + k0, dB1);
    __syncthreads();
    bf16x8 af[4], bfv[4];
#pragma unroll
    for (int m = 0; m < 4; m++)
      af[m] = *reinterpret_cast<const bf16x8*>(&lA[(wr + m * 16 + lr) * 32 + lk]);
#pragma unroll
    for (int n = 0; n < 4; n++)
      bfv[n] = *reinterpret_cast<const bf16x8*>(&lB[(wc + n * 16 + lr) * 32 + lk]);
#pragma unroll
    for (int m = 0; m < 4; m++)
#pragma unroll
      for (int n = 0; n < 4; n++)
        acc[m][n] = mfma16(af[m], bfv[n], acc[m][n]);
  }
  const int rr = (lane >> 4) * 4, cc = lane & 15;
#pragma unroll
  for (int m = 0; m < 4; m++) {
    int row0 = m0 + wr + m * 16 + rr;
#pragma unroll
    for (int n = 0; n < 4; n++) {
      int col = n0 + wc + n * 16 + cc;
      if constexpr (MODE == 0) {
#pragma unroll
        for (int r = 0; r < 4; r++)
          C[(size_t)(row0 + r) * N + col] = acc[m][n][r];
      } else {
        int bb = row0 >> 11, l = row0 & 2047;
        int d = col & 63;
        if (col < 1024) {
          int hd = col >> 6;
          u16* base = &Qc[((size_t)(bb * 16 + hd) * 2048 + l) * 64 + d];
#pragma unroll
          for (int r = 0; r < 4; r++) base[r * 64] = f2bf(acc[m][n][r]);
        } else if (col < 1280) {
          int kv = (col - 1024) >> 6;
          u16* base = &Kc[((size_t)(bb * 4 + kv) * 2048 + l) * 64 + d];
#pragma unroll
          for (int r = 0; r < 4; r++) base[r * 64] = f2bf(acc[m][n][r]);
        } else {
          int kv = (col - 1280) >> 6;
          ushort4 pv;
          pv.x = f2bf(acc[m][n][0]); pv.y = f2bf(acc[m][n][1]);
          pv.z = f2bf(acc[m][n][2]); pv.w = f2bf(acc[m][n][3]);
          *reinterpret_cast<ushort4*>(
              &Vt[((size_t)(bb * 4 + kv) * 64 + d) * 2048 + l]) = pv;
        }
      }
    }
  }
}

// ---- flash attention: swapped 32x32, 1 wave per q-tile, k-unroll x2 ------
// Wave w of block x owns qt = x + 16w (stride-16 sampling balances blocks).
// Per iteration: two 32-key tiles with independent softmax chains (ILP);
// causal mask kills the overhang tile, loads clamp to qw. No LDS, no merge.
__global__ __launch_bounds__(256) void attn(
    const u16* __restrict__ Qc, const u16* __restrict__ Kc,
    const u16* __restrict__ Vt, const int* __restrict__ sst,
    u16* __restrict__ Obuf) {
  const int h = blockIdx.y, b = blockIdx.z;
  const int kvh = h >> 2;
  const int tid = threadIdx.x;
  const int w = tid >> 6, lane = tid & 63;
  const int qt = blockIdx.x + w * 16;
  const int qi = lane & 31, hi = lane >> 5;
  const int qw = qt * 32;
  const int q = qw + qi;
  const float slope = __builtin_amdgcn_exp2f(-0.5f * (float)(h + 1));
  const float SL = slope * LOG2E;
  const float SL32 = 32.f * SL, SL64 = 64.f * SL;
  const float Cs = 0.125f * LOG2E;
  const u16* Qb = Qc + (size_t)(b * Hh + h) * Ls * HD;
  const u16* Kb = Kc + (size_t)(b * KVh + kvh) * Ls * HD;
  const u16* Vb = Vt + (size_t)(b * KVh + kvh) * HD * Ls;

  bf16x8 qf[4];
#pragma unroll
  for (int c = 0; c < 4; c++)
    qf[c] = *reinterpret_cast<const bf16x8*>(&Qb[q * HD + c * 16 + hi * 8]);

  const int start = sst[b * Ls + q];
  const int start_max = __shfl(start, 31);
  const int k_begin = __shfl(start, 0) & ~31;

  float l_run = 0.f;                      // running max folded into djm
  f32x16 olo = {}, ohi = {};
  float djm[16];
#pragma unroll
  for (int r = 0; r < 16; r++) {
    int krow = (r & 3) + 8 * (r >> 2) + 4 * hi;
    djm[r] = (float)(k_begin + krow - q) * SL;
  }

  u32x4 kr[8], vr[8];
  {
    const int r1 = min(k_begin + 32, qw);
    const u16* ka = &Kb[(size_t)(k_begin + qi) * HD + hi * 8];
    const u16* kb2 = &Kb[(size_t)(r1 + qi) * HD + hi * 8];
#pragma unroll
    for (int c = 0; c < 4; c++) {
      kr[c] = *reinterpret_cast<const u32x4*>(ka + c * 16);
      kr[4 + c] = *reinterpret_cast<const u32x4*>(kb2 + c * 16);
    }
    const u16* va0 = &Vb[(size_t)qi * Ls + k_begin + hi * 8];
    const u16* va1 = &Vb[(size_t)(32 + qi) * Ls + k_begin + hi * 8];
    const u16* vc0 = &Vb[(size_t)qi * Ls + r1 + hi * 8];
    const u16* vc1 = &Vb[(size_t)(32 + qi) * Ls + r1 + hi * 8];
    vr[0] = *reinterpret_cast<const u32x4*>(va0);
    vr[1] = *reinterpret_cast<const u32x4*>(va0 + 16);
    vr[2] = *reinterpret_cast<const u32x4*>(va1);
    vr[3] = *reinterpret_cast<const u32x4*>(va1 + 16);
    vr[4] = *reinterpret_cast<const u32x4*>(vc0);
    vr[5] = *reinterpret_cast<const u32x4*>(vc0 + 16);
    vr[6] = *reinterpret_cast<const u32x4*>(vc1);
    vr[7] = *reinterpret_cast<const u32x4*>(vc1 + 16);
  }

  for (int kk = k_begin; kk <= qw; kk += 64) {
    // QK^T both tiles
    f32x16 a0 = {}, a1 = {};
#pragma unroll
    for (int c = 0; c < 4; c++) a0 = mfma32(bc(kr[c]), qf[c], a0);
#pragma unroll
    for (int c = 0; c < 4; c++) a1 = mfma32(bc(kr[4 + c]), qf[c], a1);

    // prefetch next pair's K (hidden under softmax+PV)
    const int kn = (kk + 64 <= qw) ? kk + 64 : kk;
    const int kn2 = min(kn + 32, qw);
    {
      const u16* ka = &Kb[(size_t)(kn + qi) * HD + hi * 8];
      const u16* kb2 = &Kb[(size_t)(kn2 + qi) * HD + hi * 8];
#pragma unroll
      for (int c = 0; c < 4; c++) {
        kr[c] = *reinterpret_cast<const u32x4*>(ka + c * 16);
        kr[4 + c] = *reinterpret_cast<const u32x4*>(kb2 + c * 16);
      }
    }

    float t0[16], t1[16];
#pragma unroll
    for (int r = 0; r < 16; r++) t0[r] = fmaf(a0[r], Cs, djm[r]);
#pragma unroll
    for (int r = 0; r < 16; r++) t1[r] = fmaf(a1[r], Cs, djm[r] + SL32);
    const bool c0 = (kk >= start_max) && (kk + 31 <= qw);
    if (!c0) {
#pragma unroll
      for (int r = 0; r < 16; r++) {
        int j = kk + (r & 3) + 8 * (r >> 2) + 4 * hi;
        t0[r] = (j >= start && j <= q) ? t0[r] : -3.0e38f;
      }
    }
    const bool c1 = (kk + 32 >= start_max) && (kk + 63 <= qw);
    if (!c1) {
#pragma unroll
      for (int r = 0; r < 16; r++) {
        int j = kk + 32 + (r & 3) + 8 * (r >> 2) + 4 * hi;
        t1[r] = (j >= start && j <= q) ? t1[r] : -3.0e38f;
      }
    }
#pragma unroll
    for (int r = 0; r < 16; r++) djm[r] += SL64;

    float mt = fmaxf(t0[0], t0[1]);
#pragma unroll
    for (int r = 2; r < 16; r++) mt = fmaxf(mt, t0[r]);
#pragma unroll
    for (int r = 0; r < 16; r++) mt = fmaxf(mt, t1[r]);
    mt = fmaxf(mt, __shfl_xor(mt, 32));
    if (!__all(mt <= 8.f)) {                     // rare defer-max rescale
      float dm = fmaxf(mt, 0.f);
      float fac = __builtin_amdgcn_exp2f(-dm);
      l_run *= fac;
#pragma unroll
      for (int r = 0; r < 16; r++) { olo[r] *= fac; ohi[r] *= fac; }
#pragma unroll
      for (int r = 0; r < 16; r++) { djm[r] -= dm; t0[r] -= dm; t1[r] -= dm; }
    }
    float p0[16], p1[16];
#pragma unroll
    for (int r = 0; r < 16; r++) p0[r] = __builtin_amdgcn_exp2f(t0[r]);
#pragma unroll
    for (int r = 0; r < 16; r++) p1[r] = __builtin_amdgcn_exp2f(t1[r]);
    float ts = 0.f;
#pragma unroll
    for (int r = 0; r < 16; r++) ts += p0[r] + p1[r];
    l_run += ts + __shfl_xor(ts, 32);

    // pack both P tiles to B-frag layout
    u32 pk0[8], pk1[8], sw0[8], sw1[8];
#pragma unroll
    for (int i = 0; i < 8; i++) pk0[i] = cvtpk(p0[2 * i], p0[2 * i + 1]);
#pragma unroll
    for (int i = 0; i < 8; i++) pk1[i] = cvtpk(p1[2 * i], p1[2 * i + 1]);
#pragma unroll
    for (int i = 0; i < 8; i++) sw0[i] = __shfl_xor(pk0[i], 32);
#pragma unroll
    for (int i = 0; i < 8; i++) sw1[i] = __shfl_xor(pk1[i], 32);
    u32x4 f00 = { hi ? sw0[2] : pk0[0], hi ? sw0[3] : pk0[1],
                  hi ? pk0[2] : sw0[0], hi ? pk0[3] : sw0[1] };
    u32x4 f01 = { hi ? sw0[6] : pk0[4], hi ? sw0[7] : pk0[5],
                  hi ? pk0[6] : sw0[4], hi ? pk0[7] : sw0[5] };
    u32x4 f10 = { hi ? sw1[2] : pk1[0], hi ? sw1[3] : pk1[1],
                  hi ? pk1[2] : sw1[0], hi ? pk1[3] : sw1[1] };
    u32x4 f11 = { hi ? sw1[6] : pk1[4], hi ? sw1[7] : pk1[5],
                  hi ? pk1[6] : sw1[4], hi ? pk1[7] : sw1[5] };

    // PV both tiles
    olo = mfma32(bc(vr[0]), bc(f00), olo);
    olo = mfma32(bc(vr[1]), bc(f01), olo);
    ohi = mfma32(bc(vr[2]), bc(f00), ohi);
    ohi = mfma32(bc(vr[3]), bc(f01), ohi);
    olo = mfma32(bc(vr[4]), bc(f10), olo);
    olo = mfma32(bc(vr[5]), bc(f11), olo);
    ohi = mfma32(bc(vr[6]), bc(f10), ohi);
    ohi = mfma32(bc(vr[7]), bc(f11), ohi);

    // prefetch next pair's V (consumed at next PV)
    {
      const u16* va0 = &Vb[(size_t)qi * Ls + kn + hi * 8];
      const u16* va1 = &Vb[(size_t)(32 + qi) * Ls + kn + hi * 8];
      const u16* vc0 = &Vb[(size_t)qi * Ls + kn2 + hi * 8];
      const u16* vc1 = &Vb[(size_t)(32 + qi) * Ls + kn2 + hi * 8];
      vr[0] = *reinterpret_cast<const u32x4*>(va0);
      vr[1] = *reinterpret_cast<const u32x4*>(va0 + 16);
      vr[2] = *reinterpret_cast<const u32x4*>(va1);
      vr[3] = *reinterpret_cast<const u32x4*>(va1 + 16);
      vr[4] = *reinterpret_cast<const u32x4*>(vc0);
      vr[5] = *reinterpret_cast<const u32x4*>(vc0 + 16);
      vr[6] = *reinterpret_cast<const u32x4*>(vc1);
      vr[7] = *reinterpret_cast<const u32x4*>(vc1 + 16);
    }
  }

  const float inv = __builtin_amdgcn_rcpf(l_run);
  const size_t orow = (size_t)(b * Ls + q) * 1024 + h * 64;
#pragma unroll
  for (int g = 0; g < 4; g++) {
    int d0 = g * 8 + hi * 4;
    u32x2 pa = { cvtpk(olo[4 * g + 0] * inv, olo[4 * g + 1] * inv),
                 cvtpk(olo[4 * g + 2] * inv, olo[4 * g + 3] * inv) };
    u32x2 pb = { cvtpk(ohi[4 * g + 0] * inv, ohi[4 * g + 1] * inv),
                 cvtpk(ohi[4 * g + 2] * inv, ohi[4 * g + 3] * inv) };
    *reinterpret_cast<u32x2*>(&Obuf[orow + d0]) = pa;
    *reinterpret_cast<u32x2*>(&Obuf[orow + 32 + d0]) = pb;
  }
}

// ---- launch ---------------------------------------------------------------
extern "C" void kernel_launch(void* const* d_in, const int* in_sizes, int n_in,
                              void* d_out, int out_size, void* d_ws, size_t ws_size,
                              hipStream_t stream) {
  const float* hs = (const float*)d_in[0];
  const int* seg = (const int*)d_in[1];
  const float* Wq = (const float*)d_in[2];
  const float* Wk = (const float*)d_in[3];
  const float* Wv = (const float*)d_in[4];
  const float* Wo = (const float*)d_in[5];
  float* out = (float*)d_out;
  char* ws = (char*)d_ws;
  // hsb 8.4M | wqkvT 3.1M | woT 2.1M | qc 8.4M | kc 2.1M | vt 2.1M | sst 16K
  u16* hsb   = (u16*)(ws);
  u16* wqkvT = (u16*)(ws + 8388608);
  u16* woT   = (u16*)(ws + 11534336);
  u16* qc    = (u16*)(ws + 13631488);
  u16* kc    = (u16*)(ws + 22020096);
  u16* vt    = (u16*)(ws + 24117248);
  int* sst   = (int*)(ws + 26214400);
  u16* obuf  = hsb;   // hsb dead after GEMM1

  cvt_hs<<<dim3(4096), dim3(256), 0, stream>>>(hs, hsb);
  cvt_wt<<<dim3(32, 32), dim3(256), 0, stream>>>(Wq, wqkvT, 1024, 0);
  cvt_wt<<<dim3(8, 32), dim3(256), 0, stream>>>(Wk, wqkvT, 256, 1024);
  cvt_wt<<<dim3(8, 32), dim3(256), 0, stream>>>(Wv, wqkvT, 256, 1280);
  cvt_wt<<<dim3(32, 32), dim3(256), 0, stream>>>(Wo, woT, 1024, 0);
  seg_start<<<dim3(8, 2), dim3(256), 0, stream>>>(seg, sst);
  gemm_bt<1><<<dim3(12, 32), dim3(256), 0, stream>>>(
      hsb, wqkvT, nullptr, qc, kc, vt, 4096, 1536, 1024);
  attn<<<dim3(16, 16, 2), dim3(256), 0, stream>>>(qc, kc, vt, sst, obuf);
  gemm_bt<0><<<dim3(8, 32), dim3(256), 0, stream>>>(
      obuf, woT, out, nullptr, nullptr, nullptr, 4096, 1024, 1024);
}

// Round 6
// 113.546 us; speedup vs baseline: 2.8720x; 1.0881x over previous
//
#include <hip/hip_runtime.h>
#include <hip/hip_bf16.h>
#include <type_traits>

#define DI __device__ __forceinline__

typedef unsigned short u16;
typedef unsigned int u32;
typedef __bf16 bf16x8 __attribute__((ext_vector_type(8)));
typedef u16 u16x8 __attribute__((ext_vector_type(8)));
typedef float f32x4 __attribute__((ext_vector_type(4)));
typedef float f32x16 __attribute__((ext_vector_type(16)));
typedef u32 u32x2 __attribute__((ext_vector_type(2)));
typedef u32 u32x4 __attribute__((ext_vector_type(4)));

constexpr int Bb = 2, Ls = 2048, Hh = 16, KVh = 4, HD = 64;
constexpr float LOG2E = 1.44269504088896f;

DI u16 f2bf(float f) {
  __hip_bfloat16 h = __float2bfloat16(f);
  return __builtin_bit_cast(u16, h);
}

// packed f32x2 -> bf16x2 (RNE), single VOP3 op
DI u32 cvtpk(float lo, float hi) {
  u32 r;
  asm("v_cvt_pk_bf16_f32 %0, %1, %2" : "=v"(r) : "v"(lo), "v"(hi));
  return r;
}

DI f32x4 mfma16(bf16x8 a, bf16x8 b, f32x4 c) {
  return __builtin_amdgcn_mfma_f32_16x16x32_bf16(a, b, c, 0, 0, 0);
}
DI f32x16 mfma32(bf16x8 a, bf16x8 b, f32x16 c) {
  return __builtin_amdgcn_mfma_f32_32x32x16_bf16(a, b, c, 0, 0, 0);
}
DI bf16x8 bc(u32x4 v) { return __builtin_bit_cast(bf16x8, v); }

// async global->LDS, 16B per lane; LDS dest = wave-uniform base + lane*16
DI void gld16(const u16* g, u16* l) {
  __builtin_amdgcn_global_load_lds(
      (const __attribute__((address_space(1))) u32*)g,
      (__attribute__((address_space(3))) u32*)l, 16, 0, 0);
}

// ---- stage 1: conversions ------------------------------------------------
__global__ void cvt_hs(const float* __restrict__ in, u16* __restrict__ out) {
  int i = blockIdx.x * 256 + threadIdx.x;
  float4 v = reinterpret_cast<const float4*>(in)[i];
  ushort4 o;
  o.x = f2bf(v.x); o.y = f2bf(v.y); o.z = f2bf(v.z); o.w = f2bf(v.w);
  reinterpret_cast<ushort4*>(out)[i] = o;
}

// in: f32 [1024][N] -> out bf16 [N][1024] at row offset rowoff (tiled transpose)
__global__ void cvt_wt(const float* __restrict__ in, u16* __restrict__ out,
                       int N, int rowoff) {
  __shared__ u16 t[32][33];
  int k0 = blockIdx.y * 32, n0 = blockIdx.x * 32;
  int tx = threadIdx.x & 31, ty = threadIdx.x >> 5;
#pragma unroll
  for (int i = ty; i < 32; i += 8)
    t[i][tx] = f2bf(in[(size_t)(k0 + i) * N + n0 + tx]);
  __syncthreads();
#pragma unroll
  for (int i = ty; i < 32; i += 8)
    out[(size_t)(rowoff + n0 + i) * 1024 + k0 + tx] = t[tx][i];
}

// segment start per row: segments are sorted -> contiguous ranges
__global__ void seg_start(const int* __restrict__ seg, int* __restrict__ sst) {
  int b = blockIdx.y;
  int l = blockIdx.x * 256 + threadIdx.x;
  const int* s = seg + b * Ls;
  int v = s[l];
  int lo = 0, hi = l;
  while (lo < hi) {
    int mid = (lo + hi) >> 1;
    if (s[mid] < v) lo = mid + 1; else hi = mid;
  }
  sst[b * Ls + l] = lo;
}

// ---- GEMM: A[M][K] bf16 * Bt[N][K] bf16 ----------------------------------
// MODE 0: C[M][N] float.
// MODE 1 (qkv): scatter bf16 into FRAGMENT-LINEAR tiled layouts:
//   Qf[(bh*64+qt)*2048 + (c8*32+q32)*8 + d7]   (c8=d>>3, q32=l&31)
//   Kf[(bk*64+kt)*2048 + (c8*32+k32)*8 + d7]
//   Vf[(bk*64+kt)*2048 + (kc*64+d)*8 + k8]     (kc=(l>>3)&3, k8=l&7)
template <int MODE>
__global__ __launch_bounds__(256) void gemm_bt(
    const u16* __restrict__ A, const u16* __restrict__ Bt,
    float* __restrict__ C, u16* __restrict__ Qf, u16* __restrict__ Kf,
    u16* __restrict__ Vf, int M, int N, int K) {
  __shared__ u16 lA[128 * 32];
  __shared__ u16 lB[128 * 32];
  const int m0 = blockIdx.y * 128, n0 = blockIdx.x * 128;
  const int tid = threadIdx.x;
  const int w = tid >> 6, lane = tid & 63;
  const int wr = (w >> 1) * 64, wc = (w & 1) * 64;
  const int lr = lane & 15, lk = (lane >> 4) * 8;
  const int r0 = tid >> 2, c0 = (tid & 3) * 8;
  const int r1 = r0 + 64;
  u16* dA0 = (u16*)((char*)lA + ((tid & 192) << 4));
  u16* dA1 = (u16*)((char*)lA + 4096 + ((tid & 192) << 4));
  u16* dB0 = (u16*)((char*)lB + ((tid & 192) << 4));
  u16* dB1 = (u16*)((char*)lB + 4096 + ((tid & 192) << 4));
  const u16* pA0 = &A[(size_t)(m0 + r0) * K + c0];
  const u16* pA1 = &A[(size_t)(m0 + r1) * K + c0];
  const u16* pB0 = &Bt[(size_t)(n0 + r0) * K + c0];
  const u16* pB1 = &Bt[(size_t)(n0 + r1) * K + c0];
  f32x4 acc[4][4] = {};
  for (int k0 = 0; k0 < K; k0 += 32) {
    __syncthreads();
    gld16(pA0 + k0, dA0);
    gld16(pA1 + k0, dA1);
    gld16(pB0 + k0, dB0);
    gld16(pB1 + k0, dB1);
    __syncthreads();
    bf16x8 af[4], bfv[4];
#pragma unroll
    for (int m = 0; m < 4; m++)
      af[m] = *reinterpret_cast<const bf16x8*>(&lA[(wr + m * 16 + lr) * 32 + lk]);
#pragma unroll
    for (int n = 0; n < 4; n++)
      bfv[n] = *reinterpret_cast<const bf16x8*>(&lB[(wc + n * 16 + lr) * 32 + lk]);
#pragma unroll
    for (int m = 0; m < 4; m++)
#pragma unroll
      for (int n = 0; n < 4; n++)
        acc[m][n] = mfma16(af[m], bfv[n], acc[m][n]);
  }
  const int rr = (lane >> 4) * 4, cc = lane & 15;
#pragma unroll
  for (int m = 0; m < 4; m++) {
    int row0 = m0 + wr + m * 16 + rr;
#pragma unroll
    for (int n = 0; n < 4; n++) {
      int col = n0 + wc + n * 16 + cc;
      if constexpr (MODE == 0) {
#pragma unroll
        for (int r = 0; r < 4; r++)
          C[(size_t)(row0 + r) * N + col] = acc[m][n][r];
      } else {
        int bb = row0 >> 11, l = row0 & 2047;
        int d = col & 63, c8 = d >> 3, d7 = d & 7;
        int kt = l >> 5, r32 = l & 31;
        if (col < 1024) {
          int hd = col >> 6;
          u16* base = &Qf[((((size_t)(bb * 16 + hd) * 64 + kt) << 11)) +
                          ((c8 * 32 + r32) << 3) + d7];
#pragma unroll
          for (int r = 0; r < 4; r++) base[r * 8] = f2bf(acc[m][n][r]);
        } else if (col < 1280) {
          int kv = (col - 1024) >> 6;
          u16* base = &Kf[((((size_t)(bb * 4 + kv) * 64 + kt) << 11)) +
                          ((c8 * 32 + r32) << 3) + d7];
#pragma unroll
          for (int r = 0; r < 4; r++) base[r * 8] = f2bf(acc[m][n][r]);
        } else {
          int kv = (col - 1280) >> 6;
          ushort4 pv;
          pv.x = f2bf(acc[m][n][0]); pv.y = f2bf(acc[m][n][1]);
          pv.z = f2bf(acc[m][n][2]); pv.w = f2bf(acc[m][n][3]);
          *reinterpret_cast<ushort4*>(
              &Vf[((((size_t)(bb * 4 + kv) * 64 + kt) << 11)) +
                  ((((l >> 3) & 3) * 64 + d) << 3) + (l & 7)]) = pv;
        }
      }
    }
  }
}

// ---- flash attention: swapped 32x32, 1 wave/block, k-unroll x2 -----------
// Fragment-linear Qf/Kf/Vf: every operand load is 2x512B contiguous.
__global__ __launch_bounds__(64) void attn(
    const u16* __restrict__ Qf, const u16* __restrict__ Kf,
    const u16* __restrict__ Vf, const int* __restrict__ sst,
    u16* __restrict__ Obuf) {
  const int qt = blockIdx.x, h = blockIdx.y, b = blockIdx.z;
  const int kvh = h >> 2;
  const int lane = threadIdx.x;
  const int qi = lane & 31, hi = lane >> 5;
  const int qw = qt * 32;
  const int q = qw + qi;
  const float slope = __builtin_amdgcn_exp2f(-0.5f * (float)(h + 1));
  const float SL = slope * LOG2E;
  const float SL32 = 32.f * SL, SL64 = 64.f * SL;
  const float Cs = 0.125f * LOG2E;
  const u16* Qt = Qf + (((size_t)(b * Hh + h) * 64 + qt) << 11);
  const u16* Kbase = Kf + (((size_t)(b * KVh + kvh) * 64) << 11);
  const u16* Vbase = Vf + (((size_t)(b * KVh + kvh) * 64) << 11);

  bf16x8 qf[4];
#pragma unroll
  for (int c = 0; c < 4; c++)
    qf[c] = *reinterpret_cast<const bf16x8*>(&Qt[((2 * c + hi) * 32 + qi) * 8]);

  const int start = sst[b * Ls + q];
  const int start_max = __shfl(start, 31);
  const int k_begin = __shfl(start, 0) & ~31;

  float l_run = 0.f;                      // running max folded into djm
  f32x16 olo = {}, ohi = {};
  float djm[16];
#pragma unroll
  for (int r = 0; r < 16; r++) {
    int krow = (r & 3) + 8 * (r >> 2) + 4 * hi;
    djm[r] = (float)(k_begin + krow - q) * SL;
  }

  u32x4 kr[8], vr[8];
  {
    const int ktA = k_begin >> 5, ktB = min(k_begin + 32, qw) >> 5;
    const u16* kA = Kbase + ((size_t)ktA << 11);
    const u16* kB = Kbase + ((size_t)ktB << 11);
    const u16* vA = Vbase + ((size_t)ktA << 11);
    const u16* vB = Vbase + ((size_t)ktB << 11);
#pragma unroll
    for (int c = 0; c < 4; c++) {
      kr[c] = *reinterpret_cast<const u32x4*>(&kA[((2 * c + hi) * 32 + qi) * 8]);
      kr[4 + c] = *reinterpret_cast<const u32x4*>(&kB[((2 * c + hi) * 32 + qi) * 8]);
    }
#pragma unroll
    for (int j = 0; j < 4; j++) {
      int off = ((((j & 1) * 2 + hi) * 64) + (j >> 1) * 32 + qi) * 8;
      vr[j] = *reinterpret_cast<const u32x4*>(&vA[off]);
      vr[4 + j] = *reinterpret_cast<const u32x4*>(&vB[off]);
    }
  }

  for (int kk = k_begin; kk <= qw; kk += 64) {
    // QK^T both tiles
    f32x16 a0 = {}, a1 = {};
#pragma unroll
    for (int c = 0; c < 4; c++) a0 = mfma32(bc(kr[c]), qf[c], a0);
#pragma unroll
    for (int c = 0; c < 4; c++) a1 = mfma32(bc(kr[4 + c]), qf[c], a1);

    // prefetch next pair's K (hidden under softmax+PV)
    const int kn = (kk + 64 <= qw) ? kk + 64 : kk;
    const int kn2 = min(kn + 32, qw);
    const u16* kA = Kbase + ((size_t)(kn >> 5) << 11);
    const u16* kB = Kbase + ((size_t)(kn2 >> 5) << 11);
#pragma unroll
    for (int c = 0; c < 4; c++) {
      kr[c] = *reinterpret_cast<const u32x4*>(&kA[((2 * c + hi) * 32 + qi) * 8]);
      kr[4 + c] = *reinterpret_cast<const u32x4*>(&kB[((2 * c + hi) * 32 + qi) * 8]);
    }

    float t0[16], t1[16];
#pragma unroll
    for (int r = 0; r < 16; r++) t0[r] = fmaf(a0[r], Cs, djm[r]);
#pragma unroll
    for (int r = 0; r < 16; r++) t1[r] = fmaf(a1[r], Cs, djm[r] + SL32);
    const bool c0 = (kk >= start_max) && (kk + 31 <= qw);
    if (!c0) {
#pragma unroll
      for (int r = 0; r < 16; r++) {
        int j = kk + (r & 3) + 8 * (r >> 2) + 4 * hi;
        t0[r] = (j >= start && j <= q) ? t0[r] : -3.0e38f;
      }
    }
    const bool c1 = (kk + 32 >= start_max) && (kk + 63 <= qw);
    if (!c1) {
#pragma unroll
      for (int r = 0; r < 16; r++) {
        int j = kk + 32 + (r & 3) + 8 * (r >> 2) + 4 * hi;
        t1[r] = (j >= start && j <= q) ? t1[r] : -3.0e38f;
      }
    }
#pragma unroll
    for (int r = 0; r < 16; r++) djm[r] += SL64;

    float mt = fmaxf(t0[0], t0[1]);
#pragma unroll
    for (int r = 2; r < 16; r++) mt = fmaxf(mt, t0[r]);
#pragma unroll
    for (int r = 0; r < 16; r++) mt = fmaxf(mt, t1[r]);
    mt = fmaxf(mt, __shfl_xor(mt, 32));
    if (!__all(mt <= 8.f)) {                     // rare defer-max rescale
      float dm = fmaxf(mt, 0.f);
      float fac = __builtin_amdgcn_exp2f(-dm);
      l_run *= fac;
#pragma unroll
      for (int r = 0; r < 16; r++) { olo[r] *= fac; ohi[r] *= fac; }
#pragma unroll
      for (int r = 0; r < 16; r++) { djm[r] -= dm; t0[r] -= dm; t1[r] -= dm; }
    }
    float p0[16], p1[16];
#pragma unroll
    for (int r = 0; r < 16; r++) p0[r] = __builtin_amdgcn_exp2f(t0[r]);
#pragma unroll
    for (int r = 0; r < 16; r++) p1[r] = __builtin_amdgcn_exp2f(t1[r]);
    float ts = 0.f;
#pragma unroll
    for (int r = 0; r < 16; r++) ts += p0[r] + p1[r];
    l_run += ts + __shfl_xor(ts, 32);

    // pack both P tiles to B-frag layout
    u32 pk0[8], pk1[8], sw0[8], sw1[8];
#pragma unroll
    for (int i = 0; i < 8; i++) pk0[i] = cvtpk(p0[2 * i], p0[2 * i + 1]);
#pragma unroll
    for (int i = 0; i < 8; i++) pk1[i] = cvtpk(p1[2 * i], p1[2 * i + 1]);
#pragma unroll
    for (int i = 0; i < 8; i++) sw0[i] = __shfl_xor(pk0[i], 32);
#pragma unroll
    for (int i = 0; i < 8; i++) sw1[i] = __shfl_xor(pk1[i], 32);
    u32x4 f00 = { hi ? sw0[2] : pk0[0], hi ? sw0[3] : pk0[1],
                  hi ? pk0[2] : sw0[0], hi ? pk0[3] : sw0[1] };
    u32x4 f01 = { hi ? sw0[6] : pk0[4], hi ? sw0[7] : pk0[5],
                  hi ? pk0[6] : sw0[4], hi ? pk0[7] : sw0[5] };
    u32x4 f10 = { hi ? sw1[2] : pk1[0], hi ? sw1[3] : pk1[1],
                  hi ? pk1[2] : sw1[0], hi ? pk1[3] : sw1[1] };
    u32x4 f11 = { hi ? sw1[6] : pk1[4], hi ? sw1[7] : pk1[5],
                  hi ? pk1[6] : sw1[4], hi ? pk1[7] : sw1[5] };

    // PV both tiles
    olo = mfma32(bc(vr[0]), bc(f00), olo);
    olo = mfma32(bc(vr[1]), bc(f01), olo);
    ohi = mfma32(bc(vr[2]), bc(f00), ohi);
    ohi = mfma32(bc(vr[3]), bc(f01), ohi);
    olo = mfma32(bc(vr[4]), bc(f10), olo);
    olo = mfma32(bc(vr[5]), bc(f11), olo);
    ohi = mfma32(bc(vr[6]), bc(f10), ohi);
    ohi = mfma32(bc(vr[7]), bc(f11), ohi);

    // prefetch next pair's V (consumed at next PV)
    {
      const u16* vA = Vbase + ((size_t)(kn >> 5) << 11);
      const u16* vB = Vbase + ((size_t)(kn2 >> 5) << 11);
#pragma unroll
      for (int j = 0; j < 4; j++) {
        int off = ((((j & 1) * 2 + hi) * 64) + (j >> 1) * 32 + qi) * 8;
        vr[j] = *reinterpret_cast<const u32x4*>(&vA[off]);
        vr[4 + j] = *reinterpret_cast<const u32x4*>(&vB[off]);
      }
    }
  }

  const float inv = __builtin_amdgcn_rcpf(l_run);
  const size_t orow = (size_t)(b * Ls + q) * 1024 + h * 64;
#pragma unroll
  for (int g = 0; g < 4; g++) {
    int d0 = g * 8 + hi * 4;
    u32x2 pa = { cvtpk(olo[4 * g + 0] * inv, olo[4 * g + 1] * inv),
                 cvtpk(olo[4 * g + 2] * inv, olo[4 * g + 3] * inv) };
    u32x2 pb = { cvtpk(ohi[4 * g + 0] * inv, ohi[4 * g + 1] * inv),
                 cvtpk(ohi[4 * g + 2] * inv, ohi[4 * g + 3] * inv) };
    *reinterpret_cast<u32x2*>(&Obuf[orow + d0]) = pa;
    *reinterpret_cast<u32x2*>(&Obuf[orow + 32 + d0]) = pb;
  }
}

// ---- launch ---------------------------------------------------------------
extern "C" void kernel_launch(void* const* d_in, const int* in_sizes, int n_in,
                              void* d_out, int out_size, void* d_ws, size_t ws_size,
                              hipStream_t stream) {
  const float* hs = (const float*)d_in[0];
  const int* seg = (const int*)d_in[1];
  const float* Wq = (const float*)d_in[2];
  const float* Wk = (const float*)d_in[3];
  const float* Wv = (const float*)d_in[4];
  const float* Wo = (const float*)d_in[5];
  float* out = (float*)d_out;
  char* ws = (char*)d_ws;
  // hsb 8.4M | wqkvT 3.1M | woT 2.1M | Qf 8.4M | Kf 2.1M | Vf 2.1M | sst 16K
  u16* hsb   = (u16*)(ws);
  u16* wqkvT = (u16*)(ws + 8388608);
  u16* woT   = (u16*)(ws + 11534336);
  u16* qf    = (u16*)(ws + 13631488);
  u16* kf    = (u16*)(ws + 22020096);
  u16* vf    = (u16*)(ws + 24117248);
  int* sst   = (int*)(ws + 26214400);
  u16* obuf  = hsb;   // hsb dead after GEMM1

  cvt_hs<<<dim3(4096), dim3(256), 0, stream>>>(hs, hsb);
  cvt_wt<<<dim3(32, 32), dim3(256), 0, stream>>>(Wq, wqkvT, 1024, 0);
  cvt_wt<<<dim3(8, 32), dim3(256), 0, stream>>>(Wk, wqkvT, 256, 1024);
  cvt_wt<<<dim3(8, 32), dim3(256), 0, stream>>>(Wv, wqkvT, 256, 1280);
  cvt_wt<<<dim3(32, 32), dim3(256), 0, stream>>>(Wo, woT, 1024, 0);
  seg_start<<<dim3(8, 2), dim3(256), 0, stream>>>(seg, sst);
  gemm_bt<1><<<dim3(12, 32), dim3(256), 0, stream>>>(
      hsb, wqkvT, nullptr, qf, kf, vf, 4096, 1536, 1024);
  attn<<<dim3(64, 16, 2), dim3(64), 0, stream>>>(qf, kf, vf, sst, obuf);
  gemm_bt<0><<<dim3(8, 32), dim3(256), 0, stream>>>(
      obuf, woT, out, nullptr, nullptr, nullptr, 4096, 1024, 1024);
}

// Round 7
// 110.314 us; speedup vs baseline: 2.9561x; 1.0293x over previous
//
#include <hip/hip_runtime.h>
#include <hip/hip_bf16.h>
#include <type_traits>

#define DI __device__ __forceinline__

typedef unsigned short u16;
typedef unsigned int u32;
typedef __bf16 bf16x8 __attribute__((ext_vector_type(8)));
typedef u16 u16x8 __attribute__((ext_vector_type(8)));
typedef float f32x4 __attribute__((ext_vector_type(4)));
typedef float f32x16 __attribute__((ext_vector_type(16)));
typedef u32 u32x2 __attribute__((ext_vector_type(2)));
typedef u32 u32x4 __attribute__((ext_vector_type(4)));

constexpr int Bb = 2, Ls = 2048, Hh = 16, KVh = 4, HD = 64;
constexpr float LOG2E = 1.44269504088896f;

DI u16 f2bf(float f) {
  __hip_bfloat16 h = __float2bfloat16(f);
  return __builtin_bit_cast(u16, h);
}

// packed f32x2 -> bf16x2 (RNE), single VOP3 op
DI u32 cvtpk(float lo, float hi) {
  u32 r;
  asm("v_cvt_pk_bf16_f32 %0, %1, %2" : "=v"(r) : "v"(lo), "v"(hi));
  return r;
}

DI f32x4 mfma16(bf16x8 a, bf16x8 b, f32x4 c) {
  return __builtin_amdgcn_mfma_f32_16x16x32_bf16(a, b, c, 0, 0, 0);
}
DI f32x16 mfma32(bf16x8 a, bf16x8 b, f32x16 c) {
  return __builtin_amdgcn_mfma_f32_32x32x16_bf16(a, b, c, 0, 0, 0);
}
DI bf16x8 bc(u32x4 v) { return __builtin_bit_cast(bf16x8, v); }

// async global->LDS, 16B per lane; LDS dest = wave-uniform base + lane*16
DI void gld16(const u16* g, u16* l) {
  __builtin_amdgcn_global_load_lds(
      (const __attribute__((address_space(1))) u32*)g,
      (__attribute__((address_space(3))) u32*)l, 16, 0, 0);
}

// ---- stage 1: conversions ------------------------------------------------
__global__ void cvt_hs(const float* __restrict__ in, u16* __restrict__ out) {
  int i = blockIdx.x * 256 + threadIdx.x;
  float4 v = reinterpret_cast<const float4*>(in)[i];
  ushort4 o;
  o.x = f2bf(v.x); o.y = f2bf(v.y); o.z = f2bf(v.z); o.w = f2bf(v.w);
  reinterpret_cast<ushort4*>(out)[i] = o;
}

// in: f32 [1024][N] -> out bf16 [N][1024] at row offset rowoff (tiled transpose)
__global__ void cvt_wt(const float* __restrict__ in, u16* __restrict__ out,
                       int N, int rowoff) {
  __shared__ u16 t[32][33];
  int k0 = blockIdx.y * 32, n0 = blockIdx.x * 32;
  int tx = threadIdx.x & 31, ty = threadIdx.x >> 5;
#pragma unroll
  for (int i = ty; i < 32; i += 8)
    t[i][tx] = f2bf(in[(size_t)(k0 + i) * N + n0 + tx]);
  __syncthreads();
#pragma unroll
  for (int i = ty; i < 32; i += 8)
    out[(size_t)(rowoff + n0 + i) * 1024 + k0 + tx] = t[tx][i];
}

// segment start per row: segments are sorted -> contiguous ranges
__global__ void seg_start(const int* __restrict__ seg, int* __restrict__ sst) {
  int b = blockIdx.y;
  int l = blockIdx.x * 256 + threadIdx.x;
  const int* s = seg + b * Ls;
  int v = s[l];
  int lo = 0, hi = l;
  while (lo < hi) {
    int mid = (lo + hi) >> 1;
    if (s[mid] < v) lo = mid + 1; else hi = mid;
  }
  sst[b * Ls + l] = lo;
}

// ---- GEMM: A[M][K] bf16 * Bt[N][K] bf16, 2-phase dbuf pipeline -----------
// MODE 0: C[M][N] float.
// MODE 1 (qkv): scatter bf16 into FRAGMENT-LINEAR tiled layouts (see r6).
template <int MODE>
__global__ __launch_bounds__(256) void gemm_bt(
    const u16* __restrict__ A, const u16* __restrict__ Bt,
    float* __restrict__ C, u16* __restrict__ Qf, u16* __restrict__ Kf,
    u16* __restrict__ Vf, int M, int N, int K) {
  __shared__ u16 lA[2][128 * 32];
  __shared__ u16 lB[2][128 * 32];
  const int m0 = blockIdx.y * 128, n0 = blockIdx.x * 128;
  const int tid = threadIdx.x;
  const int w = tid >> 6, lane = tid & 63;
  const int wr = (w >> 1) * 64, wc = (w & 1) * 64;
  const int lr = lane & 15, lk = (lane >> 4) * 8;
  const int r0 = tid >> 2, c0 = (tid & 3) * 8;
  const int r1 = r0 + 64;
  const int woff = (tid & 192) << 4;            // wave-uniform byte offset
  const u16* pA0 = &A[(size_t)(m0 + r0) * K + c0];
  const u16* pA1 = &A[(size_t)(m0 + r1) * K + c0];
  const u16* pB0 = &Bt[(size_t)(n0 + r0) * K + c0];
  const u16* pB1 = &Bt[(size_t)(n0 + r1) * K + c0];

  auto stage = [&](int buf, int k0) {
    char* baseA = (char*)lA[buf] + woff;
    char* baseB = (char*)lB[buf] + woff;
    gld16(pA0 + k0, (u16*)baseA);
    gld16(pA1 + k0, (u16*)(baseA + 4096));
    gld16(pB0 + k0, (u16*)baseB);
    gld16(pB1 + k0, (u16*)(baseB + 4096));
  };

  f32x4 acc[4][4] = {};
  stage(0, 0);
  __syncthreads();                              // drains staged loads
  int cur = 0;
  for (int k0 = 0; k0 < K; k0 += 32, cur ^= 1) {
    if (k0 + 32 < K) stage(cur ^ 1, k0 + 32);   // prefetch next K-step
    bf16x8 af[4], bfv[4];
#pragma unroll
    for (int m = 0; m < 4; m++)
      af[m] = *reinterpret_cast<const bf16x8*>(
          &lA[cur][(wr + m * 16 + lr) * 32 + lk]);
#pragma unroll
    for (int n = 0; n < 4; n++)
      bfv[n] = *reinterpret_cast<const bf16x8*>(
          &lB[cur][(wc + n * 16 + lr) * 32 + lk]);
#pragma unroll
    for (int m = 0; m < 4; m++)
#pragma unroll
      for (int n = 0; n < 4; n++)
        acc[m][n] = mfma16(af[m], bfv[n], acc[m][n]);
    __syncthreads();                            // waits staged + read done
  }

  const int rr = (lane >> 4) * 4, cc = lane & 15;
#pragma unroll
  for (int m = 0; m < 4; m++) {
    int row0 = m0 + wr + m * 16 + rr;
#pragma unroll
    for (int n = 0; n < 4; n++) {
      int col = n0 + wc + n * 16 + cc;
      if constexpr (MODE == 0) {
#pragma unroll
        for (int r = 0; r < 4; r++)
          C[(size_t)(row0 + r) * N + col] = acc[m][n][r];
      } else {
        int bb = row0 >> 11, l = row0 & 2047;
        int d = col & 63, c8 = d >> 3, d7 = d & 7;
        int kt = l >> 5, r32 = l & 31;
        if (col < 1024) {
          int hd = col >> 6;
          u16* base = &Qf[((((size_t)(bb * 16 + hd) * 64 + kt) << 11)) +
                          ((c8 * 32 + r32) << 3) + d7];
#pragma unroll
          for (int r = 0; r < 4; r++) base[r * 8] = f2bf(acc[m][n][r]);
        } else if (col < 1280) {
          int kv = (col - 1024) >> 6;
          u16* base = &Kf[((((size_t)(bb * 4 + kv) * 64 + kt) << 11)) +
                          ((c8 * 32 + r32) << 3) + d7];
#pragma unroll
          for (int r = 0; r < 4; r++) base[r * 8] = f2bf(acc[m][n][r]);
        } else {
          int kv = (col - 1280) >> 6;
          ushort4 pv;
          pv.x = f2bf(acc[m][n][0]); pv.y = f2bf(acc[m][n][1]);
          pv.z = f2bf(acc[m][n][2]); pv.w = f2bf(acc[m][n][3]);
          *reinterpret_cast<ushort4*>(
              &Vf[((((size_t)(bb * 4 + kv) * 64 + kt) << 11)) +
                  ((((l >> 3) & 3) * 64 + d) << 3) + (l & 7)]) = pv;
        }
      }
    }
  }
}

// ---- flash attention: swapped 32x32, q-PAIR per wave, shared K/V ---------
// Wave owns q-tiles {2p, 2p+1} (64 q rows). Both groups consume the SAME
// K/V fragment registers (half the loads per unit work), and run two
// independent softmax chains (ILP). Per-group guards skip dead halves.
__global__ __launch_bounds__(64) void attn(
    const u16* __restrict__ Qf, const u16* __restrict__ Kf,
    const u16* __restrict__ Vf, const int* __restrict__ sst,
    u16* __restrict__ Obuf) {
  const int qp = 31 - blockIdx.x;               // big blocks dispatch first
  const int h = blockIdx.y, b = blockIdx.z;
  const int kvh = h >> 2;
  const int lane = threadIdx.x;
  const int qi = lane & 31, hi = lane >> 5;
  const int qwA = qp * 64, qwB = qwA + 32;
  const int qA = qwA + qi, qB = qwB + qi;
  const float slope = __builtin_amdgcn_exp2f(-0.5f * (float)(h + 1));
  const float SL = slope * LOG2E;
  const float SL32 = 32.f * SL;
  const float Cs = 0.125f * LOG2E;
  const u16* Qtile = Qf + (((size_t)(b * Hh + h) * 64) << 11);
  const u16* Kbase = Kf + (((size_t)(b * KVh + kvh) * 64) << 11);
  const u16* Vbase = Vf + (((size_t)(b * KVh + kvh) * 64) << 11);

  bf16x8 qfA[4], qfB[4];
  {
    const u16* QtA = Qtile + ((size_t)(2 * qp) << 11);
    const u16* QtB = Qtile + ((size_t)(2 * qp + 1) << 11);
#pragma unroll
    for (int c = 0; c < 4; c++) {
      qfA[c] = *reinterpret_cast<const bf16x8*>(&QtA[((2 * c + hi) * 32 + qi) * 8]);
      qfB[c] = *reinterpret_cast<const bf16x8*>(&QtB[((2 * c + hi) * 32 + qi) * 8]);
    }
  }

  const int startA = sst[b * Ls + qA];
  const int startB = sst[b * Ls + qB];
  const int smaxA = __shfl(startA, 31);
  const int smaxB = __shfl(startB, 31);
  const int k_begin = __shfl(startA, 0) & ~31;
  const int kBbeg = __shfl(startB, 0) & ~31;

  float krsl[16];
#pragma unroll
  for (int r = 0; r < 16; r++)
    krsl[r] = (float)((r & 3) + 8 * (r >> 2) + 4 * hi) * SL;
  float biasA = (float)(k_begin - qA) * SL;     // (kk - q)*SL - m_run
  float biasB = (float)(k_begin - qB) * SL;
  float lA = 0.f, lB = 0.f;
  f32x16 oAlo = {}, oAhi = {}, oBlo = {}, oBhi = {};

  auto KLD = [&](int kt, u32x4* dst) {
    const u16* p = Kbase + ((size_t)kt << 11);
#pragma unroll
    for (int c = 0; c < 4; c++)
      dst[c] = *reinterpret_cast<const u32x4*>(&p[((2 * c + hi) * 32 + qi) * 8]);
  };
  auto VLD = [&](int kt, u32x4* dst) {
    const u16* p = Vbase + ((size_t)kt << 11);
#pragma unroll
    for (int j = 0; j < 4; j++) {
      int off = ((((j & 1) * 2 + hi) * 64) + (j >> 1) * 32 + qi) * 8;
      dst[j] = *reinterpret_cast<const u32x4*>(&p[off]);
    }
  };

  // One 32-key tile for BOTH q-groups; prefetches its own buffers for kk+64.
  auto body = [&](int kk, u32x4* KR, u32x4* VR) {
    const bool actA = (kk <= qwA);
    const bool actB = (kk >= kBbeg);
    f32x16 aA = {}, aB = {};
    if (actA) {
#pragma unroll
      for (int c = 0; c < 4; c++) aA = mfma32(bc(KR[c]), qfA[c], aA);
    }
    if (actB) {
#pragma unroll
      for (int c = 0; c < 4; c++) aB = mfma32(bc(KR[c]), qfB[c], aB);
    }
    const int kt2 = min(kk + 64, qwB) >> 5;
    KLD(kt2, KR);                               // hidden under softmax+PV

    u32x4 fA0, fA1, fB0, fB1;
    if (actA) {
      float t[16];
#pragma unroll
      for (int r = 0; r < 16; r++) t[r] = fmaf(aA[r], Cs, biasA) + krsl[r];
      if (!(kk >= smaxA && kk < qwA)) {
#pragma unroll
        for (int r = 0; r < 16; r++) {
          int j = kk + (r & 3) + 8 * (r >> 2) + 4 * hi;
          t[r] = (j >= startA && j <= qA) ? t[r] : -3.0e38f;
        }
      }
      float mt = fmaxf(t[0], t[1]);
#pragma unroll
      for (int r = 2; r < 16; r++) mt = fmaxf(mt, t[r]);
      mt = fmaxf(mt, __shfl_xor(mt, 32));
      if (!__all(mt <= 8.f)) {
        float dm = fmaxf(mt, 0.f);
        float fac = __builtin_amdgcn_exp2f(-dm);
        biasA -= dm; lA *= fac;
#pragma unroll
        for (int r = 0; r < 16; r++) { oAlo[r] *= fac; oAhi[r] *= fac; t[r] -= dm; }
      }
      float p[16];
#pragma unroll
      for (int r = 0; r < 16; r++) p[r] = __builtin_amdgcn_exp2f(t[r]);
      float ts = 0.f;
#pragma unroll
      for (int r = 0; r < 16; r++) ts += p[r];
      lA += ts + __shfl_xor(ts, 32);
      u32 pk[8], sw[8];
#pragma unroll
      for (int i = 0; i < 8; i++) pk[i] = cvtpk(p[2 * i], p[2 * i + 1]);
#pragma unroll
      for (int i = 0; i < 8; i++) sw[i] = __shfl_xor(pk[i], 32);
      fA0 = u32x4{ hi ? sw[2] : pk[0], hi ? sw[3] : pk[1],
                   hi ? pk[2] : sw[0], hi ? pk[3] : sw[1] };
      fA1 = u32x4{ hi ? sw[6] : pk[4], hi ? sw[7] : pk[5],
                   hi ? pk[6] : sw[4], hi ? pk[7] : sw[5] };
    }
    if (actB) {
      float t[16];
#pragma unroll
      for (int r = 0; r < 16; r++) t[r] = fmaf(aB[r], Cs, biasB) + krsl[r];
      if (!(kk >= smaxB && kk < qwB)) {
#pragma unroll
        for (int r = 0; r < 16; r++) {
          int j = kk + (r & 3) + 8 * (r >> 2) + 4 * hi;
          t[r] = (j >= startB && j <= qB) ? t[r] : -3.0e38f;
        }
      }
      float mt = fmaxf(t[0], t[1]);
#pragma unroll
      for (int r = 2; r < 16; r++) mt = fmaxf(mt, t[r]);
      mt = fmaxf(mt, __shfl_xor(mt, 32));
      if (!__all(mt <= 8.f)) {
        float dm = fmaxf(mt, 0.f);
        float fac = __builtin_amdgcn_exp2f(-dm);
        biasB -= dm; lB *= fac;
#pragma unroll
        for (int r = 0; r < 16; r++) { oBlo[r] *= fac; oBhi[r] *= fac; t[r] -= dm; }
      }
      float p[16];
#pragma unroll
      for (int r = 0; r < 16; r++) p[r] = __builtin_amdgcn_exp2f(t[r]);
      float ts = 0.f;
#pragma unroll
      for (int r = 0; r < 16; r++) ts += p[r];
      lB += ts + __shfl_xor(ts, 32);
      u32 pk[8], sw[8];
#pragma unroll
      for (int i = 0; i < 8; i++) pk[i] = cvtpk(p[2 * i], p[2 * i + 1]);
#pragma unroll
      for (int i = 0; i < 8; i++) sw[i] = __shfl_xor(pk[i], 32);
      fB0 = u32x4{ hi ? sw[2] : pk[0], hi ? sw[3] : pk[1],
                   hi ? pk[2] : sw[0], hi ? pk[3] : sw[1] };
      fB1 = u32x4{ hi ? sw[6] : pk[4], hi ? sw[7] : pk[5],
                   hi ? pk[6] : sw[4], hi ? pk[7] : sw[5] };
    }
    if (actA) {
      oAlo = mfma32(bc(VR[0]), bc(fA0), oAlo);
      oAlo = mfma32(bc(VR[1]), bc(fA1), oAlo);
      oAhi = mfma32(bc(VR[2]), bc(fA0), oAhi);
      oAhi = mfma32(bc(VR[3]), bc(fA1), oAhi);
    }
    if (actB) {
      oBlo = mfma32(bc(VR[0]), bc(fB0), oBlo);
      oBlo = mfma32(bc(VR[1]), bc(fB1), oBlo);
      oBhi = mfma32(bc(VR[2]), bc(fB0), oBhi);
      oBhi = mfma32(bc(VR[3]), bc(fB1), oBhi);
    }
    VLD(kt2, VR);                               // prefetch next V
    biasA += SL32; biasB += SL32;
  };

  u32x4 KR0[4], VR0[4], KR1[4], VR1[4];
  {
    const int kt0 = k_begin >> 5;
    const int kt1 = min(k_begin + 32, qwB) >> 5;
    KLD(kt0, KR0); VLD(kt0, VR0);
    KLD(kt1, KR1); VLD(kt1, VR1);
  }
  int kk = k_begin;
  while (true) {
    body(kk, KR0, VR0);
    if (kk + 32 > qwB) break;
    body(kk + 32, KR1, VR1);
    if (kk + 64 > qwB) break;
    kk += 64;
  }

  const float invA = __builtin_amdgcn_rcpf(lA);
  const float invB = __builtin_amdgcn_rcpf(lB);
  const size_t orowA = (size_t)(b * Ls + qA) * 1024 + h * 64;
  const size_t orowB = (size_t)(b * Ls + qB) * 1024 + h * 64;
#pragma unroll
  for (int g = 0; g < 4; g++) {
    int d0 = g * 8 + hi * 4;
    u32x2 pa = { cvtpk(oAlo[4 * g + 0] * invA, oAlo[4 * g + 1] * invA),
                 cvtpk(oAlo[4 * g + 2] * invA, oAlo[4 * g + 3] * invA) };
    u32x2 pb = { cvtpk(oAhi[4 * g + 0] * invA, oAhi[4 * g + 1] * invA),
                 cvtpk(oAhi[4 * g + 2] * invA, oAhi[4 * g + 3] * invA) };
    *reinterpret_cast<u32x2*>(&Obuf[orowA + d0]) = pa;
    *reinterpret_cast<u32x2*>(&Obuf[orowA + 32 + d0]) = pb;
    u32x2 qa = { cvtpk(oBlo[4 * g + 0] * invB, oBlo[4 * g + 1] * invB),
                 cvtpk(oBlo[4 * g + 2] * invB, oBlo[4 * g + 3] * invB) };
    u32x2 qb = { cvtpk(oBhi[4 * g + 0] * invB, oBhi[4 * g + 1] * invB),
                 cvtpk(oBhi[4 * g + 2] * invB, oBhi[4 * g + 3] * invB) };
    *reinterpret_cast<u32x2*>(&Obuf[orowB + d0]) = qa;
    *reinterpret_cast<u32x2*>(&Obuf[orowB + 32 + d0]) = qb;
  }
}

// ---- launch ---------------------------------------------------------------
extern "C" void kernel_launch(void* const* d_in, const int* in_sizes, int n_in,
                              void* d_out, int out_size, void* d_ws, size_t ws_size,
                              hipStream_t stream) {
  const float* hs = (const float*)d_in[0];
  const int* seg = (const int*)d_in[1];
  const float* Wq = (const float*)d_in[2];
  const float* Wk = (const float*)d_in[3];
  const float* Wv = (const float*)d_in[4];
  const float* Wo = (const float*)d_in[5];
  float* out = (float*)d_out;
  char* ws = (char*)d_ws;
  // hsb 8.4M | wqkvT 3.1M | woT 2.1M | Qf 8.4M | Kf 2.1M | Vf 2.1M | sst 16K
  u16* hsb   = (u16*)(ws);
  u16* wqkvT = (u16*)(ws + 8388608);
  u16* woT   = (u16*)(ws + 11534336);
  u16* qf    = (u16*)(ws + 13631488);
  u16* kf    = (u16*)(ws + 22020096);
  u16* vf    = (u16*)(ws + 24117248);
  int* sst   = (int*)(ws + 26214400);
  u16* obuf  = hsb;   // hsb dead after GEMM1

  cvt_hs<<<dim3(4096), dim3(256), 0, stream>>>(hs, hsb);
  cvt_wt<<<dim3(32, 32), dim3(256), 0, stream>>>(Wq, wqkvT, 1024, 0);
  cvt_wt<<<dim3(8, 32), dim3(256), 0, stream>>>(Wk, wqkvT, 256, 1024);
  cvt_wt<<<dim3(8, 32), dim3(256), 0, stream>>>(Wv, wqkvT, 256, 1280);
  cvt_wt<<<dim3(32, 32), dim3(256), 0, stream>>>(Wo, woT, 1024, 0);
  seg_start<<<dim3(8, 2), dim3(256), 0, stream>>>(seg, sst);
  gemm_bt<1><<<dim3(12, 32), dim3(256), 0, stream>>>(
      hsb, wqkvT, nullptr, qf, kf, vf, 4096, 1536, 1024);
  attn<<<dim3(32, 16, 2), dim3(64), 0, stream>>>(qf, kf, vf, sst, obuf);
  gemm_bt<0><<<dim3(8, 32), dim3(256), 0, stream>>>(
      obuf, woT, out, nullptr, nullptr, nullptr, 4096, 1024, 1024);
}

// Round 8
// 98.247 us; speedup vs baseline: 3.3192x; 1.1228x over previous
//
#include <hip/hip_runtime.h>
#include <hip/hip_bf16.h>
#include <type_traits>

#define DI __device__ __forceinline__

typedef unsigned short u16;
typedef unsigned int u32;
typedef __bf16 bf16x8 __attribute__((ext_vector_type(8)));
typedef u16 u16x8 __attribute__((ext_vector_type(8)));
typedef float f32x4 __attribute__((ext_vector_type(4)));
typedef float f32x16 __attribute__((ext_vector_type(16)));
typedef u32 u32x2 __attribute__((ext_vector_type(2)));
typedef u32 u32x4 __attribute__((ext_vector_type(4)));

constexpr int Bb = 2, Ls = 2048, Hh = 16, KVh = 4, HD = 64;
constexpr float LOG2E = 1.44269504088896f;

DI u16 f2bf(float f) {
  __hip_bfloat16 h = __float2bfloat16(f);
  return __builtin_bit_cast(u16, h);
}

// packed f32x2 -> bf16x2 (RNE), single VOP3 op
DI u32 cvtpk(float lo, float hi) {
  u32 r;
  asm("v_cvt_pk_bf16_f32 %0, %1, %2" : "=v"(r) : "v"(lo), "v"(hi));
  return r;
}

DI f32x4 mfma16(bf16x8 a, bf16x8 b, f32x4 c) {
  return __builtin_amdgcn_mfma_f32_16x16x32_bf16(a, b, c, 0, 0, 0);
}
DI f32x16 mfma32(bf16x8 a, bf16x8 b, f32x16 c) {
  return __builtin_amdgcn_mfma_f32_32x32x16_bf16(a, b, c, 0, 0, 0);
}
DI bf16x8 bc(u32x4 v) { return __builtin_bit_cast(bf16x8, v); }

// async global->LDS, 16B per lane; LDS dest = wave-uniform base + lane*16
DI void gld16(const u16* g, u16* l) {
  __builtin_amdgcn_global_load_lds(
      (const __attribute__((address_space(1))) u32*)g,
      (__attribute__((address_space(3))) u32*)l, 16, 0, 0);
}

// ---- fused conversions ----------------------------------------------------
// blocks [0,4096): hs f32 -> bf16 (vec4/thread)
// blocks [4096,4112): segment starts (binary search; segments sorted)
__global__ void cvt_hs_seg(const float* __restrict__ in, u16* __restrict__ out,
                           const int* __restrict__ seg, int* __restrict__ sst) {
  int bid = blockIdx.x;
  if (bid < 4096) {
    int i = bid * 256 + threadIdx.x;
    float4 v = reinterpret_cast<const float4*>(in)[i];
    ushort4 o;
    o.x = f2bf(v.x); o.y = f2bf(v.y); o.z = f2bf(v.z); o.w = f2bf(v.w);
    reinterpret_cast<ushort4*>(out)[i] = o;
  } else {
    int idx = bid - 4096;
    int b = idx >> 3;
    int l = (idx & 7) * 256 + threadIdx.x;
    const int* s = seg + b * Ls;
    int v = s[l];
    int lo = 0, hi = l;
    while (lo < hi) {
      int mid = (lo + hi) >> 1;
      if (s[mid] < v) lo = mid + 1; else hi = mid;
    }
    sst[b * Ls + l] = lo;
  }
}

// all 4 weight transposes in one launch; z selects the matrix
__global__ void cvt_w_all(const float* __restrict__ Wq,
                          const float* __restrict__ Wk,
                          const float* __restrict__ Wv,
                          const float* __restrict__ Wo,
                          u16* __restrict__ wqkvT, u16* __restrict__ woT) {
  __shared__ u16 t[32][33];
  const int z = blockIdx.z;
  const float* in = (z == 0) ? Wq : (z == 1) ? Wk : (z == 2) ? Wv : Wo;
  u16* out = (z == 3) ? woT : wqkvT;
  const int N = (z == 1 || z == 2) ? 256 : 1024;
  const int rowoff = (z == 1) ? 1024 : (z == 2) ? 1280 : 0;
  if (blockIdx.x * 32 >= N) return;
  int k0 = blockIdx.y * 32, n0 = blockIdx.x * 32;
  int tx = threadIdx.x & 31, ty = threadIdx.x >> 5;
#pragma unroll
  for (int i = ty; i < 32; i += 8)
    t[i][tx] = f2bf(in[(size_t)(k0 + i) * N + n0 + tx]);
  __syncthreads();
#pragma unroll
  for (int i = ty; i < 32; i += 8)
    out[(size_t)(rowoff + n0 + i) * 1024 + k0 + tx] = t[tx][i];
}

// ---- GEMM: A[M][K] bf16 * Bt[N][K] bf16, 8-wave 128x128, 2-phase dbuf ----
// 512 threads: wave w -> (wm=w>>2)*64 rows, (wn=w&3)*32 cols.
// MODE 0: C[M][N] float.  MODE 1 (qkv): scatter into fragment-linear Qf/Kf/Vf.
template <int MODE>
__global__ __launch_bounds__(512) void gemm_bt(
    const u16* __restrict__ A, const u16* __restrict__ Bt,
    float* __restrict__ C, u16* __restrict__ Qf, u16* __restrict__ Kf,
    u16* __restrict__ Vf, int M, int N, int K) {
  __shared__ u16 lA[2][128 * 32];
  __shared__ u16 lB[2][128 * 32];
  const int m0 = blockIdx.y * 128, n0 = blockIdx.x * 128;
  const int tid = threadIdx.x;
  const int lane = tid & 63;
  const int wr = ((tid >> 8) & 1) * 64;         // wm = w>>2
  const int wc = ((tid >> 6) & 3) * 32;         // wn = w&3
  const int lr = lane & 15, lk = (lane >> 4) * 8;
  const int r0 = tid >> 2, c0 = (tid & 3) * 8;  // staging: full 128x32 tile
  const int woff = (tid & 0x1C0) << 4;          // wave-uniform LDS byte base
  const u16* pA0 = &A[(size_t)(m0 + r0) * K + c0];
  const u16* pB0 = &Bt[(size_t)(n0 + r0) * K + c0];

  auto stage = [&](int buf, int k0) {
    gld16(pA0 + k0, (u16*)((char*)lA[buf] + woff));
    gld16(pB0 + k0, (u16*)((char*)lB[buf] + woff));
  };

  f32x4 acc[4][2] = {};
  stage(0, 0);
  __syncthreads();
  int cur = 0;
  for (int k0 = 0; k0 < K; k0 += 32, cur ^= 1) {
    if (k0 + 32 < K) stage(cur ^ 1, k0 + 32);   // prefetch next K-step
    bf16x8 af[4], bfv[2];
#pragma unroll
    for (int m = 0; m < 4; m++)
      af[m] = *reinterpret_cast<const bf16x8*>(
          &lA[cur][(wr + m * 16 + lr) * 32 + lk]);
#pragma unroll
    for (int n = 0; n < 2; n++)
      bfv[n] = *reinterpret_cast<const bf16x8*>(
          &lB[cur][(wc + n * 16 + lr) * 32 + lk]);
#pragma unroll
    for (int m = 0; m < 4; m++)
#pragma unroll
      for (int n = 0; n < 2; n++)
        acc[m][n] = mfma16(af[m], bfv[n], acc[m][n]);
    __syncthreads();
  }

  const int rr = (lane >> 4) * 4, cc = lane & 15;
#pragma unroll
  for (int m = 0; m < 4; m++) {
    int row0 = m0 + wr + m * 16 + rr;
#pragma unroll
    for (int n = 0; n < 2; n++) {
      int col = n0 + wc + n * 16 + cc;
      if constexpr (MODE == 0) {
#pragma unroll
        for (int r = 0; r < 4; r++)
          C[(size_t)(row0 + r) * N + col] = acc[m][n][r];
      } else {
        int bb = row0 >> 11, l = row0 & 2047;
        int d = col & 63, c8 = d >> 3, d7 = d & 7;
        int kt = l >> 5, r32 = l & 31;
        if (col < 1024) {
          int hd = col >> 6;
          u16* base = &Qf[((((size_t)(bb * 16 + hd) * 64 + kt) << 11)) +
                          ((c8 * 32 + r32) << 3) + d7];
#pragma unroll
          for (int r = 0; r < 4; r++) base[r * 8] = f2bf(acc[m][n][r]);
        } else if (col < 1280) {
          int kv = (col - 1024) >> 6;
          u16* base = &Kf[((((size_t)(bb * 4 + kv) * 64 + kt) << 11)) +
                          ((c8 * 32 + r32) << 3) + d7];
#pragma unroll
          for (int r = 0; r < 4; r++) base[r * 8] = f2bf(acc[m][n][r]);
        } else {
          int kv = (col - 1280) >> 6;
          ushort4 pv;
          pv.x = f2bf(acc[m][n][0]); pv.y = f2bf(acc[m][n][1]);
          pv.z = f2bf(acc[m][n][2]); pv.w = f2bf(acc[m][n][3]);
          *reinterpret_cast<ushort4*>(
              &Vf[((((size_t)(bb * 4 + kv) * 64 + kt) << 11)) +
                  ((((l >> 3) & 3) * 64 + d) << 3) + (l & 7)]) = pv;
        }
      }
    }
  }
}

// ---- flash attention: swapped 32x32, q-PAIR per wave, shared K/V ---------
__global__ __launch_bounds__(64) void attn(
    const u16* __restrict__ Qf, const u16* __restrict__ Kf,
    const u16* __restrict__ Vf, const int* __restrict__ sst,
    u16* __restrict__ Obuf) {
  const int qp = 31 - blockIdx.x;               // big blocks dispatch first
  const int h = blockIdx.y, b = blockIdx.z;
  const int kvh = h >> 2;
  const int lane = threadIdx.x;
  const int qi = lane & 31, hi = lane >> 5;
  const int qwA = qp * 64, qwB = qwA + 32;
  const int qA = qwA + qi, qB = qwB + qi;
  const float slope = __builtin_amdgcn_exp2f(-0.5f * (float)(h + 1));
  const float SL = slope * LOG2E;
  const float SL32 = 32.f * SL;
  const float Cs = 0.125f * LOG2E;
  const u16* Qtile = Qf + (((size_t)(b * Hh + h) * 64) << 11);
  const u16* Kbase = Kf + (((size_t)(b * KVh + kvh) * 64) << 11);
  const u16* Vbase = Vf + (((size_t)(b * KVh + kvh) * 64) << 11);

  bf16x8 qfA[4], qfB[4];
  {
    const u16* QtA = Qtile + ((size_t)(2 * qp) << 11);
    const u16* QtB = Qtile + ((size_t)(2 * qp + 1) << 11);
#pragma unroll
    for (int c = 0; c < 4; c++) {
      qfA[c] = *reinterpret_cast<const bf16x8*>(&QtA[((2 * c + hi) * 32 + qi) * 8]);
      qfB[c] = *reinterpret_cast<const bf16x8*>(&QtB[((2 * c + hi) * 32 + qi) * 8]);
    }
  }

  const int startA = sst[b * Ls + qA];
  const int startB = sst[b * Ls + qB];
  const int smaxA = __shfl(startA, 31);
  const int smaxB = __shfl(startB, 31);
  const int k_begin = __shfl(startA, 0) & ~31;
  const int kBbeg = __shfl(startB, 0) & ~31;

  float krsl[16];
#pragma unroll
  for (int r = 0; r < 16; r++)
    krsl[r] = (float)((r & 3) + 8 * (r >> 2) + 4 * hi) * SL;
  float biasA = (float)(k_begin - qA) * SL;     // (kk - q)*SL - m_run
  float biasB = (float)(k_begin - qB) * SL;
  float lA = 0.f, lB = 0.f;
  f32x16 oAlo = {}, oAhi = {}, oBlo = {}, oBhi = {};

  auto KLD = [&](int kt, u32x4* dst) {
    const u16* p = Kbase + ((size_t)kt << 11);
#pragma unroll
    for (int c = 0; c < 4; c++)
      dst[c] = *reinterpret_cast<const u32x4*>(&p[((2 * c + hi) * 32 + qi) * 8]);
  };
  auto VLD = [&](int kt, u32x4* dst) {
    const u16* p = Vbase + ((size_t)kt << 11);
#pragma unroll
    for (int j = 0; j < 4; j++) {
      int off = ((((j & 1) * 2 + hi) * 64) + (j >> 1) * 32 + qi) * 8;
      dst[j] = *reinterpret_cast<const u32x4*>(&p[off]);
    }
  };

  auto body = [&](int kk, u32x4* KR, u32x4* VR) {
    const bool actA = (kk <= qwA);
    const bool actB = (kk >= kBbeg);
    f32x16 aA = {}, aB = {};
    __builtin_amdgcn_s_setprio(1);
    if (actA) {
#pragma unroll
      for (int c = 0; c < 4; c++) aA = mfma32(bc(KR[c]), qfA[c], aA);
    }
    if (actB) {
#pragma unroll
      for (int c = 0; c < 4; c++) aB = mfma32(bc(KR[c]), qfB[c], aB);
    }
    __builtin_amdgcn_s_setprio(0);
    const int kt2 = min(kk + 64, qwB) >> 5;
    KLD(kt2, KR);                               // hidden under softmax+PV

    u32x4 fA0, fA1, fB0, fB1;
    if (actA) {
      float t[16];
#pragma unroll
      for (int r = 0; r < 16; r++) t[r] = fmaf(aA[r], Cs, biasA) + krsl[r];
      if (!(kk >= smaxA && kk < qwA)) {
#pragma unroll
        for (int r = 0; r < 16; r++) {
          int j = kk + (r & 3) + 8 * (r >> 2) + 4 * hi;
          t[r] = (j >= startA && j <= qA) ? t[r] : -3.0e38f;
        }
      }
      float mt = fmaxf(t[0], t[1]);
#pragma unroll
      for (int r = 2; r < 16; r++) mt = fmaxf(mt, t[r]);
      mt = fmaxf(mt, __shfl_xor(mt, 32));
      if (!__all(mt <= 8.f)) {
        float dm = fmaxf(mt, 0.f);
        float fac = __builtin_amdgcn_exp2f(-dm);
        biasA -= dm; lA *= fac;
#pragma unroll
        for (int r = 0; r < 16; r++) { oAlo[r] *= fac; oAhi[r] *= fac; t[r] -= dm; }
      }
      float p[16];
#pragma unroll
      for (int r = 0; r < 16; r++) p[r] = __builtin_amdgcn_exp2f(t[r]);
      float ts = 0.f;
#pragma unroll
      for (int r = 0; r < 16; r++) ts += p[r];
      lA += ts + __shfl_xor(ts, 32);
      u32 pk[8], sw[8];
#pragma unroll
      for (int i = 0; i < 8; i++) pk[i] = cvtpk(p[2 * i], p[2 * i + 1]);
#pragma unroll
      for (int i = 0; i < 8; i++) sw[i] = __shfl_xor(pk[i], 32);
      fA0 = u32x4{ hi ? sw[2] : pk[0], hi ? sw[3] : pk[1],
                   hi ? pk[2] : sw[0], hi ? pk[3] : sw[1] };
      fA1 = u32x4{ hi ? sw[6] : pk[4], hi ? sw[7] : pk[5],
                   hi ? pk[6] : sw[4], hi ? pk[7] : sw[5] };
    }
    if (actB) {
      float t[16];
#pragma unroll
      for (int r = 0; r < 16; r++) t[r] = fmaf(aB[r], Cs, biasB) + krsl[r];
      if (!(kk >= smaxB && kk < qwB)) {
#pragma unroll
        for (int r = 0; r < 16; r++) {
          int j = kk + (r & 3) + 8 * (r >> 2) + 4 * hi;
          t[r] = (j >= startB && j <= qB) ? t[r] : -3.0e38f;
        }
      }
      float mt = fmaxf(t[0], t[1]);
#pragma unroll
      for (int r = 2; r < 16; r++) mt = fmaxf(mt, t[r]);
      mt = fmaxf(mt, __shfl_xor(mt, 32));
      if (!__all(mt <= 8.f)) {
        float dm = fmaxf(mt, 0.f);
        float fac = __builtin_amdgcn_exp2f(-dm);
        biasB -= dm; lB *= fac;
#pragma unroll
        for (int r = 0; r < 16; r++) { oBlo[r] *= fac; oBhi[r] *= fac; t[r] -= dm; }
      }
      float p[16];
#pragma unroll
      for (int r = 0; r < 16; r++) p[r] = __builtin_amdgcn_exp2f(t[r]);
      float ts = 0.f;
#pragma unroll
      for (int r = 0; r < 16; r++) ts += p[r];
      lB += ts + __shfl_xor(ts, 32);
      u32 pk[8], sw[8];
#pragma unroll
      for (int i = 0; i < 8; i++) pk[i] = cvtpk(p[2 * i], p[2 * i + 1]);
#pragma unroll
      for (int i = 0; i < 8; i++) sw[i] = __shfl_xor(pk[i], 32);
      fB0 = u32x4{ hi ? sw[2] : pk[0], hi ? sw[3] : pk[1],
                   hi ? pk[2] : sw[0], hi ? pk[3] : sw[1] };
      fB1 = u32x4{ hi ? sw[6] : pk[4], hi ? sw[7] : pk[5],
                   hi ? pk[6] : sw[4], hi ? pk[7] : sw[5] };
    }
    __builtin_amdgcn_s_setprio(1);
    if (actA) {
      oAlo = mfma32(bc(VR[0]), bc(fA0), oAlo);
      oAlo = mfma32(bc(VR[1]), bc(fA1), oAlo);
      oAhi = mfma32(bc(VR[2]), bc(fA0), oAhi);
      oAhi = mfma32(bc(VR[3]), bc(fA1), oAhi);
    }
    if (actB) {
      oBlo = mfma32(bc(VR[0]), bc(fB0), oBlo);
      oBlo = mfma32(bc(VR[1]), bc(fB1), oBlo);
      oBhi = mfma32(bc(VR[2]), bc(fB0), oBhi);
      oBhi = mfma32(bc(VR[3]), bc(fB1), oBhi);
    }
    __builtin_amdgcn_s_setprio(0);
    VLD(kt2, VR);                               // prefetch next V
    biasA += SL32; biasB += SL32;
  };

  u32x4 KR0[4], VR0[4], KR1[4], VR1[4];
  {
    const int kt0 = k_begin >> 5;
    const int kt1 = min(k_begin + 32, qwB) >> 5;
    KLD(kt0, KR0); VLD(kt0, VR0);
    KLD(kt1, KR1); VLD(kt1, VR1);
  }
  int kk = k_begin;
  while (true) {
    body(kk, KR0, VR0);
    if (kk + 32 > qwB) break;
    body(kk + 32, KR1, VR1);
    if (kk + 64 > qwB) break;
    kk += 64;
  }

  const float invA = __builtin_amdgcn_rcpf(lA);
  const float invB = __builtin_amdgcn_rcpf(lB);
  const size_t orowA = (size_t)(b * Ls + qA) * 1024 + h * 64;
  const size_t orowB = (size_t)(b * Ls + qB) * 1024 + h * 64;
#pragma unroll
  for (int g = 0; g < 4; g++) {
    int d0 = g * 8 + hi * 4;
    u32x2 pa = { cvtpk(oAlo[4 * g + 0] * invA, oAlo[4 * g + 1] * invA),
                 cvtpk(oAlo[4 * g + 2] * invA, oAlo[4 * g + 3] * invA) };
    u32x2 pb = { cvtpk(oAhi[4 * g + 0] * invA, oAhi[4 * g + 1] * invA),
                 cvtpk(oAhi[4 * g + 2] * invA, oAhi[4 * g + 3] * invA) };
    *reinterpret_cast<u32x2*>(&Obuf[orowA + d0]) = pa;
    *reinterpret_cast<u32x2*>(&Obuf[orowA + 32 + d0]) = pb;
    u32x2 qa = { cvtpk(oBlo[4 * g + 0] * invB, oBlo[4 * g + 1] * invB),
                 cvtpk(oBlo[4 * g + 2] * invB, oBlo[4 * g + 3] * invB) };
    u32x2 qb = { cvtpk(oBhi[4 * g + 0] * invB, oBhi[4 * g + 1] * invB),
                 cvtpk(oBhi[4 * g + 2] * invB, oBhi[4 * g + 3] * invB) };
    *reinterpret_cast<u32x2*>(&Obuf[orowB + d0]) = qa;
    *reinterpret_cast<u32x2*>(&Obuf[orowB + 32 + d0]) = qb;
  }
}

// ---- launch ---------------------------------------------------------------
extern "C" void kernel_launch(void* const* d_in, const int* in_sizes, int n_in,
                              void* d_out, int out_size, void* d_ws, size_t ws_size,
                              hipStream_t stream) {
  const float* hs = (const float*)d_in[0];
  const int* seg = (const int*)d_in[1];
  const float* Wq = (const float*)d_in[2];
  const float* Wk = (const float*)d_in[3];
  const float* Wv = (const float*)d_in[4];
  const float* Wo = (const float*)d_in[5];
  float* out = (float*)d_out;
  char* ws = (char*)d_ws;
  // hsb 8.4M | wqkvT 3.1M | woT 2.1M | Qf 8.4M | Kf 2.1M | Vf 2.1M | sst 16K
  u16* hsb   = (u16*)(ws);
  u16* wqkvT = (u16*)(ws + 8388608);
  u16* woT   = (u16*)(ws + 11534336);
  u16* qf    = (u16*)(ws + 13631488);
  u16* kf    = (u16*)(ws + 22020096);
  u16* vf    = (u16*)(ws + 24117248);
  int* sst   = (int*)(ws + 26214400);
  u16* obuf  = hsb;   // hsb dead after GEMM1

  cvt_hs_seg<<<dim3(4112), dim3(256), 0, stream>>>(hs, hsb, seg, sst);
  cvt_w_all<<<dim3(32, 32, 4), dim3(256), 0, stream>>>(Wq, Wk, Wv, Wo,
                                                       wqkvT, woT);
  gemm_bt<1><<<dim3(12, 32), dim3(512), 0, stream>>>(
      hsb, wqkvT, nullptr, qf, kf, vf, 4096, 1536, 1024);
  attn<<<dim3(32, 16, 2), dim3(64), 0, stream>>>(qf, kf, vf, sst, obuf);
  gemm_bt<0><<<dim3(8, 32), dim3(512), 0, stream>>>(
      obuf, woT, out, nullptr, nullptr, nullptr, 4096, 1024, 1024);
}

// Round 9
// 91.092 us; speedup vs baseline: 3.5799x; 1.0785x over previous
//
#include <hip/hip_runtime.h>
#include <hip/hip_bf16.h>
#include <type_traits>

#define DI __device__ __forceinline__

typedef unsigned short u16;
typedef unsigned int u32;
typedef __bf16 bf16x8 __attribute__((ext_vector_type(8)));
typedef u16 u16x8 __attribute__((ext_vector_type(8)));
typedef float f32x4 __attribute__((ext_vector_type(4)));
typedef float f32x16 __attribute__((ext_vector_type(16)));
typedef u32 u32x2 __attribute__((ext_vector_type(2)));
typedef u32 u32x4 __attribute__((ext_vector_type(4)));

constexpr int Bb = 2, Ls = 2048, Hh = 16, KVh = 4, HD = 64;
constexpr float LOG2E = 1.44269504088896f;
constexpr float RSQ2 = 0.70710678118654752f;   // slope ratio between heads

DI u16 f2bf(float f) {
  __hip_bfloat16 h = __float2bfloat16(f);
  return __builtin_bit_cast(u16, h);
}

// packed f32x2 -> bf16x2 (RNE), single VOP3 op
DI u32 cvtpk(float lo, float hi) {
  u32 r;
  asm("v_cvt_pk_bf16_f32 %0, %1, %2" : "=v"(r) : "v"(lo), "v"(hi));
  return r;
}

DI f32x4 mfma16(bf16x8 a, bf16x8 b, f32x4 c) {
  return __builtin_amdgcn_mfma_f32_16x16x32_bf16(a, b, c, 0, 0, 0);
}
DI f32x16 mfma32(bf16x8 a, bf16x8 b, f32x16 c) {
  return __builtin_amdgcn_mfma_f32_32x32x16_bf16(a, b, c, 0, 0, 0);
}
DI bf16x8 bc(u32x4 v) { return __builtin_bit_cast(bf16x8, v); }

// async global->LDS, 16B per lane; LDS dest = wave-uniform base + lane*16
DI void gld16(const u16* g, u16* l) {
  __builtin_amdgcn_global_load_lds(
      (const __attribute__((address_space(1))) u32*)g,
      (__attribute__((address_space(3))) u32*)l, 16, 0, 0);
}

// ---- fused prep: hs cvt + seg starts + all 4 weight transposes -----------
// blocks [0,4096): hs f32->bf16 ; [4096,4112): seg starts ;
// [4112, 4112+2560): 32x32 transpose tiles (Wq 1024 | Wk 256 | Wv 256 | Wo 1024)
__global__ void prep(const float* __restrict__ hs, u16* __restrict__ hsb,
                     const int* __restrict__ seg, int* __restrict__ sst,
                     const float* __restrict__ Wq, const float* __restrict__ Wk,
                     const float* __restrict__ Wv, const float* __restrict__ Wo,
                     u16* __restrict__ wqkvT, u16* __restrict__ woT) {
  int bid = blockIdx.x;
  if (bid < 4096) {
    int i = bid * 256 + threadIdx.x;
    float4 v = reinterpret_cast<const float4*>(hs)[i];
    ushort4 o;
    o.x = f2bf(v.x); o.y = f2bf(v.y); o.z = f2bf(v.z); o.w = f2bf(v.w);
    reinterpret_cast<ushort4*>(hsb)[i] = o;
    return;
  }
  if (bid < 4112) {
    int idx = bid - 4096;
    int b = idx >> 3;
    int l = (idx & 7) * 256 + threadIdx.x;
    const int* s = seg + b * Ls;
    int v = s[l];
    int lo = 0, hi = l;
    while (lo < hi) {
      int mid = (lo + hi) >> 1;
      if (s[mid] < v) lo = mid + 1; else hi = mid;
    }
    sst[b * Ls + l] = lo;
    return;
  }
  int t = bid - 4112;
  const float* in; u16* out; int N, rowoff, x, y;
  if (t < 1024)      { in = Wq; out = wqkvT; N = 1024; rowoff = 0;
                       x = t & 31; y = t >> 5; }
  else if (t < 1280) { in = Wk; out = wqkvT; N = 256; rowoff = 1024;
                       int u = t - 1024; x = u & 7; y = u >> 3; }
  else if (t < 1536) { in = Wv; out = wqkvT; N = 256; rowoff = 1280;
                       int u = t - 1280; x = u & 7; y = u >> 3; }
  else               { in = Wo; out = woT; N = 1024; rowoff = 0;
                       int u = t - 1536; x = u & 31; y = u >> 5; }
  __shared__ u16 tl[32][33];
  int k0 = y * 32, n0 = x * 32;
  int tx = threadIdx.x & 31, ty = threadIdx.x >> 5;
#pragma unroll
  for (int i = ty; i < 32; i += 8)
    tl[i][tx] = f2bf(in[(size_t)(k0 + i) * N + n0 + tx]);
  __syncthreads();
#pragma unroll
  for (int i = ty; i < 32; i += 8)
    out[(size_t)(rowoff + n0 + i) * 1024 + k0 + tx] = tl[tx][i];
}

// ---- GEMM: A[M][K] bf16 * Bt[N][K] bf16, 8-wave 128x128, counted vmcnt ---
// 2-phase dbuf; barrier waits vmcnt(2) (keeps the just-issued prefetch in
// flight) instead of __syncthreads' vmcnt(0) drain.
// MODE 0: C[M][N] float.  MODE 1 (qkv): scatter into fragment-linear Qf/Kf/Vf.
template <int MODE>
__global__ __launch_bounds__(512) void gemm_bt(
    const u16* __restrict__ A, const u16* __restrict__ Bt,
    float* __restrict__ C, u16* __restrict__ Qf, u16* __restrict__ Kf,
    u16* __restrict__ Vf, int M, int N, int K) {
  __shared__ u16 lA[2][128 * 32];
  __shared__ u16 lB[2][128 * 32];
  const int m0 = blockIdx.y * 128, n0 = blockIdx.x * 128;
  const int tid = threadIdx.x;
  const int lane = tid & 63;
  const int wr = ((tid >> 8) & 1) * 64;         // wm = w>>2
  const int wc = ((tid >> 6) & 3) * 32;         // wn = w&3
  const int lr = lane & 15, lk = (lane >> 4) * 8;
  const int r0 = tid >> 2, c0 = (tid & 3) * 8;  // staging: full 128x32 tile
  const int woff = (tid & 0x1C0) << 4;          // wave-uniform LDS byte base
  const u16* pA0 = &A[(size_t)(m0 + r0) * K + c0];
  const u16* pB0 = &Bt[(size_t)(n0 + r0) * K + c0];

  auto stage = [&](int buf, int k0) {
    gld16(pA0 + k0, (u16*)((char*)lA[buf] + woff));
    gld16(pB0 + k0, (u16*)((char*)lB[buf] + woff));
  };

  f32x4 acc[4][2] = {};
  stage(0, 0);
  int cur = 0;
  for (int k0 = 0; k0 < K; k0 += 32, cur ^= 1) {
    if (k0 + 32 < K) {
      stage(cur ^ 1, k0 + 32);                  // prefetch next K-step
      asm volatile("s_waitcnt vmcnt(2)" ::: "memory");  // cur landed; keep 2 in flight
    } else {
      asm volatile("s_waitcnt vmcnt(0)" ::: "memory");
    }
    __builtin_amdgcn_s_barrier();
    bf16x8 af[4], bfv[2];
#pragma unroll
    for (int m = 0; m < 4; m++)
      af[m] = *reinterpret_cast<const bf16x8*>(
          &lA[cur][(wr + m * 16 + lr) * 32 + lk]);
#pragma unroll
    for (int n = 0; n < 2; n++)
      bfv[n] = *reinterpret_cast<const bf16x8*>(
          &lB[cur][(wc + n * 16 + lr) * 32 + lk]);
#pragma unroll
    for (int m = 0; m < 4; m++)
#pragma unroll
      for (int n = 0; n < 2; n++)
        acc[m][n] = mfma16(af[m], bfv[n], acc[m][n]);
    asm volatile("" ::: "memory");
    __builtin_amdgcn_s_barrier();               // reads done before re-stage
  }

  const int rr = (lane >> 4) * 4, cc = lane & 15;
#pragma unroll
  for (int m = 0; m < 4; m++) {
    int row0 = m0 + wr + m * 16 + rr;
#pragma unroll
    for (int n = 0; n < 2; n++) {
      int col = n0 + wc + n * 16 + cc;
      if constexpr (MODE == 0) {
#pragma unroll
        for (int r = 0; r < 4; r++)
          C[(size_t)(row0 + r) * N + col] = acc[m][n][r];
      } else {
        int bb = row0 >> 11, l = row0 & 2047;
        int d = col & 63, c8 = d >> 3, d7 = d & 7;
        int kt = l >> 5, r32 = l & 31;
        if (col < 1024) {
          int hd = col >> 6;
          u16* base = &Qf[((((size_t)(bb * 16 + hd) * 64 + kt) << 11)) +
                          ((c8 * 32 + r32) << 3) + d7];
#pragma unroll
          for (int r = 0; r < 4; r++) base[r * 8] = f2bf(acc[m][n][r]);
        } else if (col < 1280) {
          int kv = (col - 1024) >> 6;
          u16* base = &Kf[((((size_t)(bb * 4 + kv) * 64 + kt) << 11)) +
                          ((c8 * 32 + r32) << 3) + d7];
#pragma unroll
          for (int r = 0; r < 4; r++) base[r * 8] = f2bf(acc[m][n][r]);
        } else {
          int kv = (col - 1280) >> 6;
          ushort4 pv;
          pv.x = f2bf(acc[m][n][0]); pv.y = f2bf(acc[m][n][1]);
          pv.z = f2bf(acc[m][n][2]); pv.w = f2bf(acc[m][n][3]);
          *reinterpret_cast<ushort4*>(
              &Vf[((((size_t)(bb * 4 + kv) * 64 + kt) << 11)) +
                  ((((l >> 3) & 3) * 64 + d) << 3) + (l & 7)]) = pv;
        }
      }
    }
  }
}

// ---- flash attention: swapped 32x32, HEAD-PAIR per wave, shared K/V ------
// Wave owns q-tile qt for heads {2g, 2g+1}: same KV head, same span, same
// mask -> both chains always active, mask computed once, K/V regs shared.
// Slopes differ by 2^-0.5: chain B bias derives from chain A's krsl by mul.
__global__ __launch_bounds__(64, 1) void attn(
    const u16* __restrict__ Qf, const u16* __restrict__ Kf,
    const u16* __restrict__ Vf, const int* __restrict__ sst,
    u16* __restrict__ Obuf) {
  const int qt = 63 - blockIdx.x;               // big blocks dispatch first
  const int hp = blockIdx.y, b = blockIdx.z;
  const int h0 = hp << 1;
  const int kvh = h0 >> 2;
  const int lane = threadIdx.x;
  const int qi = lane & 31, hi = lane >> 5;
  const int qw = qt * 32;
  const int q = qw + qi;
  const float slope0 = __builtin_amdgcn_exp2f(-0.5f * (float)(h0 + 1));
  const float SL0 = slope0 * LOG2E;
  const float SL1 = SL0 * RSQ2;
  const float SL0x32 = 32.f * SL0, SL1x32 = 32.f * SL1;
  const float Cs = 0.125f * LOG2E;
  const u16* Qt0 = Qf + (((size_t)(b * Hh + h0) * 64 + qt) << 11);
  const u16* Qt1 = Qt0 + ((size_t)64 << 11);    // head h0+1
  const u16* Kbase = Kf + (((size_t)(b * KVh + kvh) * 64) << 11);
  const u16* Vbase = Vf + (((size_t)(b * KVh + kvh) * 64) << 11);

  bf16x8 qfA[4], qfB[4];
#pragma unroll
  for (int c = 0; c < 4; c++) {
    qfA[c] = *reinterpret_cast<const bf16x8*>(&Qt0[((2 * c + hi) * 32 + qi) * 8]);
    qfB[c] = *reinterpret_cast<const bf16x8*>(&Qt1[((2 * c + hi) * 32 + qi) * 8]);
  }

  const int start = sst[b * Ls + q];
  const int smax = __shfl(start, 31);
  const int k_begin = __shfl(start, 0) & ~31;

  float krsl[16];                               // krow * SL0 (chain A)
#pragma unroll
  for (int r = 0; r < 16; r++)
    krsl[r] = (float)((r & 3) + 8 * (r >> 2) + 4 * hi) * SL0;
  float biasA = (float)(k_begin - q) * SL0;     // (kk - q)*SL - m_run (folded)
  float biasB = (float)(k_begin - q) * SL1;
  float lA = 0.f, lB = 0.f;
  f32x16 oAlo = {}, oAhi = {}, oBlo = {}, oBhi = {};

  auto KLD = [&](int kt, u32x4* dst) {
    const u16* p = Kbase + ((size_t)kt << 11);
#pragma unroll
    for (int c = 0; c < 4; c++)
      dst[c] = *reinterpret_cast<const u32x4*>(&p[((2 * c + hi) * 32 + qi) * 8]);
  };
  auto VLD = [&](int kt, u32x4* dst) {
    const u16* p = Vbase + ((size_t)kt << 11);
#pragma unroll
    for (int j = 0; j < 4; j++) {
      int off = ((((j & 1) * 2 + hi) * 64) + (j >> 1) * 32 + qi) * 8;
      dst[j] = *reinterpret_cast<const u32x4*>(&p[off]);
    }
  };

  auto body = [&](int kk, u32x4* KR, u32x4* VR) {
    f32x16 aA = {}, aB = {};
    __builtin_amdgcn_s_setprio(1);
#pragma unroll
    for (int c = 0; c < 4; c++) aA = mfma32(bc(KR[c]), qfA[c], aA);
#pragma unroll
    for (int c = 0; c < 4; c++) aB = mfma32(bc(KR[c]), qfB[c], aB);
    __builtin_amdgcn_s_setprio(0);
    const int kt2 = min(kk + 64, qw) >> 5;
    KLD(kt2, KR);                               // hidden under softmax+PV

    float tA[16], tB[16];
#pragma unroll
    for (int r = 0; r < 16; r++) {
      tA[r] = fmaf(aA[r], Cs, biasA) + krsl[r];
      tB[r] = fmaf(aB[r], Cs, biasB) + krsl[r] * RSQ2;
    }
    if (!(kk >= smax && kk < qw)) {             // mask once for both heads
#pragma unroll
      for (int r = 0; r < 16; r++) {
        int j = kk + (r & 3) + 8 * (r >> 2) + 4 * hi;
        bool v = (j >= start) && (j <= q);
        tA[r] = v ? tA[r] : -3.0e38f;
        tB[r] = v ? tB[r] : -3.0e38f;
      }
    }
    {
      float mt = fmaxf(tA[0], tA[1]);
#pragma unroll
      for (int r = 2; r < 16; r++) mt = fmaxf(mt, tA[r]);
      mt = fmaxf(mt, __shfl_xor(mt, 32));
      if (!__all(mt <= 8.f)) {                  // rare defer-max rescale
        float dm = fmaxf(mt, 0.f);
        float fac = __builtin_amdgcn_exp2f(-dm);
        biasA -= dm; lA *= fac;
#pragma unroll
        for (int r = 0; r < 16; r++) { oAlo[r] *= fac; oAhi[r] *= fac; tA[r] -= dm; }
      }
    }
    {
      float mt = fmaxf(tB[0], tB[1]);
#pragma unroll
      for (int r = 2; r < 16; r++) mt = fmaxf(mt, tB[r]);
      mt = fmaxf(mt, __shfl_xor(mt, 32));
      if (!__all(mt <= 8.f)) {
        float dm = fmaxf(mt, 0.f);
        float fac = __builtin_amdgcn_exp2f(-dm);
        biasB -= dm; lB *= fac;
#pragma unroll
        for (int r = 0; r < 16; r++) { oBlo[r] *= fac; oBhi[r] *= fac; tB[r] -= dm; }
      }
    }
    float pA[16], pB[16];
#pragma unroll
    for (int r = 0; r < 16; r++) {
      pA[r] = __builtin_amdgcn_exp2f(tA[r]);
      pB[r] = __builtin_amdgcn_exp2f(tB[r]);
    }
    float tsA = 0.f, tsB = 0.f;
#pragma unroll
    for (int r = 0; r < 16; r++) { tsA += pA[r]; tsB += pB[r]; }
    lA += tsA + __shfl_xor(tsA, 32);
    lB += tsB + __shfl_xor(tsB, 32);

    u32 pkA[8], pkB[8], swA[8], swB[8];
#pragma unroll
    for (int i = 0; i < 8; i++) {
      pkA[i] = cvtpk(pA[2 * i], pA[2 * i + 1]);
      pkB[i] = cvtpk(pB[2 * i], pB[2 * i + 1]);
    }
#pragma unroll
    for (int i = 0; i < 8; i++) {
      swA[i] = __shfl_xor(pkA[i], 32);
      swB[i] = __shfl_xor(pkB[i], 32);
    }
    u32x4 fA0 = { hi ? swA[2] : pkA[0], hi ? swA[3] : pkA[1],
                  hi ? pkA[2] : swA[0], hi ? pkA[3] : swA[1] };
    u32x4 fA1 = { hi ? swA[6] : pkA[4], hi ? swA[7] : pkA[5],
                  hi ? pkA[6] : swA[4], hi ? pkA[7] : swA[5] };
    u32x4 fB0 = { hi ? swB[2] : pkB[0], hi ? swB[3] : pkB[1],
                  hi ? pkB[2] : swB[0], hi ? pkB[3] : swB[1] };
    u32x4 fB1 = { hi ? swB[6] : pkB[4], hi ? swB[7] : pkB[5],
                  hi ? pkB[6] : swB[4], hi ? pkB[7] : swB[5] };

    __builtin_amdgcn_s_setprio(1);
    oAlo = mfma32(bc(VR[0]), bc(fA0), oAlo);
    oAlo = mfma32(bc(VR[1]), bc(fA1), oAlo);
    oAhi = mfma32(bc(VR[2]), bc(fA0), oAhi);
    oAhi = mfma32(bc(VR[3]), bc(fA1), oAhi);
    oBlo = mfma32(bc(VR[0]), bc(fB0), oBlo);
    oBlo = mfma32(bc(VR[1]), bc(fB1), oBlo);
    oBhi = mfma32(bc(VR[2]), bc(fB0), oBhi);
    oBhi = mfma32(bc(VR[3]), bc(fB1), oBhi);
    __builtin_amdgcn_s_setprio(0);
    VLD(kt2, VR);                               // prefetch next V
    biasA += SL0x32; biasB += SL1x32;
  };

  u32x4 KR0[4], VR0[4], KR1[4], VR1[4];
  {
    const int kt0 = k_begin >> 5;
    const int kt1 = min(k_begin + 32, qw) >> 5;
    KLD(kt0, KR0); VLD(kt0, VR0);
    KLD(kt1, KR1); VLD(kt1, VR1);
  }
  int kk = k_begin;
  while (true) {
    body(kk, KR0, VR0);
    if (kk + 32 > qw) break;
    body(kk + 32, KR1, VR1);
    if (kk + 64 > qw) break;
    kk += 64;
  }

  const float invA = __builtin_amdgcn_rcpf(lA);
  const float invB = __builtin_amdgcn_rcpf(lB);
  const size_t orow = (size_t)(b * Ls + q) * 1024 + h0 * 64;
#pragma unroll
  for (int g = 0; g < 4; g++) {
    int d0 = g * 8 + hi * 4;
    u32x2 pa = { cvtpk(oAlo[4 * g + 0] * invA, oAlo[4 * g + 1] * invA),
                 cvtpk(oAlo[4 * g + 2] * invA, oAlo[4 * g + 3] * invA) };
    u32x2 pb = { cvtpk(oAhi[4 * g + 0] * invA, oAhi[4 * g + 1] * invA),
                 cvtpk(oAhi[4 * g + 2] * invA, oAhi[4 * g + 3] * invA) };
    *reinterpret_cast<u32x2*>(&Obuf[orow + d0]) = pa;
    *reinterpret_cast<u32x2*>(&Obuf[orow + 32 + d0]) = pb;
    u32x2 qa = { cvtpk(oBlo[4 * g + 0] * invB, oBlo[4 * g + 1] * invB),
                 cvtpk(oBlo[4 * g + 2] * invB, oBlo[4 * g + 3] * invB) };
    u32x2 qb = { cvtpk(oBhi[4 * g + 0] * invB, oBhi[4 * g + 1] * invB),
                 cvtpk(oBhi[4 * g + 2] * invB, oBhi[4 * g + 3] * invB) };
    *reinterpret_cast<u32x2*>(&Obuf[orow + 64 + d0]) = qa;
    *reinterpret_cast<u32x2*>(&Obuf[orow + 96 + d0]) = qb;
  }
}

// ---- launch ---------------------------------------------------------------
extern "C" void kernel_launch(void* const* d_in, const int* in_sizes, int n_in,
                              void* d_out, int out_size, void* d_ws, size_t ws_size,
                              hipStream_t stream) {
  const float* hs = (const float*)d_in[0];
  const int* seg = (const int*)d_in[1];
  const float* Wq = (const float*)d_in[2];
  const float* Wk = (const float*)d_in[3];
  const float* Wv = (const float*)d_in[4];
  const float* Wo = (const float*)d_in[5];
  float* out = (float*)d_out;
  char* ws = (char*)d_ws;
  // hsb 8.4M | wqkvT 3.1M | woT 2.1M | Qf 8.4M | Kf 2.1M | Vf 2.1M | sst 16K
  u16* hsb   = (u16*)(ws);
  u16* wqkvT = (u16*)(ws + 8388608);
  u16* woT   = (u16*)(ws + 11534336);
  u16* qf    = (u16*)(ws + 13631488);
  u16* kf    = (u16*)(ws + 22020096);
  u16* vf    = (u16*)(ws + 24117248);
  int* sst   = (int*)(ws + 26214400);
  u16* obuf  = hsb;   // hsb dead after GEMM1

  prep<<<dim3(6672), dim3(256), 0, stream>>>(hs, hsb, seg, sst,
                                             Wq, Wk, Wv, Wo, wqkvT, woT);
  gemm_bt<1><<<dim3(12, 32), dim3(512), 0, stream>>>(
      hsb, wqkvT, nullptr, qf, kf, vf, 4096, 1536, 1024);
  attn<<<dim3(64, 8, 2), dim3(64), 0, stream>>>(qf, kf, vf, sst, obuf);
  gemm_bt<0><<<dim3(8, 32), dim3(512), 0, stream>>>(
      obuf, woT, out, nullptr, nullptr, nullptr, 4096, 1024, 1024);
}

// Round 10
// 80.146 us; speedup vs baseline: 4.0688x; 1.1366x over previous
//
#include <hip/hip_runtime.h>
#include <hip/hip_bf16.h>
#include <type_traits>

#define DI __device__ __forceinline__

typedef unsigned short u16;
typedef unsigned int u32;
typedef __bf16 bf16x8 __attribute__((ext_vector_type(8)));
typedef u16 u16x8 __attribute__((ext_vector_type(8)));
typedef float f32x4 __attribute__((ext_vector_type(4)));
typedef float f32x16 __attribute__((ext_vector_type(16)));
typedef u32 u32x2 __attribute__((ext_vector_type(2)));
typedef u32 u32x4 __attribute__((ext_vector_type(4)));

constexpr int Bb = 2, Ls = 2048, Hh = 16, KVh = 4, HD = 64;
constexpr float LOG2E = 1.44269504088896f;
constexpr float RSQ2 = 0.70710678118654752f;   // slope ratio between heads

DI u16 f2bf(float f) {
  __hip_bfloat16 h = __float2bfloat16(f);
  return __builtin_bit_cast(u16, h);
}

// packed f32x2 -> bf16x2 (RNE), single VOP3 op
DI u32 cvtpk(float lo, float hi) {
  u32 r;
  asm("v_cvt_pk_bf16_f32 %0, %1, %2" : "=v"(r) : "v"(lo), "v"(hi));
  return r;
}

// a' = [a.lo | b.lo], b' = [a.hi | b.hi]  (swap a's hi 32 lanes with b's lo)
DI void pls(u32& a, u32& b) {
  asm("v_permlane32_swap_b32 %0, %1" : "+v"(a), "+v"(b));
}
DI float sum_halves(float v) {        // v[l] + v[l^32], valid in all lanes
  u32 a = __builtin_bit_cast(u32, v), b = a;
  pls(a, b);
  return __builtin_bit_cast(float, a) + __builtin_bit_cast(float, b);
}
DI float max_halves(float v) {
  u32 a = __builtin_bit_cast(u32, v), b = a;
  pls(a, b);
  return fmaxf(__builtin_bit_cast(float, a), __builtin_bit_cast(float, b));
}

DI f32x4 mfma16(bf16x8 a, bf16x8 b, f32x4 c) {
  return __builtin_amdgcn_mfma_f32_16x16x32_bf16(a, b, c, 0, 0, 0);
}
DI f32x16 mfma32(bf16x8 a, bf16x8 b, f32x16 c) {
  return __builtin_amdgcn_mfma_f32_32x32x16_bf16(a, b, c, 0, 0, 0);
}
DI bf16x8 bc(u32x4 v) { return __builtin_bit_cast(bf16x8, v); }

// async global->LDS, 16B per lane; LDS dest = wave-uniform base + lane*16
DI void gld16(const u16* g, u16* l) {
  __builtin_amdgcn_global_load_lds(
      (const __attribute__((address_space(1))) u32*)g,
      (__attribute__((address_space(3))) u32*)l, 16, 0, 0);
}

// ---- fused prep: hs cvt + seg starts + all 4 weight transposes -----------
__global__ void prep(const float* __restrict__ hs, u16* __restrict__ hsb,
                     const int* __restrict__ seg, int* __restrict__ sst,
                     const float* __restrict__ Wq, const float* __restrict__ Wk,
                     const float* __restrict__ Wv, const float* __restrict__ Wo,
                     u16* __restrict__ wqkvT, u16* __restrict__ woT) {
  int bid = blockIdx.x;
  if (bid < 4096) {
    int i = bid * 256 + threadIdx.x;
    float4 v = reinterpret_cast<const float4*>(hs)[i];
    ushort4 o;
    o.x = f2bf(v.x); o.y = f2bf(v.y); o.z = f2bf(v.z); o.w = f2bf(v.w);
    reinterpret_cast<ushort4*>(hsb)[i] = o;
    return;
  }
  if (bid < 4112) {
    int idx = bid - 4096;
    int b = idx >> 3;
    int l = (idx & 7) * 256 + threadIdx.x;
    const int* s = seg + b * Ls;
    int v = s[l];
    int lo = 0, hi = l;
    while (lo < hi) {
      int mid = (lo + hi) >> 1;
      if (s[mid] < v) lo = mid + 1; else hi = mid;
    }
    sst[b * Ls + l] = lo;
    return;
  }
  int t = bid - 4112;
  const float* in; u16* out; int N, rowoff, x, y;
  if (t < 1024)      { in = Wq; out = wqkvT; N = 1024; rowoff = 0;
                       x = t & 31; y = t >> 5; }
  else if (t < 1280) { in = Wk; out = wqkvT; N = 256; rowoff = 1024;
                       int u = t - 1024; x = u & 7; y = u >> 3; }
  else if (t < 1536) { in = Wv; out = wqkvT; N = 256; rowoff = 1280;
                       int u = t - 1280; x = u & 7; y = u >> 3; }
  else               { in = Wo; out = woT; N = 1024; rowoff = 0;
                       int u = t - 1536; x = u & 31; y = u >> 5; }
  __shared__ u16 tl[32][33];
  int k0 = y * 32, n0 = x * 32;
  int tx = threadIdx.x & 31, ty = threadIdx.x >> 5;
#pragma unroll
  for (int i = ty; i < 32; i += 8)
    tl[i][tx] = f2bf(in[(size_t)(k0 + i) * N + n0 + tx]);
  __syncthreads();
#pragma unroll
  for (int i = ty; i < 32; i += 8)
    out[(size_t)(rowoff + n0 + i) * 1024 + k0 + tx] = tl[tx][i];
}

// ---- GEMM: 8-wave 128x128, 4-buffer rotation, 1 barrier/K-step -----------
// Pipeline: stage buf (b+3)&3 right after barrier (3 tiles / 6 loads in
// flight, vmcnt(4) steady, 4/2/0 drain). Requires K % 128 == 0.
// MODE 0: C[M][N] float.  MODE 1 (qkv): scatter into fragment-linear Qf/Kf/Vf.
template <int MODE>
__global__ __launch_bounds__(512) void gemm_bt(
    const u16* __restrict__ A, const u16* __restrict__ Bt,
    float* __restrict__ C, u16* __restrict__ Qf, u16* __restrict__ Kf,
    u16* __restrict__ Vf, int M, int N, int K) {
  __shared__ u16 lA[4][128 * 32];
  __shared__ u16 lB[4][128 * 32];
  const int m0 = blockIdx.y * 128, n0 = blockIdx.x * 128;
  const int tid = threadIdx.x;
  const int lane = tid & 63;
  const int wr = ((tid >> 8) & 1) * 64;         // wm = w>>2
  const int wc = ((tid >> 6) & 3) * 32;         // wn = w&3
  const int lr = lane & 15, lk = (lane >> 4) * 8;
  const int r0 = tid >> 2, c0 = (tid & 3) * 8;  // staging: full 128x32 tile
  const int woff = (tid & 0x1C0) << 4;          // wave-uniform LDS byte base
  const u16* pA0 = &A[(size_t)(m0 + r0) * K + c0];
  const u16* pB0 = &Bt[(size_t)(n0 + r0) * K + c0];

  auto stage = [&](u16* sA, u16* sB, int k0) {
    gld16(pA0 + k0, (u16*)((char*)sA + woff));
    gld16(pB0 + k0, (u16*)((char*)sB + woff));
  };

  f32x4 acc[4][2] = {};
  auto compute = [&](const u16* sA, const u16* sB) {
    bf16x8 af[4], bfv[2];
#pragma unroll
    for (int m = 0; m < 4; m++)
      af[m] = *reinterpret_cast<const bf16x8*>(&sA[(wr + m * 16 + lr) * 32 + lk]);
#pragma unroll
    for (int n = 0; n < 2; n++)
      bfv[n] = *reinterpret_cast<const bf16x8*>(&sB[(wc + n * 16 + lr) * 32 + lk]);
#pragma unroll
    for (int m = 0; m < 4; m++)
#pragma unroll
      for (int n = 0; n < 2; n++)
        acc[m][n] = mfma16(af[m], bfv[n], acc[m][n]);
  };

#define BODY(B, VM, KC, DOST)                                        \
  do {                                                               \
    asm volatile("s_waitcnt vmcnt(" VM ")" ::: "memory");            \
    __builtin_amdgcn_s_barrier();                                    \
    asm volatile("" ::: "memory");                                   \
    if (DOST) stage(lA[(B + 3) & 3], lB[(B + 3) & 3], (KC) + 96);    \
    compute(lA[B], lB[B]);                                           \
  } while (0)

  stage(lA[0], lB[0], 0);
  stage(lA[1], lB[1], 32);
  stage(lA[2], lB[2], 64);
  int k0 = 0;
  for (; k0 + 224 <= K; k0 += 128) {            // full groups, all stage
    BODY(0, "4", k0, 1);
    BODY(1, "4", k0 + 32, 1);
    BODY(2, "4", k0 + 64, 1);
    BODY(3, "4", k0 + 96, 1);
  }
  BODY(0, "4", k0, 1);                          // stages K-32
  BODY(1, "4", k0 + 32, 0);
  BODY(2, "2", k0 + 64, 0);
  BODY(3, "0", k0 + 96, 0);
#undef BODY

  const int rr = (lane >> 4) * 4, cc = lane & 15;
#pragma unroll
  for (int m = 0; m < 4; m++) {
    int row0 = m0 + wr + m * 16 + rr;
#pragma unroll
    for (int n = 0; n < 2; n++) {
      int col = n0 + wc + n * 16 + cc;
      if constexpr (MODE == 0) {
#pragma unroll
        for (int r = 0; r < 4; r++)
          C[(size_t)(row0 + r) * N + col] = acc[m][n][r];
      } else {
        int bb = row0 >> 11, l = row0 & 2047;
        int d = col & 63, c8 = d >> 3, d7 = d & 7;
        int kt = l >> 5, r32 = l & 31;
        if (col < 1024) {
          int hd = col >> 6;
          u16* base = &Qf[((((size_t)(bb * 16 + hd) * 64 + kt) << 11)) +
                          ((c8 * 32 + r32) << 3) + d7];
#pragma unroll
          for (int r = 0; r < 4; r++) base[r * 8] = f2bf(acc[m][n][r]);
        } else if (col < 1280) {
          int kv = (col - 1024) >> 6;
          u16* base = &Kf[((((size_t)(bb * 4 + kv) * 64 + kt) << 11)) +
                          ((c8 * 32 + r32) << 3) + d7];
#pragma unroll
          for (int r = 0; r < 4; r++) base[r * 8] = f2bf(acc[m][n][r]);
        } else {
          int kv = (col - 1280) >> 6;
          ushort4 pv;
          pv.x = f2bf(acc[m][n][0]); pv.y = f2bf(acc[m][n][1]);
          pv.z = f2bf(acc[m][n][2]); pv.w = f2bf(acc[m][n][3]);
          *reinterpret_cast<ushort4*>(
              &Vf[((((size_t)(bb * 4 + kv) * 64 + kt) << 11)) +
                  ((((l >> 3) & 3) * 64 + d) << 3) + (l & 7)]) = pv;
        }
      }
    }
  }
}

// ---- flash attention: swapped 32x32, HEAD-PAIR per wave, shared K/V ------
// P redistribution via v_permlane32_swap (T12): swap(pk0,pk2) yields B-frag
// words 0/2 directly; 8 swaps replace 16 ds_bpermute + 16 selects.
__global__ __launch_bounds__(64, 1) void attn(
    const u16* __restrict__ Qf, const u16* __restrict__ Kf,
    const u16* __restrict__ Vf, const int* __restrict__ sst,
    u16* __restrict__ Obuf) {
  const int qt = 63 - blockIdx.x;               // big blocks dispatch first
  const int hp = blockIdx.y, b = blockIdx.z;
  const int h0 = hp << 1;
  const int kvh = h0 >> 2;
  const int lane = threadIdx.x;
  const int qi = lane & 31, hi = lane >> 5;
  const int qw = qt * 32;
  const int q = qw + qi;
  const float slope0 = __builtin_amdgcn_exp2f(-0.5f * (float)(h0 + 1));
  const float SL0 = slope0 * LOG2E;
  const float SL1 = SL0 * RSQ2;
  const float SL0x32 = 32.f * SL0, SL1x32 = 32.f * SL1;
  const float Cs = 0.125f * LOG2E;
  const u16* Qt0 = Qf + (((size_t)(b * Hh + h0) * 64 + qt) << 11);
  const u16* Qt1 = Qt0 + ((size_t)64 << 11);    // head h0+1
  const u16* Kbase = Kf + (((size_t)(b * KVh + kvh) * 64) << 11);
  const u16* Vbase = Vf + (((size_t)(b * KVh + kvh) * 64) << 11);

  bf16x8 qfA[4], qfB[4];
#pragma unroll
  for (int c = 0; c < 4; c++) {
    qfA[c] = *reinterpret_cast<const bf16x8*>(&Qt0[((2 * c + hi) * 32 + qi) * 8]);
    qfB[c] = *reinterpret_cast<const bf16x8*>(&Qt1[((2 * c + hi) * 32 + qi) * 8]);
  }

  const int start = sst[b * Ls + q];
  const int smax = __shfl(start, 31);
  const int k_begin = __shfl(start, 0) & ~31;

  float krsl[16];                               // krow * SL0 (chain A)
#pragma unroll
  for (int r = 0; r < 16; r++)
    krsl[r] = (float)((r & 3) + 8 * (r >> 2) + 4 * hi) * SL0;
  float biasA = (float)(k_begin - q) * SL0;     // (kk - q)*SL - m_run (folded)
  float biasB = (float)(k_begin - q) * SL1;
  float lA = 0.f, lB = 0.f;
  f32x16 oAlo = {}, oAhi = {}, oBlo = {}, oBhi = {};

  auto KLD = [&](int kt, u32x4* dst) {
    const u16* p = Kbase + ((size_t)kt << 11);
#pragma unroll
    for (int c = 0; c < 4; c++)
      dst[c] = *reinterpret_cast<const u32x4*>(&p[((2 * c + hi) * 32 + qi) * 8]);
  };
  auto VLD = [&](int kt, u32x4* dst) {
    const u16* p = Vbase + ((size_t)kt << 11);
#pragma unroll
    for (int j = 0; j < 4; j++) {
      int off = ((((j & 1) * 2 + hi) * 64) + (j >> 1) * 32 + qi) * 8;
      dst[j] = *reinterpret_cast<const u32x4*>(&p[off]);
    }
  };

  auto rowmax = [&](const float* t) {           // balanced tree, depth 4
    float u0 = fmaxf(t[0], t[1]), u1 = fmaxf(t[2], t[3]);
    float u2 = fmaxf(t[4], t[5]), u3 = fmaxf(t[6], t[7]);
    float u4 = fmaxf(t[8], t[9]), u5 = fmaxf(t[10], t[11]);
    float u6 = fmaxf(t[12], t[13]), u7 = fmaxf(t[14], t[15]);
    u0 = fmaxf(u0, u1); u2 = fmaxf(u2, u3);
    u4 = fmaxf(u4, u5); u6 = fmaxf(u6, u7);
    return fmaxf(fmaxf(u0, u2), fmaxf(u4, u6));
  };

  auto body = [&](int kk, u32x4* KR, u32x4* VR) {
    f32x16 aA = {}, aB = {};
    __builtin_amdgcn_s_setprio(1);
#pragma unroll
    for (int c = 0; c < 4; c++) aA = mfma32(bc(KR[c]), qfA[c], aA);
#pragma unroll
    for (int c = 0; c < 4; c++) aB = mfma32(bc(KR[c]), qfB[c], aB);
    __builtin_amdgcn_s_setprio(0);
    const int kt2 = min(kk + 64, qw) >> 5;
    KLD(kt2, KR);                               // hidden under softmax+PV

    float tA[16], tB[16];
#pragma unroll
    for (int r = 0; r < 16; r++) {
      tA[r] = fmaf(aA[r], Cs, biasA) + krsl[r];
      tB[r] = fmaf(aB[r], Cs, biasB) + krsl[r] * RSQ2;
    }
    if (!(kk >= smax && kk < qw)) {             // mask once for both heads
#pragma unroll
      for (int r = 0; r < 16; r++) {
        int j = kk + (r & 3) + 8 * (r >> 2) + 4 * hi;
        bool v = (j >= start) && (j <= q);
        tA[r] = v ? tA[r] : -3.0e38f;
        tB[r] = v ? tB[r] : -3.0e38f;
      }
    }
    {
      float mt = max_halves(rowmax(tA));
      if (!__all(mt <= 8.f)) {                  // rare defer-max rescale
        float dm = fmaxf(mt, 0.f);
        float fac = __builtin_amdgcn_exp2f(-dm);
        biasA -= dm; lA *= fac;
#pragma unroll
        for (int r = 0; r < 16; r++) { oAlo[r] *= fac; oAhi[r] *= fac; tA[r] -= dm; }
      }
    }
    {
      float mt = max_halves(rowmax(tB));
      if (!__all(mt <= 8.f)) {
        float dm = fmaxf(mt, 0.f);
        float fac = __builtin_amdgcn_exp2f(-dm);
        biasB -= dm; lB *= fac;
#pragma unroll
        for (int r = 0; r < 16; r++) { oBlo[r] *= fac; oBhi[r] *= fac; tB[r] -= dm; }
      }
    }
    float pA[16], pB[16];
#pragma unroll
    for (int r = 0; r < 16; r++) {
      pA[r] = __builtin_amdgcn_exp2f(tA[r]);
      pB[r] = __builtin_amdgcn_exp2f(tB[r]);
    }
    float tsA = 0.f, tsB = 0.f;
#pragma unroll
    for (int r = 0; r < 16; r++) { tsA += pA[r]; tsB += pB[r]; }
    lA += sum_halves(tsA);
    lB += sum_halves(tsB);

    u32 pkA[8], pkB[8];
#pragma unroll
    for (int i = 0; i < 8; i++) {
      pkA[i] = cvtpk(pA[2 * i], pA[2 * i + 1]);
      pkB[i] = cvtpk(pB[2 * i], pB[2 * i + 1]);
    }
    pls(pkA[0], pkA[2]); pls(pkA[1], pkA[3]);
    pls(pkA[4], pkA[6]); pls(pkA[5], pkA[7]);
    pls(pkB[0], pkB[2]); pls(pkB[1], pkB[3]);
    pls(pkB[4], pkB[6]); pls(pkB[5], pkB[7]);
    u32x4 fA0 = { pkA[0], pkA[1], pkA[2], pkA[3] };
    u32x4 fA1 = { pkA[4], pkA[5], pkA[6], pkA[7] };
    u32x4 fB0 = { pkB[0], pkB[1], pkB[2], pkB[3] };
    u32x4 fB1 = { pkB[4], pkB[5], pkB[6], pkB[7] };

    __builtin_amdgcn_s_setprio(1);
    oAlo = mfma32(bc(VR[0]), bc(fA0), oAlo);
    oAlo = mfma32(bc(VR[1]), bc(fA1), oAlo);
    oAhi = mfma32(bc(VR[2]), bc(fA0), oAhi);
    oAhi = mfma32(bc(VR[3]), bc(fA1), oAhi);
    oBlo = mfma32(bc(VR[0]), bc(fB0), oBlo);
    oBlo = mfma32(bc(VR[1]), bc(fB1), oBlo);
    oBhi = mfma32(bc(VR[2]), bc(fB0), oBhi);
    oBhi = mfma32(bc(VR[3]), bc(fB1), oBhi);
    __builtin_amdgcn_s_setprio(0);
    VLD(kt2, VR);                               // prefetch next V
    biasA += SL0x32; biasB += SL1x32;
  };

  u32x4 KR0[4], VR0[4], KR1[4], VR1[4];
  {
    const int kt0 = k_begin >> 5;
    const int kt1 = min(k_begin + 32, qw) >> 5;
    KLD(kt0, KR0); VLD(kt0, VR0);
    KLD(kt1, KR1); VLD(kt1, VR1);
  }
  int kk = k_begin;
  while (true) {
    body(kk, KR0, VR0);
    if (kk + 32 > qw) break;
    body(kk + 32, KR1, VR1);
    if (kk + 64 > qw) break;
    kk += 64;
  }

  const float invA = __builtin_amdgcn_rcpf(lA);
  const float invB = __builtin_amdgcn_rcpf(lB);
  const size_t orow = (size_t)(b * Ls + q) * 1024 + h0 * 64;
#pragma unroll
  for (int g = 0; g < 4; g++) {
    int d0 = g * 8 + hi * 4;
    u32x2 pa = { cvtpk(oAlo[4 * g + 0] * invA, oAlo[4 * g + 1] * invA),
                 cvtpk(oAlo[4 * g + 2] * invA, oAlo[4 * g + 3] * invA) };
    u32x2 pb = { cvtpk(oAhi[4 * g + 0] * invA, oAhi[4 * g + 1] * invA),
                 cvtpk(oAhi[4 * g + 2] * invA, oAhi[4 * g + 3] * invA) };
    *reinterpret_cast<u32x2*>(&Obuf[orow + d0]) = pa;
    *reinterpret_cast<u32x2*>(&Obuf[orow + 32 + d0]) = pb;
    u32x2 qa = { cvtpk(oBlo[4 * g + 0] * invB, oBlo[4 * g + 1] * invB),
                 cvtpk(oBlo[4 * g + 2] * invB, oBlo[4 * g + 3] * invB) };
    u32x2 qb = { cvtpk(oBhi[4 * g + 0] * invB, oBhi[4 * g + 1] * invB),
                 cvtpk(oBhi[4 * g + 2] * invB, oBhi[4 * g + 3] * invB) };
    *reinterpret_cast<u32x2*>(&Obuf[orow + 64 + d0]) = qa;
    *reinterpret_cast<u32x2*>(&Obuf[orow + 96 + d0]) = qb;
  }
}

// ---- launch ---------------------------------------------------------------
extern "C" void kernel_launch(void* const* d_in, const int* in_sizes, int n_in,
                              void* d_out, int out_size, void* d_ws, size_t ws_size,
                              hipStream_t stream) {
  const float* hs = (const float*)d_in[0];
  const int* seg = (const int*)d_in[1];
  const float* Wq = (const float*)d_in[2];
  const float* Wk = (const float*)d_in[3];
  const float* Wv = (const float*)d_in[4];
  const float* Wo = (const float*)d_in[5];
  float* out = (float*)d_out;
  char* ws = (char*)d_ws;
  // hsb 8.4M | wqkvT 3.1M | woT 2.1M | Qf 8.4M | Kf 2.1M | Vf 2.1M | sst 16K
  u16* hsb   = (u16*)(ws);
  u16* wqkvT = (u16*)(ws + 8388608);
  u16* woT   = (u16*)(ws + 11534336);
  u16* qf    = (u16*)(ws + 13631488);
  u16* kf    = (u16*)(ws + 22020096);
  u16* vf    = (u16*)(ws + 24117248);
  int* sst   = (int*)(ws + 26214400);
  u16* obuf  = hsb;   // hsb dead after GEMM1

  prep<<<dim3(6672), dim3(256), 0, stream>>>(hs, hsb, seg, sst,
                                             Wq, Wk, Wv, Wo, wqkvT, woT);
  gemm_bt<1><<<dim3(12, 32), dim3(512), 0, stream>>>(
      hsb, wqkvT, nullptr, qf, kf, vf, 4096, 1536, 1024);
  attn<<<dim3(64, 8, 2), dim3(64), 0, stream>>>(qf, kf, vf, sst, obuf);
  gemm_bt<0><<<dim3(8, 32), dim3(512), 0, stream>>>(
      obuf, woT, out, nullptr, nullptr, nullptr, 4096, 1024, 1024);
}

// Round 11
// 78.915 us; speedup vs baseline: 4.1323x; 1.0156x over previous
//
#include <hip/hip_runtime.h>
#include <hip/hip_bf16.h>
#include <type_traits>

#define DI __device__ __forceinline__

typedef unsigned short u16;
typedef unsigned int u32;
typedef __bf16 bf16x8 __attribute__((ext_vector_type(8)));
typedef u16 u16x8 __attribute__((ext_vector_type(8)));
typedef float f32x4 __attribute__((ext_vector_type(4)));
typedef float f32x16 __attribute__((ext_vector_type(16)));
typedef u32 u32x2 __attribute__((ext_vector_type(2)));
typedef u32 u32x4 __attribute__((ext_vector_type(4)));

constexpr int Bb = 2, Ls = 2048, Hh = 16, KVh = 4, HD = 64;
constexpr float LOG2E = 1.44269504088896f;
constexpr float RSQ2 = 0.70710678118654752f;   // slope ratio between heads

DI u16 f2bf(float f) {
  __hip_bfloat16 h = __float2bfloat16(f);
  return __builtin_bit_cast(u16, h);
}

// packed f32x2 -> bf16x2 (RNE), single VOP3 op
DI u32 cvtpk(float lo, float hi) {
  u32 r;
  asm("v_cvt_pk_bf16_f32 %0, %1, %2" : "=v"(r) : "v"(lo), "v"(hi));
  return r;
}

// a' = [a.lo | b.lo], b' = [a.hi | b.hi]  (swap a's hi 32 lanes with b's lo)
DI void pls(u32& a, u32& b) {
  asm("v_permlane32_swap_b32 %0, %1" : "+v"(a), "+v"(b));
}
DI float sum_halves(float v) {        // v[l] + v[l^32], valid in all lanes
  u32 a = __builtin_bit_cast(u32, v), b = a;
  pls(a, b);
  return __builtin_bit_cast(float, a) + __builtin_bit_cast(float, b);
}
DI float max_halves(float v) {
  u32 a = __builtin_bit_cast(u32, v), b = a;
  pls(a, b);
  return fmaxf(__builtin_bit_cast(float, a), __builtin_bit_cast(float, b));
}

DI f32x4 mfma16(bf16x8 a, bf16x8 b, f32x4 c) {
  return __builtin_amdgcn_mfma_f32_16x16x32_bf16(a, b, c, 0, 0, 0);
}
DI f32x16 mfma32(bf16x8 a, bf16x8 b, f32x16 c) {
  return __builtin_amdgcn_mfma_f32_32x32x16_bf16(a, b, c, 0, 0, 0);
}
DI bf16x8 bc(u32x4 v) { return __builtin_bit_cast(bf16x8, v); }

// async global->LDS, 16B per lane; LDS dest = wave-uniform base + lane*16
DI void gld16(const u16* g, u16* l) {
  __builtin_amdgcn_global_load_lds(
      (const __attribute__((address_space(1))) u32*)g,
      (__attribute__((address_space(3))) u32*)l, 16, 0, 0);
}

// ---- fused prep: hs cvt + seg starts + all 4 weight transposes -----------
__global__ void prep(const float* __restrict__ hs, u16* __restrict__ hsb,
                     const int* __restrict__ seg, int* __restrict__ sst,
                     const float* __restrict__ Wq, const float* __restrict__ Wk,
                     const float* __restrict__ Wv, const float* __restrict__ Wo,
                     u16* __restrict__ wqkvT, u16* __restrict__ woT) {
  int bid = blockIdx.x;
  if (bid < 4096) {
    int i = bid * 256 + threadIdx.x;
    float4 v = reinterpret_cast<const float4*>(hs)[i];
    ushort4 o;
    o.x = f2bf(v.x); o.y = f2bf(v.y); o.z = f2bf(v.z); o.w = f2bf(v.w);
    reinterpret_cast<ushort4*>(hsb)[i] = o;
    return;
  }
  if (bid < 4112) {
    int idx = bid - 4096;
    int b = idx >> 3;
    int l = (idx & 7) * 256 + threadIdx.x;
    const int* s = seg + b * Ls;
    int v = s[l];
    int lo = 0, hi = l;
    while (lo < hi) {
      int mid = (lo + hi) >> 1;
      if (s[mid] < v) lo = mid + 1; else hi = mid;
    }
    sst[b * Ls + l] = lo;
    return;
  }
  int t = bid - 4112;
  const float* in; u16* out; int N, rowoff, x, y;
  if (t < 1024)      { in = Wq; out = wqkvT; N = 1024; rowoff = 0;
                       x = t & 31; y = t >> 5; }
  else if (t < 1280) { in = Wk; out = wqkvT; N = 256; rowoff = 1024;
                       int u = t - 1024; x = u & 7; y = u >> 3; }
  else if (t < 1536) { in = Wv; out = wqkvT; N = 256; rowoff = 1280;
                       int u = t - 1280; x = u & 7; y = u >> 3; }
  else               { in = Wo; out = woT; N = 1024; rowoff = 0;
                       int u = t - 1536; x = u & 31; y = u >> 5; }
  __shared__ u16 tl[32][33];
  int k0 = y * 32, n0 = x * 32;
  int tx = threadIdx.x & 31, ty = threadIdx.x >> 5;
#pragma unroll
  for (int i = ty; i < 32; i += 8)
    tl[i][tx] = f2bf(in[(size_t)(k0 + i) * N + n0 + tx]);
  __syncthreads();
#pragma unroll
  for (int i = ty; i < 32; i += 8)
    out[(size_t)(rowoff + n0 + i) * 1024 + k0 + tx] = tl[tx][i];
}

// ---- GEMM: 8-wave 128x128, 4-buffer rotation, 1 barrier/K-step -----------
// LDS XOR swizzle (both-sides): staged colgroup g at (row,slot s) holds
// global group s^(row&3); frag read uses slot (lane>>4)^(lane&3).
// Cuts the 64B-row ds_read_b128 8-way bank conflict to 4-way.
// MODE 0: C[M][N] float.  MODE 1 (qkv): scatter into fragment-linear Qf/Kf/Vf.
template <int MODE>
__global__ __launch_bounds__(512) void gemm_bt(
    const u16* __restrict__ A, const u16* __restrict__ Bt,
    float* __restrict__ C, u16* __restrict__ Qf, u16* __restrict__ Kf,
    u16* __restrict__ Vf, int M, int N, int K) {
  __shared__ u16 lA[4][128 * 32];
  __shared__ u16 lB[4][128 * 32];
  const int m0 = blockIdx.y * 128, n0 = blockIdx.x * 128;
  const int tid = threadIdx.x;
  const int lane = tid & 63;
  const int wr = ((tid >> 8) & 1) * 64;         // wm = w>>2
  const int wc = ((tid >> 6) & 3) * 32;         // wn = w&3
  const int lr = lane & 15;
  const int lk = (((lane >> 4) ^ (lane & 3)) * 8);   // swizzled read slot
  const int r0 = tid >> 2;
  const int c0 = (((tid & 3) ^ ((tid >> 2) & 3)) * 8); // swizzled src group
  const int woff = (tid & 0x1C0) << 4;          // wave-uniform LDS byte base
  const u16* pA0 = &A[(size_t)(m0 + r0) * K + c0];
  const u16* pB0 = &Bt[(size_t)(n0 + r0) * K + c0];

  auto stage = [&](u16* sA, u16* sB, int k0) {
    gld16(pA0 + k0, (u16*)((char*)sA + woff));
    gld16(pB0 + k0, (u16*)((char*)sB + woff));
  };

  f32x4 acc[4][2] = {};
  auto compute = [&](const u16* sA, const u16* sB) {
    bf16x8 af[4], bfv[2];
#pragma unroll
    for (int m = 0; m < 4; m++)
      af[m] = *reinterpret_cast<const bf16x8*>(&sA[(wr + m * 16 + lr) * 32 + lk]);
#pragma unroll
    for (int n = 0; n < 2; n++)
      bfv[n] = *reinterpret_cast<const bf16x8*>(&sB[(wc + n * 16 + lr) * 32 + lk]);
#pragma unroll
    for (int m = 0; m < 4; m++)
#pragma unroll
      for (int n = 0; n < 2; n++)
        acc[m][n] = mfma16(af[m], bfv[n], acc[m][n]);
  };

#define BODY(B, VM, KC, DOST)                                        \
  do {                                                               \
    asm volatile("s_waitcnt vmcnt(" VM ")" ::: "memory");            \
    __builtin_amdgcn_s_barrier();                                    \
    asm volatile("" ::: "memory");                                   \
    if (DOST) stage(lA[(B + 3) & 3], lB[(B + 3) & 3], (KC) + 96);    \
    compute(lA[B], lB[B]);                                           \
  } while (0)

  stage(lA[0], lB[0], 0);
  stage(lA[1], lB[1], 32);
  stage(lA[2], lB[2], 64);
  int k0 = 0;
  for (; k0 + 224 <= K; k0 += 128) {            // full groups, all stage
    BODY(0, "4", k0, 1);
    BODY(1, "4", k0 + 32, 1);
    BODY(2, "4", k0 + 64, 1);
    BODY(3, "4", k0 + 96, 1);
  }
  BODY(0, "4", k0, 1);                          // stages K-32
  BODY(1, "4", k0 + 32, 0);
  BODY(2, "2", k0 + 64, 0);
  BODY(3, "0", k0 + 96, 0);
#undef BODY

  const int rr = (lane >> 4) * 4, cc = lane & 15;
#pragma unroll
  for (int m = 0; m < 4; m++) {
    int row0 = m0 + wr + m * 16 + rr;
#pragma unroll
    for (int n = 0; n < 2; n++) {
      int col = n0 + wc + n * 16 + cc;
      if constexpr (MODE == 0) {
#pragma unroll
        for (int r = 0; r < 4; r++)
          C[(size_t)(row0 + r) * N + col] = acc[m][n][r];
      } else {
        int bb = row0 >> 11, l = row0 & 2047;
        int d = col & 63, c8 = d >> 3, d7 = d & 7;
        int kt = l >> 5, r32 = l & 31;
        if (col < 1024) {
          int hd = col >> 6;
          u16* base = &Qf[((((size_t)(bb * 16 + hd) * 64 + kt) << 11)) +
                          ((c8 * 32 + r32) << 3) + d7];
#pragma unroll
          for (int r = 0; r < 4; r++) base[r * 8] = f2bf(acc[m][n][r]);
        } else if (col < 1280) {
          int kv = (col - 1024) >> 6;
          u16* base = &Kf[((((size_t)(bb * 4 + kv) * 64 + kt) << 11)) +
                          ((c8 * 32 + r32) << 3) + d7];
#pragma unroll
          for (int r = 0; r < 4; r++) base[r * 8] = f2bf(acc[m][n][r]);
        } else {
          int kv = (col - 1280) >> 6;
          ushort4 pv;
          pv.x = f2bf(acc[m][n][0]); pv.y = f2bf(acc[m][n][1]);
          pv.z = f2bf(acc[m][n][2]); pv.w = f2bf(acc[m][n][3]);
          *reinterpret_cast<ushort4*>(
              &Vf[((((size_t)(bb * 4 + kv) * 64 + kt) << 11)) +
                  ((((l >> 3) & 3) * 64 + d) << 3) + (l & 7)]) = pv;
        }
      }
    }
  }
}

// ---- flash attention: swapped 32x32, HEAD-PAIR wave, 2-wave split-KV -----
// Block = 2 waves; wave w takes key tiles k_begin+32w stride 64. Each wave
// runs the dual-head online softmax with per-lane m_acc; LDS merge at end
// (factors == 1 unless a defer-max rescale fired).
__global__ __launch_bounds__(128, 1) void attn(
    const u16* __restrict__ Qf, const u16* __restrict__ Kf,
    const u16* __restrict__ Vf, const int* __restrict__ sst,
    u16* __restrict__ Obuf) {
  const int qt = 63 - blockIdx.x;               // big blocks dispatch first
  const int hp = blockIdx.y, b = blockIdx.z;
  const int h0 = hp << 1;
  const int kvh = h0 >> 2;
  const int tid = threadIdx.x;
  const int w = tid >> 6, lane = tid & 63;
  const int qi = lane & 31, hi = lane >> 5;
  const int qw = qt * 32;
  const int q = qw + qi;
  const float slope0 = __builtin_amdgcn_exp2f(-0.5f * (float)(h0 + 1));
  const float SL0 = slope0 * LOG2E;
  const float SL1 = SL0 * RSQ2;
  const float SL0x64 = 64.f * SL0, SL1x64 = 64.f * SL1;
  const float Cs = 0.125f * LOG2E;
  const u16* Qt0 = Qf + (((size_t)(b * Hh + h0) * 64 + qt) << 11);
  const u16* Qt1 = Qt0 + ((size_t)64 << 11);    // head h0+1
  const u16* Kbase = Kf + (((size_t)(b * KVh + kvh) * 64) << 11);
  const u16* Vbase = Vf + (((size_t)(b * KVh + kvh) * 64) << 11);

  bf16x8 qfA[4], qfB[4];
#pragma unroll
  for (int c = 0; c < 4; c++) {
    qfA[c] = *reinterpret_cast<const bf16x8*>(&Qt0[((2 * c + hi) * 32 + qi) * 8]);
    qfB[c] = *reinterpret_cast<const bf16x8*>(&Qt1[((2 * c + hi) * 32 + qi) * 8]);
  }

  const int start = sst[b * Ls + q];
  const int smax = __shfl(start, 31);
  const int k_begin = __shfl(start, 0) & ~31;

  float krsl[16];                               // krow * SL0 (chain A)
#pragma unroll
  for (int r = 0; r < 16; r++)
    krsl[r] = (float)((r & 3) + 8 * (r >> 2) + 4 * hi) * SL0;
  float biasA = (float)(k_begin + 32 * w - q) * SL0;  // (kk-q)*SL - m_acc
  float biasB = (float)(k_begin + 32 * w - q) * SL1;
  float mAacc = 0.f, mBacc = 0.f;
  float lA = 0.f, lB = 0.f;
  f32x16 oAlo = {}, oAhi = {}, oBlo = {}, oBhi = {};

  auto KLD = [&](int kt, u32x4* dst) {
    const u16* p = Kbase + ((size_t)kt << 11);
#pragma unroll
    for (int c = 0; c < 4; c++)
      dst[c] = *reinterpret_cast<const u32x4*>(&p[((2 * c + hi) * 32 + qi) * 8]);
  };
  auto VLD = [&](int kt, u32x4* dst) {
    const u16* p = Vbase + ((size_t)kt << 11);
#pragma unroll
    for (int j = 0; j < 4; j++) {
      int off = ((((j & 1) * 2 + hi) * 64) + (j >> 1) * 32 + qi) * 8;
      dst[j] = *reinterpret_cast<const u32x4*>(&p[off]);
    }
  };

  auto rowmax = [&](const float* t) {           // balanced tree, depth 4
    float u0 = fmaxf(t[0], t[1]), u1 = fmaxf(t[2], t[3]);
    float u2 = fmaxf(t[4], t[5]), u3 = fmaxf(t[6], t[7]);
    float u4 = fmaxf(t[8], t[9]), u5 = fmaxf(t[10], t[11]);
    float u6 = fmaxf(t[12], t[13]), u7 = fmaxf(t[14], t[15]);
    u0 = fmaxf(u0, u1); u2 = fmaxf(u2, u3);
    u4 = fmaxf(u4, u5); u6 = fmaxf(u6, u7);
    return fmaxf(fmaxf(u0, u2), fmaxf(u4, u6));
  };

  auto body = [&](int kk, u32x4* KR, u32x4* VR) {
    f32x16 aA = {}, aB = {};
    __builtin_amdgcn_s_setprio(1);
#pragma unroll
    for (int c = 0; c < 4; c++) aA = mfma32(bc(KR[c]), qfA[c], aA);
#pragma unroll
    for (int c = 0; c < 4; c++) aB = mfma32(bc(KR[c]), qfB[c], aB);
    __builtin_amdgcn_s_setprio(0);
    const int kt2 = min(kk + 64, qw) >> 5;
    KLD(kt2, KR);                               // hidden under softmax+PV

    float tA[16], tB[16];
#pragma unroll
    for (int r = 0; r < 16; r++) {
      tA[r] = fmaf(aA[r], Cs, biasA) + krsl[r];
      tB[r] = fmaf(aB[r], Cs, biasB) + krsl[r] * RSQ2;
    }
    if (!(kk >= smax && kk < qw)) {             // mask once for both heads
#pragma unroll
      for (int r = 0; r < 16; r++) {
        int j = kk + (r & 3) + 8 * (r >> 2) + 4 * hi;
        bool v = (j >= start) && (j <= q);
        tA[r] = v ? tA[r] : -3.0e38f;
        tB[r] = v ? tB[r] : -3.0e38f;
      }
    }
    {
      float mt = max_halves(rowmax(tA));
      if (!__all(mt <= 8.f)) {                  // rare defer-max rescale
        float dm = fmaxf(mt, 0.f);
        float fac = __builtin_amdgcn_exp2f(-dm);
        biasA -= dm; lA *= fac; mAacc += dm;
#pragma unroll
        for (int r = 0; r < 16; r++) { oAlo[r] *= fac; oAhi[r] *= fac; tA[r] -= dm; }
      }
    }
    {
      float mt = max_halves(rowmax(tB));
      if (!__all(mt <= 8.f)) {
        float dm = fmaxf(mt, 0.f);
        float fac = __builtin_amdgcn_exp2f(-dm);
        biasB -= dm; lB *= fac; mBacc += dm;
#pragma unroll
        for (int r = 0; r < 16; r++) { oBlo[r] *= fac; oBhi[r] *= fac; tB[r] -= dm; }
      }
    }
    float pA[16], pB[16];
#pragma unroll
    for (int r = 0; r < 16; r++) {
      pA[r] = __builtin_amdgcn_exp2f(tA[r]);
      pB[r] = __builtin_amdgcn_exp2f(tB[r]);
    }
    float tsA = 0.f, tsB = 0.f;
#pragma unroll
    for (int r = 0; r < 16; r++) { tsA += pA[r]; tsB += pB[r]; }
    lA += sum_halves(tsA);
    lB += sum_halves(tsB);

    u32 pkA[8], pkB[8];
#pragma unroll
    for (int i = 0; i < 8; i++) {
      pkA[i] = cvtpk(pA[2 * i], pA[2 * i + 1]);
      pkB[i] = cvtpk(pB[2 * i], pB[2 * i + 1]);
    }
    pls(pkA[0], pkA[2]); pls(pkA[1], pkA[3]);
    pls(pkA[4], pkA[6]); pls(pkA[5], pkA[7]);
    pls(pkB[0], pkB[2]); pls(pkB[1], pkB[3]);
    pls(pkB[4], pkB[6]); pls(pkB[5], pkB[7]);
    u32x4 fA0 = { pkA[0], pkA[1], pkA[2], pkA[3] };
    u32x4 fA1 = { pkA[4], pkA[5], pkA[6], pkA[7] };
    u32x4 fB0 = { pkB[0], pkB[1], pkB[2], pkB[3] };
    u32x4 fB1 = { pkB[4], pkB[5], pkB[6], pkB[7] };

    __builtin_amdgcn_s_setprio(1);
    oAlo = mfma32(bc(VR[0]), bc(fA0), oAlo);
    oAlo = mfma32(bc(VR[1]), bc(fA1), oAlo);
    oAhi = mfma32(bc(VR[2]), bc(fA0), oAhi);
    oAhi = mfma32(bc(VR[3]), bc(fA1), oAhi);
    oBlo = mfma32(bc(VR[0]), bc(fB0), oBlo);
    oBlo = mfma32(bc(VR[1]), bc(fB1), oBlo);
    oBhi = mfma32(bc(VR[2]), bc(fB0), oBhi);
    oBhi = mfma32(bc(VR[3]), bc(fB1), oBhi);
    __builtin_amdgcn_s_setprio(0);
    VLD(kt2, VR);                               // prefetch next V
    biasA += SL0x64; biasB += SL1x64;
  };

  u32x4 KR[4], VR[4];
  int kk = k_begin + 32 * w;
  if (kk <= qw) { KLD(kk >> 5, KR); VLD(kk >> 5, VR); }
  for (; kk <= qw; kk += 64) body(kk, KR, VR);

  // ---- cross-wave merge (wave 1 publishes, wave 0 combines + stores) ----
  __shared__ float sm[64][69];                  // 69-stride: conflict-free
  if (w == 1) {
#pragma unroll
    for (int r = 0; r < 16; r++) {
      sm[lane][r] = oAlo[r];      sm[lane][16 + r] = oAhi[r];
      sm[lane][32 + r] = oBlo[r]; sm[lane][48 + r] = oBhi[r];
    }
    sm[lane][64] = lA; sm[lane][65] = lB;
    sm[lane][66] = mAacc; sm[lane][67] = mBacc;
  }
  __syncthreads();
  if (w == 1) return;
  {
    float mA1 = sm[lane][66], mB1 = sm[lane][67];
    float MA = fmaxf(mAacc, mA1), MB = fmaxf(mBacc, mB1);
    float fa0 = __builtin_amdgcn_exp2f(mAacc - MA);
    float fa1 = __builtin_amdgcn_exp2f(mA1 - MA);
    float fb0 = __builtin_amdgcn_exp2f(mBacc - MB);
    float fb1 = __builtin_amdgcn_exp2f(mB1 - MB);
    lA = lA * fa0 + sm[lane][64] * fa1;
    lB = lB * fb0 + sm[lane][65] * fb1;
#pragma unroll
    for (int r = 0; r < 16; r++) {
      oAlo[r] = oAlo[r] * fa0 + sm[lane][r] * fa1;
      oAhi[r] = oAhi[r] * fa0 + sm[lane][16 + r] * fa1;
      oBlo[r] = oBlo[r] * fb0 + sm[lane][32 + r] * fb1;
      oBhi[r] = oBhi[r] * fb0 + sm[lane][48 + r] * fb1;
    }
  }

  const float invA = __builtin_amdgcn_rcpf(lA);
  const float invB = __builtin_amdgcn_rcpf(lB);
  const size_t orow = (size_t)(b * Ls + q) * 1024 + h0 * 64;
#pragma unroll
  for (int g = 0; g < 4; g++) {
    int d0 = g * 8 + hi * 4;
    u32x2 pa = { cvtpk(oAlo[4 * g + 0] * invA, oAlo[4 * g + 1] * invA),
                 cvtpk(oAlo[4 * g + 2] * invA, oAlo[4 * g + 3] * invA) };
    u32x2 pb = { cvtpk(oAhi[4 * g + 0] * invA, oAhi[4 * g + 1] * invA),
                 cvtpk(oAhi[4 * g + 2] * invA, oAhi[4 * g + 3] * invA) };
    *reinterpret_cast<u32x2*>(&Obuf[orow + d0]) = pa;
    *reinterpret_cast<u32x2*>(&Obuf[orow + 32 + d0]) = pb;
    u32x2 qa = { cvtpk(oBlo[4 * g + 0] * invB, oBlo[4 * g + 1] * invB),
                 cvtpk(oBlo[4 * g + 2] * invB, oBlo[4 * g + 3] * invB) };
    u32x2 qb = { cvtpk(oBhi[4 * g + 0] * invB, oBhi[4 * g + 1] * invB),
                 cvtpk(oBhi[4 * g + 2] * invB, oBhi[4 * g + 3] * invB) };
    *reinterpret_cast<u32x2*>(&Obuf[orow + 64 + d0]) = qa;
    *reinterpret_cast<u32x2*>(&Obuf[orow + 96 + d0]) = qb;
  }
}

// ---- launch ---------------------------------------------------------------
extern "C" void kernel_launch(void* const* d_in, const int* in_sizes, int n_in,
                              void* d_out, int out_size, void* d_ws, size_t ws_size,
                              hipStream_t stream) {
  const float* hs = (const float*)d_in[0];
  const int* seg = (const int*)d_in[1];
  const float* Wq = (const float*)d_in[2];
  const float* Wk = (const float*)d_in[3];
  const float* Wv = (const float*)d_in[4];
  const float* Wo = (const float*)d_in[5];
  float* out = (float*)d_out;
  char* ws = (char*)d_ws;
  // hsb 8.4M | wqkvT 3.1M | woT 2.1M | Qf 8.4M | Kf 2.1M | Vf 2.1M | sst 16K
  u16* hsb   = (u16*)(ws);
  u16* wqkvT = (u16*)(ws + 8388608);
  u16* woT   = (u16*)(ws + 11534336);
  u16* qf    = (u16*)(ws + 13631488);
  u16* kf    = (u16*)(ws + 22020096);
  u16* vf    = (u16*)(ws + 24117248);
  int* sst   = (int*)(ws + 26214400);
  u16* obuf  = hsb;   // hsb dead after GEMM1

  prep<<<dim3(6672), dim3(256), 0, stream>>>(hs, hsb, seg, sst,
                                             Wq, Wk, Wv, Wo, wqkvT, woT);
  gemm_bt<1><<<dim3(12, 32), dim3(512), 0, stream>>>(
      hsb, wqkvT, nullptr, qf, kf, vf, 4096, 1536, 1024);
  attn<<<dim3(64, 8, 2), dim3(128), 0, stream>>>(qf, kf, vf, sst, obuf);
  gemm_bt<0><<<dim3(8, 32), dim3(512), 0, stream>>>(
      obuf, woT, out, nullptr, nullptr, nullptr, 4096, 1024, 1024);
}